// Round 6
// baseline (313.392 us; speedup 1.0000x reference)
//
#include <hip/hip_runtime.h>
#include <math.h>

// Problem constants
#define B_ 16
#define L_ 1024
#define D_ 768

typedef short bf16x8 __attribute__((ext_vector_type(8)));
typedef float f32x4 __attribute__((ext_vector_type(4)));

// round-to-nearest-even f32 -> bf16 (bit trick; inputs never NaN)
__device__ __forceinline__ unsigned short f2bf(float x) {
  unsigned u = __float_as_uint(x);
  u = (u + 0x7FFFu + ((u >> 16) & 1u)) >> 16;
  return (unsigned short)u;
}
__device__ __forceinline__ float bf2f(unsigned short h) {
  return __uint_as_float(((unsigned)h) << 16);
}

// ---------------------------------------------------------------------------
// K0: canonicalize mask (bool-bytes / int32 / int64 auto-detect). 1 = padding.
// ---------------------------------------------------------------------------
__global__ __launch_bounds__(256) void k_mask(const void* __restrict__ mraw,
                                              int* __restrict__ canon) {
  __shared__ int flags[2];
  if (threadIdx.x < 2) flags[threadIdx.x] = 0;
  __syncthreads();
  const unsigned* m32 = (const unsigned*)mraw;
  int gt = 0, oddnz = 0;
  for (int i = threadIdx.x; i < 4096; i += 256) {
    unsigned v = m32[i];
    if (v > 1u) gt = 1;
    if ((i & 1) && v != 0u) oddnz = 1;
  }
  if (gt) atomicOr(&flags[0], 1);
  if (oddnz) atomicOr(&flags[1], 1);
  __syncthreads();
  const int mode = flags[0] ? 0 : (flags[1] ? 1 : 2);  // 0=u8, 1=i32, 2=i64
  for (int i = threadIdx.x; i < B_ * L_; i += 256) {
    int v;
    if (mode == 0)      v = ((const unsigned char*)mraw)[i];
    else if (mode == 1) v = ((const int*)mraw)[i];
    else                v = (int)(((const long long*)mraw)[i] != 0);
    canon[i] = (v != 0);
  }
}

// ---------------------------------------------------------------------------
// K-split: elementwise f32 -> bf16 hi/lo pair, 8 elems/thread, coalesced.
// ---------------------------------------------------------------------------
__global__ __launch_bounds__(256) void k_split(const float* __restrict__ src,
                                               unsigned short* __restrict__ hi,
                                               unsigned short* __restrict__ lo,
                                               int n8) {
  const int i = blockIdx.x * 256 + threadIdx.x;
  if (i >= n8) return;
  const float4 a = *(const float4*)(src + (size_t)i * 8);
  const float4 b = *(const float4*)(src + (size_t)i * 8 + 4);
  const float xs[8] = {a.x, a.y, a.z, a.w, b.x, b.y, b.z, b.w};
  unsigned short h[8], l[8];
#pragma unroll
  for (int e = 0; e < 8; ++e) {
    h[e] = f2bf(xs[e]);
    l[e] = f2bf(xs[e] - bf2f(h[e]));
  }
  *(ushort4*)(hi + (size_t)i * 8)     = make_ushort4(h[0], h[1], h[2], h[3]);
  *(ushort4*)(hi + (size_t)i * 8 + 4) = make_ushort4(h[4], h[5], h[6], h[7]);
  *(ushort4*)(lo + (size_t)i * 8)     = make_ushort4(l[0], l[1], l[2], l[3]);
  *(ushort4*)(lo + (size_t)i * 8 + 4) = make_ushort4(l[4], l[5], l[6], l[7]);
}

// ---------------------------------------------------------------------------
// Shared staging helpers (m97-style): 128-row x 128B LDS panels,
// rows = [hi 4x16B | lo 4x16B] slots, XOR-swizzled via pre-swizzled source.
// ---------------------------------------------------------------------------
__device__ __forceinline__ void stage_panel(const unsigned short* __restrict__ ph,
                                            const unsigned short* __restrict__ pl,
                                            size_t grow0, int kk,
                                            char* ldsbase, int wave, int lane) {
#pragma unroll
  for (int q = 0; q < 4; ++q) {
    const int s = wave * 4 + q;              // 1KB span: 8 rows x 128B
    const int row = s * 8 + (lane >> 3);
    const int xs = (lane & 7) ^ (row & 7);   // pre-swizzled source slot
    const unsigned short* src = (xs & 4) ? pl : ph;
    const unsigned short* g = src + (grow0 + row) * D_ + kk + (xs & 3) * 8;
    __builtin_amdgcn_global_load_lds(
        (const __attribute__((address_space(1))) void*)g,
        (__attribute__((address_space(3))) void*)(ldsbase + s * 1024),
        16, 0, 0);
  }
}

__device__ __forceinline__ bf16x8 ldsfrag(const char* base, int row, int g) {
  // g: 0-3 = hi slots, 4-7 = lo slots
  return *(const bf16x8*)(base + row * 128 + ((g ^ (row & 7)) * 16));
}

// ---------------------------------------------------------------------------
// K1 v2 (MFMA): P = relu(Xs·Ws^T + b) from pre-split bf16 inputs.
// A (X panel) double-buffered, B (W panel) single-buffered -> 48KB LDS,
// 3 blocks/CU, grid 768 = exactly 3 waves-of-blocks x 256 CUs. n-outer
// m-inner XCD chunking keeps each XCD's W panel L2-resident.
// ---------------------------------------------------------------------------
__global__ __launch_bounds__(256) void k_proj2(const unsigned short* __restrict__ Xh,
                                               const unsigned short* __restrict__ Xl,
                                               const unsigned short* __restrict__ Wh,
                                               const unsigned short* __restrict__ Wl,
                                               const float* __restrict__ bias,
                                               unsigned short* __restrict__ Ph,
                                               unsigned short* __restrict__ Pl) {
  __shared__ __align__(16) char smem[49152];  // A: 2x16KB @0, B: 16KB @32KB
  const int tid = threadIdx.x;
  const int swz = ((int)blockIdx.x % 8) * 96 + (int)blockIdx.x / 8;
  const int n0 = (swz >> 7) * 128;   // 6 n-tiles, outer
  const int m0 = (swz & 127) * 128;  // 128 m-tiles, inner
  const int lane = tid & 63, wave = tid >> 6;
  const int wr = wave >> 1, wc = wave & 1;
  const int fr = lane & 15, kg = lane >> 4;
  f32x4 acc[4][4];
#pragma unroll
  for (int i = 0; i < 4; ++i)
#pragma unroll
    for (int j = 0; j < 4; ++j) acc[i][j] = 0;

  stage_panel(Xh, Xl, (size_t)m0, 0, smem, wave, lane);
  stage_panel(Wh, Wl, (size_t)n0, 0, smem + 32768, wave, lane);
  __syncthreads();  // drains vmcnt -> buffers ready

  int cur = 0;
  for (int it = 0; it < D_ / 32; ++it) {
    const char* ab = smem + cur * 16384;
    const char* bb = smem + 32768;
    bf16x8 fah[4], fal[4], fbh[4], fbl[4];
#pragma unroll
    for (int i = 0; i < 4; ++i) {
      const int ra = wr * 64 + i * 16 + fr;
      const int rb = wc * 64 + i * 16 + fr;
      fah[i] = ldsfrag(ab, ra, kg);
      fal[i] = ldsfrag(ab, ra, kg + 4);
      fbh[i] = ldsfrag(bb, rb, kg);
      fbl[i] = ldsfrag(bb, rb, kg + 4);
    }
    __syncthreads();  // all reads done -> safe to overwrite B / stage next A
    if (it + 1 < D_ / 32) {
      stage_panel(Xh, Xl, (size_t)m0, (it + 1) * 32, smem + (cur ^ 1) * 16384, wave, lane);
      stage_panel(Wh, Wl, (size_t)n0, (it + 1) * 32, smem + 32768, wave, lane);
    }
#pragma unroll
    for (int i = 0; i < 4; ++i)
#pragma unroll
      for (int j = 0; j < 4; ++j) {
        acc[i][j] = __builtin_amdgcn_mfma_f32_16x16x32_bf16(fah[i], fbh[j], acc[i][j], 0, 0, 0);
        acc[i][j] = __builtin_amdgcn_mfma_f32_16x16x32_bf16(fah[i], fbl[j], acc[i][j], 0, 0, 0);
        acc[i][j] = __builtin_amdgcn_mfma_f32_16x16x32_bf16(fal[i], fbh[j], acc[i][j], 0, 0, 0);
      }
    __syncthreads();  // drains vmcnt -> next buffers ready
    cur ^= 1;
  }

  // Epilogue: bias+relu+split in regs; LDS transpose; 2x uint4/lane per array.
  unsigned short* scr = (unsigned short*)smem + wave * 2304;  // [2][16][72]/wave
  const int row = lane >> 2, seg = lane & 3;
  float bj[4];
#pragma unroll
  for (int j = 0; j < 4; ++j) bj[j] = bias[n0 + wc * 64 + j * 16 + fr];
  for (int i = 0; i < 4; ++i) {
    __syncthreads();
#pragma unroll
    for (int j = 0; j < 4; ++j)
#pragma unroll
      for (int r = 0; r < 4; ++r) {
        float v = fmaxf(acc[i][j][r] + bj[j], 0.f);
        const unsigned short h = f2bf(v);
        scr[(kg * 4 + r) * 72 + j * 16 + fr] = h;
        scr[1152 + (kg * 4 + r) * 72 + j * 16 + fr] = f2bf(v - bf2f(h));
      }
    __syncthreads();
    const size_t gr = (size_t)(m0 + wr * 64 + i * 16 + row);
    const int gc0 = n0 + wc * 64 + seg * 16;
    const uint4 h0 = *(const uint4*)&scr[row * 72 + seg * 16];
    const uint4 h1 = *(const uint4*)&scr[row * 72 + seg * 16 + 8];
    const uint4 q0 = *(const uint4*)&scr[1152 + row * 72 + seg * 16];
    const uint4 q1 = *(const uint4*)&scr[1152 + row * 72 + seg * 16 + 8];
    *(uint4*)(Ph + gr * D_ + gc0)     = h0;
    *(uint4*)(Ph + gr * D_ + gc0 + 8) = h1;
    *(uint4*)(Pl + gr * D_ + gc0)     = q0;
    *(uint4*)(Pl + gr * D_ + gc0 + 8) = q1;
  }
}

// ---------------------------------------------------------------------------
// K1 fallback (r5): P = relu(X·W^T + b), on-the-fly split (used if ws small).
// ---------------------------------------------------------------------------
__global__ __launch_bounds__(256) void k_proj(const float* __restrict__ X,
                                              const float* __restrict__ W,
                                              const float* __restrict__ bias,
                                              unsigned short* __restrict__ Ph,
                                              unsigned short* __restrict__ Pl) {
  __shared__ __align__(16) unsigned short smem[4 * 128 * 32];  // 32 KB
  unsigned short (*Ah)[32] = (unsigned short(*)[32])smem;
  unsigned short (*Al)[32] = (unsigned short(*)[32])(smem + 1 * 128 * 32);
  unsigned short (*Bh)[32] = (unsigned short(*)[32])(smem + 2 * 128 * 32);
  unsigned short (*Bl)[32] = (unsigned short(*)[32])(smem + 3 * 128 * 32);

  const int tid = threadIdx.x;
  const int swz = ((int)blockIdx.x % 8) * 96 + (int)blockIdx.x / 8;
  const int m0 = (swz / 6) * 128, n0 = (swz % 6) * 128;
  const int lane = tid & 63, wave = tid >> 6;
  const int wr = wave >> 1, wc = wave & 1;
  const int fr = lane & 15, kg = lane >> 4;
  f32x4 acc[4][4];
#pragma unroll
  for (int i = 0; i < 4; ++i)
#pragma unroll
    for (int j = 0; j < 4; ++j) acc[i][j] = 0;

  float4 av[4], bv[4];
#pragma unroll
  for (int p = 0; p < 4; ++p) {
    const int f = tid + p * 256, r = f >> 3, c = f & 7;
    av[p] = *(const float4*)(X + (size_t)(m0 + r) * D_ + c * 4);
    bv[p] = *(const float4*)(W + (size_t)(n0 + r) * D_ + c * 4);
  }

  for (int it = 0; it < D_ / 32; ++it) {
    __syncthreads();
#pragma unroll
    for (int p = 0; p < 4; ++p) {
      const int f = tid + p * 256, r = f >> 3, c = f & 7;
      {
        const float x0 = av[p].x, x1 = av[p].y, x2 = av[p].z, x3 = av[p].w;
        const unsigned short h0 = f2bf(x0), h1 = f2bf(x1), h2 = f2bf(x2), h3 = f2bf(x3);
        *(ushort4*)&Ah[r][c * 4] = make_ushort4(h0, h1, h2, h3);
        *(ushort4*)&Al[r][c * 4] = make_ushort4(f2bf(x0 - bf2f(h0)), f2bf(x1 - bf2f(h1)),
                                                f2bf(x2 - bf2f(h2)), f2bf(x3 - bf2f(h3)));
      }
      {
        const float x0 = bv[p].x, x1 = bv[p].y, x2 = bv[p].z, x3 = bv[p].w;
        const unsigned short h0 = f2bf(x0), h1 = f2bf(x1), h2 = f2bf(x2), h3 = f2bf(x3);
        *(ushort4*)&Bh[r][c * 4] = make_ushort4(h0, h1, h2, h3);
        *(ushort4*)&Bl[r][c * 4] = make_ushort4(f2bf(x0 - bf2f(h0)), f2bf(x1 - bf2f(h1)),
                                                f2bf(x2 - bf2f(h2)), f2bf(x3 - bf2f(h3)));
      }
    }
    __syncthreads();
    if (it + 1 < D_ / 32) {
      const int kk = (it + 1) * 32;
#pragma unroll
      for (int p = 0; p < 4; ++p) {
        const int f = tid + p * 256, r = f >> 3, c = f & 7;
        av[p] = *(const float4*)(X + (size_t)(m0 + r) * D_ + kk + c * 4);
        bv[p] = *(const float4*)(W + (size_t)(n0 + r) * D_ + kk + c * 4);
      }
    }
    bf16x8 fah[4], fal[4], fbh[4], fbl[4];
#pragma unroll
    for (int i = 0; i < 4; ++i) {
      fah[i] = *(const bf16x8*)&Ah[wr * 64 + i * 16 + fr][kg * 8];
      fal[i] = *(const bf16x8*)&Al[wr * 64 + i * 16 + fr][kg * 8];
      fbh[i] = *(const bf16x8*)&Bh[wc * 64 + i * 16 + fr][kg * 8];
      fbl[i] = *(const bf16x8*)&Bl[wc * 64 + i * 16 + fr][kg * 8];
    }
#pragma unroll
    for (int i = 0; i < 4; ++i)
#pragma unroll
      for (int j = 0; j < 4; ++j) {
        acc[i][j] = __builtin_amdgcn_mfma_f32_16x16x32_bf16(fah[i], fbh[j], acc[i][j], 0, 0, 0);
        acc[i][j] = __builtin_amdgcn_mfma_f32_16x16x32_bf16(fah[i], fbl[j], acc[i][j], 0, 0, 0);
        acc[i][j] = __builtin_amdgcn_mfma_f32_16x16x32_bf16(fal[i], fbh[j], acc[i][j], 0, 0, 0);
      }
  }

  unsigned short* scr = smem + wave * 2304;
  const int row = lane >> 2, seg = lane & 3;
  float bj[4];
#pragma unroll
  for (int j = 0; j < 4; ++j) bj[j] = bias[n0 + wc * 64 + j * 16 + fr];
  for (int i = 0; i < 4; ++i) {
    __syncthreads();
#pragma unroll
    for (int j = 0; j < 4; ++j)
#pragma unroll
      for (int r = 0; r < 4; ++r) {
        float v = fmaxf(acc[i][j][r] + bj[j], 0.f);
        const unsigned short h = f2bf(v);
        scr[(kg * 4 + r) * 72 + j * 16 + fr] = h;
        scr[1152 + (kg * 4 + r) * 72 + j * 16 + fr] = f2bf(v - bf2f(h));
      }
    __syncthreads();
    const size_t gr = (size_t)(m0 + wr * 64 + i * 16 + row);
    const int gc0 = n0 + wc * 64 + seg * 16;
    const uint4 h0 = *(const uint4*)&scr[row * 72 + seg * 16];
    const uint4 h1 = *(const uint4*)&scr[row * 72 + seg * 16 + 8];
    const uint4 q0 = *(const uint4*)&scr[1152 + row * 72 + seg * 16];
    const uint4 q1 = *(const uint4*)&scr[1152 + row * 72 + seg * 16 + 8];
    *(uint4*)(Ph + gr * D_ + gc0)     = h0;
    *(uint4*)(Ph + gr * D_ + gc0 + 8) = h1;
    *(uint4*)(Pl + gr * D_ + gc0)     = q0;
    *(uint4*)(Pl + gr * D_ + gc0 + 8) = q1;
  }
}

// ---------------------------------------------------------------------------
// K2 (MFMA): S = P·P^T, symmetric pairs, gload_lds double-buffered (r5).
// ---------------------------------------------------------------------------
__global__ __launch_bounds__(256) void k_scores(const unsigned short* __restrict__ Ph,
                                                const unsigned short* __restrict__ Pl,
                                                const int* __restrict__ mask,
                                                float* __restrict__ S) {
  __shared__ __align__(16) char smem[65536];  // 2 buffers x (A 16KB + B 16KB)

  const int tid = threadIdx.x;
  const int swz = ((int)blockIdx.x % 8) * 72 + (int)blockIdx.x / 8;
  const int bb = swz / 36;
  const int pr = swz % 36;
  int ti = 0;
  while ((ti + 1) * (ti + 2) / 2 <= pr) ++ti;
  const int tj = pr - ti * (ti + 1) / 2;
  const int l0 = ti * 128, m0 = tj * 128;
  const int lane = tid & 63, wave = tid >> 6;
  const int wr = wave >> 1, wc = wave & 1;
  const int fr = lane & 15, kg = lane >> 4;
  f32x4 acc[4][4];
#pragma unroll
  for (int i = 0; i < 4; ++i)
#pragma unroll
    for (int j = 0; j < 4; ++j) acc[i][j] = 0;

  const size_t arow0 = (size_t)bb * L_ + l0;
  const size_t brow0 = (size_t)bb * L_ + m0;

  stage_panel(Ph, Pl, arow0, 0, smem, wave, lane);
  stage_panel(Ph, Pl, brow0, 0, smem + 16384, wave, lane);
  __syncthreads();

  int cur = 0;
  for (int it = 0; it < D_ / 32; ++it) {
    char* cb = smem + cur * 32768;
    if (it + 1 < D_ / 32) {
      char* nb = smem + (cur ^ 1) * 32768;
      stage_panel(Ph, Pl, arow0, (it + 1) * 32, nb, wave, lane);
      stage_panel(Ph, Pl, brow0, (it + 1) * 32, nb + 16384, wave, lane);
    }
    bf16x8 fah[4], fal[4], fbh[4], fbl[4];
#pragma unroll
    for (int i = 0; i < 4; ++i) {
      const int ra = wr * 64 + i * 16 + fr;
      const int rb = wc * 64 + i * 16 + fr;
      fah[i] = ldsfrag(cb, ra, kg);
      fal[i] = ldsfrag(cb, ra, kg + 4);
      fbh[i] = ldsfrag(cb + 16384, rb, kg);
      fbl[i] = ldsfrag(cb + 16384, rb, kg + 4);
    }
#pragma unroll
    for (int i = 0; i < 4; ++i)
#pragma unroll
      for (int j = 0; j < 4; ++j) {
        acc[i][j] = __builtin_amdgcn_mfma_f32_16x16x32_bf16(fah[i], fbh[j], acc[i][j], 0, 0, 0);
        acc[i][j] = __builtin_amdgcn_mfma_f32_16x16x32_bf16(fah[i], fbl[j], acc[i][j], 0, 0, 0);
        acc[i][j] = __builtin_amdgcn_mfma_f32_16x16x32_bf16(fal[i], fbh[j], acc[i][j], 0, 0, 0);
      }
    __syncthreads();
    cur ^= 1;
  }

  // ---- main tile epilogue ----
  float* scr = (float*)smem + wave * 1280;
  const int row = lane >> 2, seg = lane & 3;
  for (int i = 0; i < 4; ++i) {
    __syncthreads();
#pragma unroll
    for (int j = 0; j < 4; ++j)
#pragma unroll
      for (int r = 0; r < 4; ++r)
        scr[(kg * 4 + r) * 68 + j * 16 + fr] = acc[i][j][r];
    __syncthreads();
    const int gl = l0 + wr * 64 + i * 16 + row;
    const int gm0 = m0 + wc * 64 + seg * 16;
    const size_t sbase = ((size_t)bb * L_ + gl) * L_ + gm0;
#pragma unroll
    for (int t = 0; t < 4; ++t) {
      float4 o = *(const float4*)&scr[row * 68 + seg * 16 + t * 4];
      const int4 mk = *(const int4*)(mask + bb * L_ + gm0 + t * 4);
      float* op = (float*)&o;
      const int* mp = (const int*)&mk;
#pragma unroll
      for (int e = 0; e < 4; ++e) {
        const int gm = gm0 + t * 4 + e;
        if (gm == gl) op[e] = 0.f;
        if (mp[e]) op[e] = -INFINITY;
      }
      *(float4*)(S + sbase + t * 4) = o;
    }
  }

  // ---- mirror tile: full 128x128 staged in LDS, 512B-contiguous rows ----
  if (ti != tj) {
    __syncthreads();
#pragma unroll
    for (int j = 0; j < 4; ++j) {
      const int mloc = wc * 64 + j * 16 + fr;
#pragma unroll
      for (int i = 0; i < 4; ++i) {
        const int slot = wr * 16 + i * 4 + kg;
        const int xs = slot ^ (mloc & 7);
        *(f32x4*)(smem + mloc * 512 + xs * 16) = acc[i][j];
      }
    }
    __syncthreads();
    const int mrow = tid >> 1, half = tid & 1;
    const size_t sbase = ((size_t)bb * L_ + m0 + mrow) * L_ + l0;
#pragma unroll
    for (int q = 0; q < 16; ++q) {
      const int slot = half * 16 + q;
      const int xs = slot ^ (mrow & 7);
      float4 o = *(const float4*)(smem + mrow * 512 + xs * 16);
      const int4 mk = *(const int4*)(mask + bb * L_ + l0 + slot * 4);
      if (mk.x) o.x = -INFINITY;
      if (mk.y) o.y = -INFINITY;
      if (mk.z) o.z = -INFINITY;
      if (mk.w) o.w = -INFINITY;
      *(float4*)(S + sbase + slot * 4) = o;
    }
  }
}

// ---------------------------------------------------------------------------
// K3: in-place row softmax over 1024 keys.
// ---------------------------------------------------------------------------
__global__ __launch_bounds__(256) void k_softmax(float* __restrict__ S) {
  const size_t row = blockIdx.x;
  float4* rp = (float4*)(S + row * L_);
  float4 v = rp[threadIdx.x];
  float mx = fmaxf(fmaxf(v.x, v.y), fmaxf(v.z, v.w));
#pragma unroll
  for (int o = 32; o > 0; o >>= 1) mx = fmaxf(mx, __shfl_xor(mx, o));
  __shared__ float rmax[4], rsum[4];
  const int wv = threadIdx.x >> 6, ln = threadIdx.x & 63;
  if (ln == 0) rmax[wv] = mx;
  __syncthreads();
  mx = fmaxf(fmaxf(rmax[0], rmax[1]), fmaxf(rmax[2], rmax[3]));
  float4 e;
  e.x = __expf(v.x - mx); e.y = __expf(v.y - mx);
  e.z = __expf(v.z - mx); e.w = __expf(v.w - mx);
  float s = (e.x + e.y) + (e.z + e.w);
#pragma unroll
  for (int o = 32; o > 0; o >>= 1) s += __shfl_xor(s, o);
  if (ln == 0) rsum[wv] = s;
  __syncthreads();
  s = (rsum[0] + rsum[1]) + (rsum[2] + rsum[3]);
  const float inv = 1.0f / s;
  e.x *= inv; e.y *= inv; e.z *= inv; e.w *= inv;
  rp[threadIdx.x] = e;
}

// ---------------------------------------------------------------------------
// K4: Xt[b][d][m] = bf16(X[b][m][d])
// ---------------------------------------------------------------------------
__global__ __launch_bounds__(256) void k_transpose(const float* __restrict__ X,
                                                   unsigned short* __restrict__ Xt) {
  __shared__ float t[32][33];
  const int b = blockIdx.z;
  const int d0 = blockIdx.x * 32, m0 = blockIdx.y * 32;
  const int tx = threadIdx.x & 31, ty = threadIdx.x >> 5;
#pragma unroll
  for (int i = 0; i < 32; i += 8)
    t[ty + i][tx] = X[((size_t)b * L_ + m0 + ty + i) * D_ + d0 + tx];
  __syncthreads();
#pragma unroll
  for (int i = 0; i < 32; i += 8)
    Xt[((size_t)b * D_ + d0 + ty + i) * L_ + m0 + tx] = f2bf(t[tx][ty + i]);
}

// ---------------------------------------------------------------------------
// K5 (MFMA): align = alpha·X per batch. (unchanged r4/r5)
// ---------------------------------------------------------------------------
__global__ __launch_bounds__(256) void k_align(const float* __restrict__ A,
                                               const unsigned short* __restrict__ Xt,
                                               float* __restrict__ O) {
  __shared__ __align__(16) unsigned short smem[2 * 128 * 32];
  __shared__ __align__(16) float scr_s[4 * 1104];
  unsigned short (*Ab)[32] = (unsigned short(*)[32])smem;
  unsigned short (*Bb)[32] = (unsigned short(*)[32])(smem + 128 * 32);

  const int tid = threadIdx.x;
  const int swz = ((int)blockIdx.x % 8) * 96 + (int)blockIdx.x / 8;
  const int bb = swz / 48;
  const int l0 = ((swz / 6) % 8) * 128;
  const int n0 = (swz % 6) * 128;
  const int lane = tid & 63, wave = tid >> 6;
  const int wr = wave >> 1, wc = wave & 1;
  const int fr = lane & 15, kg = lane >> 4;
  f32x4 acc[4][4];
#pragma unroll
  for (int i = 0; i < 4; ++i)
#pragma unroll
    for (int j = 0; j < 4; ++j) acc[i][j] = 0;

  float4 av[4];
  uint4 bv[2];
#pragma unroll
  for (int p = 0; p < 4; ++p) {
    const int f = tid + p * 256, r = f >> 3, c = f & 7;
    av[p] = *(const float4*)(A + ((size_t)bb * L_ + l0 + r) * L_ + c * 4);
  }
#pragma unroll
  for (int p = 0; p < 2; ++p) {
    const int f = tid + p * 256, r = f >> 2, sl = f & 3;
    bv[p] = *(const uint4*)(Xt + ((size_t)bb * D_ + n0 + r) * L_ + sl * 8);
  }

  for (int it = 0; it < L_ / 32; ++it) {
    __syncthreads();
#pragma unroll
    for (int p = 0; p < 4; ++p) {
      const int f = tid + p * 256, r = f >> 3, c = f & 7;
      *(ushort4*)&Ab[r][c * 4] = make_ushort4(f2bf(av[p].x), f2bf(av[p].y),
                                              f2bf(av[p].z), f2bf(av[p].w));
    }
#pragma unroll
    for (int p = 0; p < 2; ++p) {
      const int f = tid + p * 256, r = f >> 2, sl = f & 3;
      *(uint4*)&Bb[r][sl * 8] = bv[p];
    }
    __syncthreads();
    if (it + 1 < L_ / 32) {
      const int kk = (it + 1) * 32;
#pragma unroll
      for (int p = 0; p < 4; ++p) {
        const int f = tid + p * 256, r = f >> 3, c = f & 7;
        av[p] = *(const float4*)(A + ((size_t)bb * L_ + l0 + r) * L_ + kk + c * 4);
      }
#pragma unroll
      for (int p = 0; p < 2; ++p) {
        const int f = tid + p * 256, r = f >> 2, sl = f & 3;
        bv[p] = *(const uint4*)(Xt + ((size_t)bb * D_ + n0 + r) * L_ + kk + sl * 8);
      }
    }
    bf16x8 fa[4], fb[4];
#pragma unroll
    for (int i = 0; i < 4; ++i) {
      fa[i] = *(const bf16x8*)&Ab[wr * 64 + i * 16 + fr][kg * 8];
      fb[i] = *(const bf16x8*)&Bb[wc * 64 + i * 16 + fr][kg * 8];
    }
#pragma unroll
    for (int i = 0; i < 4; ++i)
#pragma unroll
      for (int j = 0; j < 4; ++j)
        acc[i][j] = __builtin_amdgcn_mfma_f32_16x16x32_bf16(fa[i], fb[j], acc[i][j], 0, 0, 0);
  }

  float* scr = scr_s + wave * 1104;
  const int row = lane >> 2, seg = lane & 3;
  for (int i = 0; i < 4; ++i) {
    __syncthreads();
#pragma unroll
    for (int j = 0; j < 4; ++j)
#pragma unroll
      for (int r = 0; r < 4; ++r)
        scr[(kg * 4 + r) * 68 + j * 16 + fr] = acc[i][j][r];
    __syncthreads();
    const int gl = l0 + wr * 64 + i * 16 + row;
    const int gc0 = n0 + wc * 64 + seg * 16;
    const size_t obase = ((size_t)bb * L_ + gl) * D_ + gc0;
#pragma unroll
    for (int t = 0; t < 4; ++t) {
      const float4 o = *(const float4*)&scr[row * 68 + seg * 16 + t * 4];
      *(float4*)(O + obase + t * 4) = o;
    }
  }
}

// ---------------------------------------------------------------------------
extern "C" void kernel_launch(void* const* d_in, const int* in_sizes, int n_in,
                              void* d_out, int out_size, void* d_ws, size_t ws_size,
                              hipStream_t stream) {
  const float* X    = (const float*)d_in[0];  // [B,L,D]
  const void*  mraw = d_in[1];                // [B,L] bool/int
  const float* W    = (const float*)d_in[2];  // [D,D]
  const float* bias = (const float*)d_in[3];  // [D]

  float* out   = (float*)d_out;
  float* align = out;                          // B*L*D fp32 (48MB)
  float* alpha = out + (size_t)B_ * L_ * D_;   // B*L*L fp32 (64MB)

  const size_t NX = (size_t)B_ * L_ * D_;  // 12,582,912
  const size_t NW = (size_t)D_ * D_;       // 589,824

  int* maskC = (int*)d_ws;                                      // 64 KB
  unsigned short* Xt = (unsigned short*)((char*)d_ws + 65536);  // 25.17 MB

  // fast-path ws layout: maskC | Xt | Wh | Wl | Pl
  const size_t offWh = 65536 + NX * 2;
  const size_t offWl = offWh + NW * 2;
  const size_t offPl = offWl + NW * 2;
  const size_t need  = offPl + NX * 2;  // ~52.8 MB

  hipLaunchKernelGGL(k_mask, dim3(1), dim3(256), 0, stream, mraw, maskC);
  hipLaunchKernelGGL(k_transpose, dim3(D_ / 32, L_ / 32, B_), dim3(256), 0, stream, X, Xt);

  unsigned short* Ph;
  unsigned short* Pl;
  if (ws_size >= need) {
    // Xh/Xl live in the (dead-until-scores) alpha region; Pl in ws -> no overlap.
    unsigned short* Xh = (unsigned short*)alpha;
    unsigned short* Xl = Xh + NX;
    unsigned short* Wh = (unsigned short*)((char*)d_ws + offWh);
    unsigned short* Wl = (unsigned short*)((char*)d_ws + offWl);
    Ph = (unsigned short*)align;
    Pl = (unsigned short*)((char*)d_ws + offPl);
    hipLaunchKernelGGL(k_split, dim3((int)(NX / 8 / 256)), dim3(256), 0, stream, X, Xh, Xl, (int)(NX / 8));
    hipLaunchKernelGGL(k_split, dim3((int)(NW / 8 / 256)), dim3(256), 0, stream, W, Wh, Wl, (int)(NW / 8));
    hipLaunchKernelGGL(k_proj2, dim3(768), dim3(256), 0, stream, Xh, Xl, Wh, Wl, bias, Ph, Pl);
  } else {
    // fallback (r5 layout): Ph,Pl packed in align region (benign phase-separated spill)
    Ph = (unsigned short*)align;
    Pl = Ph + NX;
    hipLaunchKernelGGL(k_proj, dim3(768), dim3(256), 0, stream, X, W, bias, Ph, Pl);
  }

  hipLaunchKernelGGL(k_scores, dim3(576), dim3(256), 0, stream, Ph, Pl, maskC, alpha);
  hipLaunchKernelGGL(k_softmax, dim3(B_ * L_), dim3(256), 0, stream, alpha);
  hipLaunchKernelGGL(k_align, dim3(768), dim3(256), 0, stream, alpha, Xt, align);
}

// Round 7
// 271.682 us; speedup vs baseline: 1.1535x; 1.1535x over previous
//
#include <hip/hip_runtime.h>
#include <math.h>

// Problem constants
#define B_ 16
#define L_ 1024
#define D_ 768

typedef short bf16x8 __attribute__((ext_vector_type(8)));
typedef float f32x4 __attribute__((ext_vector_type(4)));

// round-to-nearest-even f32 -> bf16 (bit trick; inputs never NaN)
__device__ __forceinline__ unsigned short f2bf(float x) {
  unsigned u = __float_as_uint(x);
  u = (u + 0x7FFFu + ((u >> 16) & 1u)) >> 16;
  return (unsigned short)u;
}
__device__ __forceinline__ float bf2f(unsigned short h) {
  return __uint_as_float(((unsigned)h) << 16);
}

// ---------------------------------------------------------------------------
// K0: canonicalize mask (bool-bytes / int32 / int64 auto-detect). 1 = padding.
// ---------------------------------------------------------------------------
__global__ __launch_bounds__(256) void k_mask(const void* __restrict__ mraw,
                                              int* __restrict__ canon) {
  __shared__ int flags[2];
  if (threadIdx.x < 2) flags[threadIdx.x] = 0;
  __syncthreads();
  const unsigned* m32 = (const unsigned*)mraw;
  int gt = 0, oddnz = 0;
  for (int i = threadIdx.x; i < 4096; i += 256) {
    unsigned v = m32[i];
    if (v > 1u) gt = 1;
    if ((i & 1) && v != 0u) oddnz = 1;
  }
  if (gt) atomicOr(&flags[0], 1);
  if (oddnz) atomicOr(&flags[1], 1);
  __syncthreads();
  const int mode = flags[0] ? 0 : (flags[1] ? 1 : 2);  // 0=u8, 1=i32, 2=i64
  for (int i = threadIdx.x; i < B_ * L_; i += 256) {
    int v;
    if (mode == 0)      v = ((const unsigned char*)mraw)[i];
    else if (mode == 1) v = ((const int*)mraw)[i];
    else                v = (int)(((const long long*)mraw)[i] != 0);
    canon[i] = (v != 0);
  }
}

// ---------------------------------------------------------------------------
// K-prep: ONE pass over X producing Xh, Xl (hi/lo bf16, X layout) and
// Xt (bf16 transposed [b][d][m]). 64m x 64d tile; all global writes are
// full 128B lines; LDS pad 66 -> 2-way (free) bank aliasing.
// ---------------------------------------------------------------------------
__global__ __launch_bounds__(256) void k_prep(const float* __restrict__ X,
                                              unsigned short* __restrict__ Xh,
                                              unsigned short* __restrict__ Xl,
                                              unsigned short* __restrict__ Xt) {
  __shared__ unsigned short t16[64][66];
  const int b = blockIdx.z;
  const int d0 = blockIdx.x * 64, m0 = blockIdx.y * 64;
  const int dd = threadIdx.x & 63, mq = threadIdx.x >> 6;
#pragma unroll
  for (int i = 0; i < 16; ++i) {
    const int m = mq * 16 + i;
    const size_t gidx = ((size_t)b * L_ + m0 + m) * D_ + d0 + dd;
    const float x = X[gidx];
    const unsigned short h = f2bf(x);
    Xh[gidx] = h;
    Xl[gidx] = f2bf(x - bf2f(h));
    t16[dd][m] = h;
  }
  __syncthreads();
  const int mm = threadIdx.x & 63, dq = threadIdx.x >> 6;
#pragma unroll
  for (int i = 0; i < 16; ++i) {
    const int d = dq * 16 + i;
    Xt[((size_t)b * D_ + d0 + d) * L_ + m0 + mm] = t16[d][mm];
  }
}

// ---------------------------------------------------------------------------
// K-split: elementwise f32 -> bf16 hi/lo pair (used for W only).
// ---------------------------------------------------------------------------
__global__ __launch_bounds__(256) void k_split(const float* __restrict__ src,
                                               unsigned short* __restrict__ hi,
                                               unsigned short* __restrict__ lo,
                                               int n8) {
  const int i = blockIdx.x * 256 + threadIdx.x;
  if (i >= n8) return;
  const float4 a = *(const float4*)(src + (size_t)i * 8);
  const float4 b = *(const float4*)(src + (size_t)i * 8 + 4);
  const float xs[8] = {a.x, a.y, a.z, a.w, b.x, b.y, b.z, b.w};
  unsigned short h[8], l[8];
#pragma unroll
  for (int e = 0; e < 8; ++e) {
    h[e] = f2bf(xs[e]);
    l[e] = f2bf(xs[e] - bf2f(h[e]));
  }
  *(ushort4*)(hi + (size_t)i * 8)     = make_ushort4(h[0], h[1], h[2], h[3]);
  *(ushort4*)(hi + (size_t)i * 8 + 4) = make_ushort4(h[4], h[5], h[6], h[7]);
  *(ushort4*)(lo + (size_t)i * 8)     = make_ushort4(l[0], l[1], l[2], l[3]);
  *(ushort4*)(lo + (size_t)i * 8 + 4) = make_ushort4(l[4], l[5], l[6], l[7]);
}

// ---------------------------------------------------------------------------
// Staging helpers: 128-row x 128B LDS panels, 16B slots XOR-swizzled via
// pre-swizzled global source (slot xs = s ^ (row&7)).
// stage_panel: rows = [hi 4 slots | lo 4 slots] from two arrays (K-tile 32).
// stage_panel1: 8 slots from one bf16 array (K-tile 64), row stride in elems.
// ---------------------------------------------------------------------------
__device__ __forceinline__ void stage_panel(const unsigned short* __restrict__ ph,
                                            const unsigned short* __restrict__ pl,
                                            size_t grow0, int kk,
                                            char* ldsbase, int wave, int lane) {
#pragma unroll
  for (int q = 0; q < 4; ++q) {
    const int s = wave * 4 + q;              // 1KB span: 8 rows x 128B
    const int row = s * 8 + (lane >> 3);
    const int xs = (lane & 7) ^ (row & 7);   // pre-swizzled source slot
    const unsigned short* src = (xs & 4) ? pl : ph;
    const unsigned short* g = src + (grow0 + row) * D_ + kk + (xs & 3) * 8;
    __builtin_amdgcn_global_load_lds(
        (const __attribute__((address_space(1))) void*)g,
        (__attribute__((address_space(3))) void*)(ldsbase + s * 1024),
        16, 0, 0);
  }
}

__device__ __forceinline__ void stage_panel1(const unsigned short* __restrict__ g0,
                                             size_t rstride,
                                             char* ldsbase, int wave, int lane) {
#pragma unroll
  for (int q = 0; q < 4; ++q) {
    const int s = wave * 4 + q;
    const int row = s * 8 + (lane >> 3);
    const int xs = (lane & 7) ^ (row & 7);
    const unsigned short* g = g0 + (size_t)row * rstride + xs * 8;
    __builtin_amdgcn_global_load_lds(
        (const __attribute__((address_space(1))) void*)g,
        (__attribute__((address_space(3))) void*)(ldsbase + s * 1024),
        16, 0, 0);
  }
}

__device__ __forceinline__ bf16x8 ldsfrag(const char* base, int row, int g) {
  return *(const bf16x8*)(base + row * 128 + ((g ^ (row & 7)) * 16));
}

// ---------------------------------------------------------------------------
// K1 v2 (MFMA): P = relu(Xs·Ws^T + b) from pre-split bf16 inputs.
// ---------------------------------------------------------------------------
__global__ __launch_bounds__(256) void k_proj2(const unsigned short* __restrict__ Xh,
                                               const unsigned short* __restrict__ Xl,
                                               const unsigned short* __restrict__ Wh,
                                               const unsigned short* __restrict__ Wl,
                                               const float* __restrict__ bias,
                                               unsigned short* __restrict__ Ph,
                                               unsigned short* __restrict__ Pl) {
  __shared__ __align__(16) char smem[49152];  // A: 2x16KB @0, B: 16KB @32KB
  const int tid = threadIdx.x;
  const int swz = ((int)blockIdx.x % 8) * 96 + (int)blockIdx.x / 8;
  const int n0 = (swz >> 7) * 128;
  const int m0 = (swz & 127) * 128;
  const int lane = tid & 63, wave = tid >> 6;
  const int wr = wave >> 1, wc = wave & 1;
  const int fr = lane & 15, kg = lane >> 4;
  f32x4 acc[4][4];
#pragma unroll
  for (int i = 0; i < 4; ++i)
#pragma unroll
    for (int j = 0; j < 4; ++j) acc[i][j] = 0;

  stage_panel(Xh, Xl, (size_t)m0, 0, smem, wave, lane);
  stage_panel(Wh, Wl, (size_t)n0, 0, smem + 32768, wave, lane);
  __syncthreads();

  int cur = 0;
  for (int it = 0; it < D_ / 32; ++it) {
    const char* ab = smem + cur * 16384;
    const char* bb = smem + 32768;
    bf16x8 fah[4], fal[4], fbh[4], fbl[4];
#pragma unroll
    for (int i = 0; i < 4; ++i) {
      const int ra = wr * 64 + i * 16 + fr;
      const int rb = wc * 64 + i * 16 + fr;
      fah[i] = ldsfrag(ab, ra, kg);
      fal[i] = ldsfrag(ab, ra, kg + 4);
      fbh[i] = ldsfrag(bb, rb, kg);
      fbl[i] = ldsfrag(bb, rb, kg + 4);
    }
    __syncthreads();
    if (it + 1 < D_ / 32) {
      stage_panel(Xh, Xl, (size_t)m0, (it + 1) * 32, smem + (cur ^ 1) * 16384, wave, lane);
      stage_panel(Wh, Wl, (size_t)n0, (it + 1) * 32, smem + 32768, wave, lane);
    }
#pragma unroll
    for (int i = 0; i < 4; ++i)
#pragma unroll
      for (int j = 0; j < 4; ++j) {
        acc[i][j] = __builtin_amdgcn_mfma_f32_16x16x32_bf16(fah[i], fbh[j], acc[i][j], 0, 0, 0);
        acc[i][j] = __builtin_amdgcn_mfma_f32_16x16x32_bf16(fah[i], fbl[j], acc[i][j], 0, 0, 0);
        acc[i][j] = __builtin_amdgcn_mfma_f32_16x16x32_bf16(fal[i], fbh[j], acc[i][j], 0, 0, 0);
      }
    __syncthreads();
    cur ^= 1;
  }

  unsigned short* scr = (unsigned short*)smem + wave * 2304;
  const int row = lane >> 2, seg = lane & 3;
  float bj[4];
#pragma unroll
  for (int j = 0; j < 4; ++j) bj[j] = bias[n0 + wc * 64 + j * 16 + fr];
  for (int i = 0; i < 4; ++i) {
    __syncthreads();
#pragma unroll
    for (int j = 0; j < 4; ++j)
#pragma unroll
      for (int r = 0; r < 4; ++r) {
        float v = fmaxf(acc[i][j][r] + bj[j], 0.f);
        const unsigned short h = f2bf(v);
        scr[(kg * 4 + r) * 72 + j * 16 + fr] = h;
        scr[1152 + (kg * 4 + r) * 72 + j * 16 + fr] = f2bf(v - bf2f(h));
      }
    __syncthreads();
    const size_t gr = (size_t)(m0 + wr * 64 + i * 16 + row);
    const int gc0 = n0 + wc * 64 + seg * 16;
    const uint4 h0 = *(const uint4*)&scr[row * 72 + seg * 16];
    const uint4 h1 = *(const uint4*)&scr[row * 72 + seg * 16 + 8];
    const uint4 q0 = *(const uint4*)&scr[1152 + row * 72 + seg * 16];
    const uint4 q1 = *(const uint4*)&scr[1152 + row * 72 + seg * 16 + 8];
    *(uint4*)(Ph + gr * D_ + gc0)     = h0;
    *(uint4*)(Ph + gr * D_ + gc0 + 8) = h1;
    *(uint4*)(Pl + gr * D_ + gc0)     = q0;
    *(uint4*)(Pl + gr * D_ + gc0 + 8) = q1;
  }
}

// ---------------------------------------------------------------------------
// K1 fallback (r5): on-the-fly split proj (used if ws is small).
// ---------------------------------------------------------------------------
__global__ __launch_bounds__(256) void k_proj(const float* __restrict__ X,
                                              const float* __restrict__ W,
                                              const float* __restrict__ bias,
                                              unsigned short* __restrict__ Ph,
                                              unsigned short* __restrict__ Pl) {
  __shared__ __align__(16) unsigned short smem[4 * 128 * 32];
  unsigned short (*Ah)[32] = (unsigned short(*)[32])smem;
  unsigned short (*Al)[32] = (unsigned short(*)[32])(smem + 1 * 128 * 32);
  unsigned short (*Bh)[32] = (unsigned short(*)[32])(smem + 2 * 128 * 32);
  unsigned short (*Bl)[32] = (unsigned short(*)[32])(smem + 3 * 128 * 32);

  const int tid = threadIdx.x;
  const int swz = ((int)blockIdx.x % 8) * 96 + (int)blockIdx.x / 8;
  const int m0 = (swz / 6) * 128, n0 = (swz % 6) * 128;
  const int lane = tid & 63, wave = tid >> 6;
  const int wr = wave >> 1, wc = wave & 1;
  const int fr = lane & 15, kg = lane >> 4;
  f32x4 acc[4][4];
#pragma unroll
  for (int i = 0; i < 4; ++i)
#pragma unroll
    for (int j = 0; j < 4; ++j) acc[i][j] = 0;

  float4 av[4], bv[4];
#pragma unroll
  for (int p = 0; p < 4; ++p) {
    const int f = tid + p * 256, r = f >> 3, c = f & 7;
    av[p] = *(const float4*)(X + (size_t)(m0 + r) * D_ + c * 4);
    bv[p] = *(const float4*)(W + (size_t)(n0 + r) * D_ + c * 4);
  }

  for (int it = 0; it < D_ / 32; ++it) {
    __syncthreads();
#pragma unroll
    for (int p = 0; p < 4; ++p) {
      const int f = tid + p * 256, r = f >> 3, c = f & 7;
      {
        const float x0 = av[p].x, x1 = av[p].y, x2 = av[p].z, x3 = av[p].w;
        const unsigned short h0 = f2bf(x0), h1 = f2bf(x1), h2 = f2bf(x2), h3 = f2bf(x3);
        *(ushort4*)&Ah[r][c * 4] = make_ushort4(h0, h1, h2, h3);
        *(ushort4*)&Al[r][c * 4] = make_ushort4(f2bf(x0 - bf2f(h0)), f2bf(x1 - bf2f(h1)),
                                                f2bf(x2 - bf2f(h2)), f2bf(x3 - bf2f(h3)));
      }
      {
        const float x0 = bv[p].x, x1 = bv[p].y, x2 = bv[p].z, x3 = bv[p].w;
        const unsigned short h0 = f2bf(x0), h1 = f2bf(x1), h2 = f2bf(x2), h3 = f2bf(x3);
        *(ushort4*)&Bh[r][c * 4] = make_ushort4(h0, h1, h2, h3);
        *(ushort4*)&Bl[r][c * 4] = make_ushort4(f2bf(x0 - bf2f(h0)), f2bf(x1 - bf2f(h1)),
                                                f2bf(x2 - bf2f(h2)), f2bf(x3 - bf2f(h3)));
      }
    }
    __syncthreads();
    if (it + 1 < D_ / 32) {
      const int kk = (it + 1) * 32;
#pragma unroll
      for (int p = 0; p < 4; ++p) {
        const int f = tid + p * 256, r = f >> 3, c = f & 7;
        av[p] = *(const float4*)(X + (size_t)(m0 + r) * D_ + kk + c * 4);
        bv[p] = *(const float4*)(W + (size_t)(n0 + r) * D_ + kk + c * 4);
      }
    }
    bf16x8 fah[4], fal[4], fbh[4], fbl[4];
#pragma unroll
    for (int i = 0; i < 4; ++i) {
      fah[i] = *(const bf16x8*)&Ah[wr * 64 + i * 16 + fr][kg * 8];
      fal[i] = *(const bf16x8*)&Al[wr * 64 + i * 16 + fr][kg * 8];
      fbh[i] = *(const bf16x8*)&Bh[wc * 64 + i * 16 + fr][kg * 8];
      fbl[i] = *(const bf16x8*)&Bl[wc * 64 + i * 16 + fr][kg * 8];
    }
#pragma unroll
    for (int i = 0; i < 4; ++i)
#pragma unroll
      for (int j = 0; j < 4; ++j) {
        acc[i][j] = __builtin_amdgcn_mfma_f32_16x16x32_bf16(fah[i], fbh[j], acc[i][j], 0, 0, 0);
        acc[i][j] = __builtin_amdgcn_mfma_f32_16x16x32_bf16(fah[i], fbl[j], acc[i][j], 0, 0, 0);
        acc[i][j] = __builtin_amdgcn_mfma_f32_16x16x32_bf16(fal[i], fbh[j], acc[i][j], 0, 0, 0);
      }
  }

  unsigned short* scr = smem + wave * 2304;
  const int row = lane >> 2, seg = lane & 3;
  float bj[4];
#pragma unroll
  for (int j = 0; j < 4; ++j) bj[j] = bias[n0 + wc * 64 + j * 16 + fr];
  for (int i = 0; i < 4; ++i) {
    __syncthreads();
#pragma unroll
    for (int j = 0; j < 4; ++j)
#pragma unroll
      for (int r = 0; r < 4; ++r) {
        float v = fmaxf(acc[i][j][r] + bj[j], 0.f);
        const unsigned short h = f2bf(v);
        scr[(kg * 4 + r) * 72 + j * 16 + fr] = h;
        scr[1152 + (kg * 4 + r) * 72 + j * 16 + fr] = f2bf(v - bf2f(h));
      }
    __syncthreads();
    const size_t gr = (size_t)(m0 + wr * 64 + i * 16 + row);
    const int gc0 = n0 + wc * 64 + seg * 16;
    const uint4 h0 = *(const uint4*)&scr[row * 72 + seg * 16];
    const uint4 h1 = *(const uint4*)&scr[row * 72 + seg * 16 + 8];
    const uint4 q0 = *(const uint4*)&scr[1152 + row * 72 + seg * 16];
    const uint4 q1 = *(const uint4*)&scr[1152 + row * 72 + seg * 16 + 8];
    *(uint4*)(Ph + gr * D_ + gc0)     = h0;
    *(uint4*)(Ph + gr * D_ + gc0 + 8) = h1;
    *(uint4*)(Pl + gr * D_ + gc0)     = q0;
    *(uint4*)(Pl + gr * D_ + gc0 + 8) = q1;
  }
}

// ---------------------------------------------------------------------------
// K2 (MFMA): S = P·P^T, symmetric pairs, gload_lds double-buffered (r5).
// ---------------------------------------------------------------------------
__global__ __launch_bounds__(256) void k_scores(const unsigned short* __restrict__ Ph,
                                                const unsigned short* __restrict__ Pl,
                                                const int* __restrict__ mask,
                                                float* __restrict__ S) {
  __shared__ __align__(16) char smem[65536];

  const int tid = threadIdx.x;
  const int swz = ((int)blockIdx.x % 8) * 72 + (int)blockIdx.x / 8;
  const int bb = swz / 36;
  const int pr = swz % 36;
  int ti = 0;
  while ((ti + 1) * (ti + 2) / 2 <= pr) ++ti;
  const int tj = pr - ti * (ti + 1) / 2;
  const int l0 = ti * 128, m0 = tj * 128;
  const int lane = tid & 63, wave = tid >> 6;
  const int wr = wave >> 1, wc = wave & 1;
  const int fr = lane & 15, kg = lane >> 4;
  f32x4 acc[4][4];
#pragma unroll
  for (int i = 0; i < 4; ++i)
#pragma unroll
    for (int j = 0; j < 4; ++j) acc[i][j] = 0;

  const size_t arow0 = (size_t)bb * L_ + l0;
  const size_t brow0 = (size_t)bb * L_ + m0;

  stage_panel(Ph, Pl, arow0, 0, smem, wave, lane);
  stage_panel(Ph, Pl, brow0, 0, smem + 16384, wave, lane);
  __syncthreads();

  int cur = 0;
  for (int it = 0; it < D_ / 32; ++it) {
    char* cb = smem + cur * 32768;
    if (it + 1 < D_ / 32) {
      char* nb = smem + (cur ^ 1) * 32768;
      stage_panel(Ph, Pl, arow0, (it + 1) * 32, nb, wave, lane);
      stage_panel(Ph, Pl, brow0, (it + 1) * 32, nb + 16384, wave, lane);
    }
    bf16x8 fah[4], fal[4], fbh[4], fbl[4];
#pragma unroll
    for (int i = 0; i < 4; ++i) {
      const int ra = wr * 64 + i * 16 + fr;
      const int rb = wc * 64 + i * 16 + fr;
      fah[i] = ldsfrag(cb, ra, kg);
      fal[i] = ldsfrag(cb, ra, kg + 4);
      fbh[i] = ldsfrag(cb + 16384, rb, kg);
      fbl[i] = ldsfrag(cb + 16384, rb, kg + 4);
    }
#pragma unroll
    for (int i = 0; i < 4; ++i)
#pragma unroll
      for (int j = 0; j < 4; ++j) {
        acc[i][j] = __builtin_amdgcn_mfma_f32_16x16x32_bf16(fah[i], fbh[j], acc[i][j], 0, 0, 0);
        acc[i][j] = __builtin_amdgcn_mfma_f32_16x16x32_bf16(fah[i], fbl[j], acc[i][j], 0, 0, 0);
        acc[i][j] = __builtin_amdgcn_mfma_f32_16x16x32_bf16(fal[i], fbh[j], acc[i][j], 0, 0, 0);
      }
    __syncthreads();
    cur ^= 1;
  }

  float* scr = (float*)smem + wave * 1280;
  const int row = lane >> 2, seg = lane & 3;
  for (int i = 0; i < 4; ++i) {
    __syncthreads();
#pragma unroll
    for (int j = 0; j < 4; ++j)
#pragma unroll
      for (int r = 0; r < 4; ++r)
        scr[(kg * 4 + r) * 68 + j * 16 + fr] = acc[i][j][r];
    __syncthreads();
    const int gl = l0 + wr * 64 + i * 16 + row;
    const int gm0 = m0 + wc * 64 + seg * 16;
    const size_t sbase = ((size_t)bb * L_ + gl) * L_ + gm0;
#pragma unroll
    for (int t = 0; t < 4; ++t) {
      float4 o = *(const float4*)&scr[row * 68 + seg * 16 + t * 4];
      const int4 mk = *(const int4*)(mask + bb * L_ + gm0 + t * 4);
      float* op = (float*)&o;
      const int* mp = (const int*)&mk;
#pragma unroll
      for (int e = 0; e < 4; ++e) {
        const int gm = gm0 + t * 4 + e;
        if (gm == gl) op[e] = 0.f;
        if (mp[e]) op[e] = -INFINITY;
      }
      *(float4*)(S + sbase + t * 4) = o;
    }
  }

  if (ti != tj) {
    __syncthreads();
#pragma unroll
    for (int j = 0; j < 4; ++j) {
      const int mloc = wc * 64 + j * 16 + fr;
#pragma unroll
      for (int i = 0; i < 4; ++i) {
        const int slot = wr * 16 + i * 4 + kg;
        const int xs = slot ^ (mloc & 7);
        *(f32x4*)(smem + mloc * 512 + xs * 16) = acc[i][j];
      }
    }
    __syncthreads();
    const int mrow = tid >> 1, half = tid & 1;
    const size_t sbase = ((size_t)bb * L_ + m0 + mrow) * L_ + l0;
#pragma unroll
    for (int q = 0; q < 16; ++q) {
      const int slot = half * 16 + q;
      const int xs = slot ^ (mrow & 7);
      float4 o = *(const float4*)(smem + mrow * 512 + xs * 16);
      const int4 mk = *(const int4*)(mask + bb * L_ + l0 + slot * 4);
      if (mk.x) o.x = -INFINITY;
      if (mk.y) o.y = -INFINITY;
      if (mk.z) o.z = -INFINITY;
      if (mk.w) o.w = -INFINITY;
      *(float4*)(S + sbase + slot * 4) = o;
    }
  }
}

// ---------------------------------------------------------------------------
// K3: in-place row softmax; optionally also emits bf16 copy (for k_align2).
// ---------------------------------------------------------------------------
__global__ __launch_bounds__(256) void k_softmax(float* __restrict__ S,
                                                 unsigned short* __restrict__ a16) {
  const size_t row = blockIdx.x;
  float4* rp = (float4*)(S + row * L_);
  float4 v = rp[threadIdx.x];
  float mx = fmaxf(fmaxf(v.x, v.y), fmaxf(v.z, v.w));
#pragma unroll
  for (int o = 32; o > 0; o >>= 1) mx = fmaxf(mx, __shfl_xor(mx, o));
  __shared__ float rmax[4], rsum[4];
  const int wv = threadIdx.x >> 6, ln = threadIdx.x & 63;
  if (ln == 0) rmax[wv] = mx;
  __syncthreads();
  mx = fmaxf(fmaxf(rmax[0], rmax[1]), fmaxf(rmax[2], rmax[3]));
  float4 e;
  e.x = __expf(v.x - mx); e.y = __expf(v.y - mx);
  e.z = __expf(v.z - mx); e.w = __expf(v.w - mx);
  float s = (e.x + e.y) + (e.z + e.w);
#pragma unroll
  for (int o = 32; o > 0; o >>= 1) s += __shfl_xor(s, o);
  if (ln == 0) rsum[wv] = s;
  __syncthreads();
  s = (rsum[0] + rsum[1]) + (rsum[2] + rsum[3]);
  const float inv = 1.0f / s;
  e.x *= inv; e.y *= inv; e.z *= inv; e.w *= inv;
  rp[threadIdx.x] = e;
  if (a16) {
    *(ushort4*)(a16 + row * L_ + threadIdx.x * 4) =
        make_ushort4(f2bf(e.x), f2bf(e.y), f2bf(e.z), f2bf(e.w));
  }
}

// ---------------------------------------------------------------------------
// K5 v2 (MFMA): align = alpha16·Xt^T per batch. Both operands bf16;
// gload_lds + XOR-swizzle + double-buffer, K-tile 64 (2 MFMA substeps).
// ---------------------------------------------------------------------------
__global__ __launch_bounds__(256) void k_align2(const unsigned short* __restrict__ A16,
                                                const unsigned short* __restrict__ Xt,
                                                float* __restrict__ O) {
  __shared__ __align__(16) char smem[65536];  // 2 x (A 16KB + B 16KB)
  const int tid = threadIdx.x;
  const int swz = ((int)blockIdx.x % 8) * 96 + (int)blockIdx.x / 8;
  const int bb = swz / 48;
  const int l0 = ((swz / 6) % 8) * 128;
  const int n0 = (swz % 6) * 128;
  const int lane = tid & 63, wave = tid >> 6;
  const int wr = wave >> 1, wc = wave & 1;
  const int fr = lane & 15, kg = lane >> 4;
  f32x4 acc[4][4];
#pragma unroll
  for (int i = 0; i < 4; ++i)
#pragma unroll
    for (int j = 0; j < 4; ++j) acc[i][j] = 0;

  const unsigned short* a0 = A16 + ((size_t)bb * L_ + l0) * L_;
  const unsigned short* b0 = Xt + ((size_t)bb * D_ + n0) * L_;

  stage_panel1(a0, L_, smem, wave, lane);
  stage_panel1(b0, L_, smem + 16384, wave, lane);
  __syncthreads();

  int cur = 0;
  for (int it = 0; it < L_ / 64; ++it) {
    char* cb = smem + cur * 32768;
    if (it + 1 < L_ / 64) {
      char* nb = smem + (cur ^ 1) * 32768;
      stage_panel1(a0 + (it + 1) * 64, L_, nb, wave, lane);
      stage_panel1(b0 + (it + 1) * 64, L_, nb + 16384, wave, lane);
    }
    bf16x8 fa[2][4], fb[2][4];
#pragma unroll
    for (int i = 0; i < 4; ++i) {
      const int ra = wr * 64 + i * 16 + fr;
      const int rb = wc * 64 + i * 16 + fr;
#pragma unroll
      for (int ks = 0; ks < 2; ++ks) {
        fa[ks][i] = ldsfrag(cb, ra, ks * 4 + kg);
        fb[ks][i] = ldsfrag(cb + 16384, rb, ks * 4 + kg);
      }
    }
#pragma unroll
    for (int ks = 0; ks < 2; ++ks)
#pragma unroll
      for (int i = 0; i < 4; ++i)
#pragma unroll
        for (int j = 0; j < 4; ++j)
          acc[i][j] = __builtin_amdgcn_mfma_f32_16x16x32_bf16(fa[ks][i], fb[ks][j],
                                                              acc[i][j], 0, 0, 0);
    __syncthreads();
    cur ^= 1;
  }

  // Epilogue: LDS transpose -> 4x float4 per lane, row-contiguous.
  float* scr = (float*)smem + wave * 1280;
  const int row = lane >> 2, seg = lane & 3;
  for (int i = 0; i < 4; ++i) {
    __syncthreads();
#pragma unroll
    for (int j = 0; j < 4; ++j)
#pragma unroll
      for (int r = 0; r < 4; ++r)
        scr[(kg * 4 + r) * 68 + j * 16 + fr] = acc[i][j][r];
    __syncthreads();
    const int gl = l0 + wr * 64 + i * 16 + row;
    const int gc0 = n0 + wc * 64 + seg * 16;
    const size_t obase = ((size_t)bb * L_ + gl) * D_ + gc0;
#pragma unroll
    for (int t = 0; t < 4; ++t) {
      const float4 o = *(const float4*)&scr[row * 68 + seg * 16 + t * 4];
      *(float4*)(O + obase + t * 4) = o;
    }
  }
}

// ---------------------------------------------------------------------------
// K5 fallback (r6): align = alpha(f32)·Xt^T with in-staging conversion.
// ---------------------------------------------------------------------------
__global__ __launch_bounds__(256) void k_align(const float* __restrict__ A,
                                               const unsigned short* __restrict__ Xt,
                                               float* __restrict__ O) {
  __shared__ __align__(16) unsigned short smem[2 * 128 * 32];
  __shared__ __align__(16) float scr_s[4 * 1104];
  unsigned short (*Ab)[32] = (unsigned short(*)[32])smem;
  unsigned short (*Bb)[32] = (unsigned short(*)[32])(smem + 128 * 32);

  const int tid = threadIdx.x;
  const int swz = ((int)blockIdx.x % 8) * 96 + (int)blockIdx.x / 8;
  const int bb = swz / 48;
  const int l0 = ((swz / 6) % 8) * 128;
  const int n0 = (swz % 6) * 128;
  const int lane = tid & 63, wave = tid >> 6;
  const int wr = wave >> 1, wc = wave & 1;
  const int fr = lane & 15, kg = lane >> 4;
  f32x4 acc[4][4];
#pragma unroll
  for (int i = 0; i < 4; ++i)
#pragma unroll
    for (int j = 0; j < 4; ++j) acc[i][j] = 0;

  float4 av[4];
  uint4 bv[2];
#pragma unroll
  for (int p = 0; p < 4; ++p) {
    const int f = tid + p * 256, r = f >> 3, c = f & 7;
    av[p] = *(const float4*)(A + ((size_t)bb * L_ + l0 + r) * L_ + c * 4);
  }
#pragma unroll
  for (int p = 0; p < 2; ++p) {
    const int f = tid + p * 256, r = f >> 2, sl = f & 3;
    bv[p] = *(const uint4*)(Xt + ((size_t)bb * D_ + n0 + r) * L_ + sl * 8);
  }

  for (int it = 0; it < L_ / 32; ++it) {
    __syncthreads();
#pragma unroll
    for (int p = 0; p < 4; ++p) {
      const int f = tid + p * 256, r = f >> 3, c = f & 7;
      *(ushort4*)&Ab[r][c * 4] = make_ushort4(f2bf(av[p].x), f2bf(av[p].y),
                                              f2bf(av[p].z), f2bf(av[p].w));
    }
#pragma unroll
    for (int p = 0; p < 2; ++p) {
      const int f = tid + p * 256, r = f >> 2, sl = f & 3;
      *(uint4*)&Bb[r][sl * 8] = bv[p];
    }
    __syncthreads();
    if (it + 1 < L_ / 32) {
      const int kk = (it + 1) * 32;
#pragma unroll
      for (int p = 0; p < 4; ++p) {
        const int f = tid + p * 256, r = f >> 3, c = f & 7;
        av[p] = *(const float4*)(A + ((size_t)bb * L_ + l0 + r) * L_ + kk + c * 4);
      }
#pragma unroll
      for (int p = 0; p < 2; ++p) {
        const int f = tid + p * 256, r = f >> 2, sl = f & 3;
        bv[p] = *(const uint4*)(Xt + ((size_t)bb * D_ + n0 + r) * L_ + kk + sl * 8);
      }
    }
    bf16x8 fa[4], fb[4];
#pragma unroll
    for (int i = 0; i < 4; ++i) {
      fa[i] = *(const bf16x8*)&Ab[wr * 64 + i * 16 + fr][kg * 8];
      fb[i] = *(const bf16x8*)&Bb[wc * 64 + i * 16 + fr][kg * 8];
    }
#pragma unroll
    for (int i = 0; i < 4; ++i)
#pragma unroll
      for (int j = 0; j < 4; ++j)
        acc[i][j] = __builtin_amdgcn_mfma_f32_16x16x32_bf16(fa[i], fb[j], acc[i][j], 0, 0, 0);
  }

  float* scr = scr_s + wave * 1104;
  const int row = lane >> 2, seg = lane & 3;
  for (int i = 0; i < 4; ++i) {
    __syncthreads();
#pragma unroll
    for (int j = 0; j < 4; ++j)
#pragma unroll
      for (int r = 0; r < 4; ++r)
        scr[(kg * 4 + r) * 68 + j * 16 + fr] = acc[i][j][r];
    __syncthreads();
    const int gl = l0 + wr * 64 + i * 16 + row;
    const int gc0 = n0 + wc * 64 + seg * 16;
    const size_t obase = ((size_t)bb * L_ + gl) * D_ + gc0;
#pragma unroll
    for (int t = 0; t < 4; ++t) {
      const float4 o = *(const float4*)&scr[row * 68 + seg * 16 + t * 4];
      *(float4*)(O + obase + t * 4) = o;
    }
  }
}

// ---------------------------------------------------------------------------
extern "C" void kernel_launch(void* const* d_in, const int* in_sizes, int n_in,
                              void* d_out, int out_size, void* d_ws, size_t ws_size,
                              hipStream_t stream) {
  const float* X    = (const float*)d_in[0];  // [B,L,D]
  const void*  mraw = d_in[1];                // [B,L] bool/int
  const float* W    = (const float*)d_in[2];  // [D,D]
  const float* bias = (const float*)d_in[3];  // [D]

  float* out   = (float*)d_out;
  float* align = out;                          // B*L*D fp32 (48MB)
  float* alpha = out + (size_t)B_ * L_ * D_;   // B*L*L fp32 (64MB)

  const size_t NX = (size_t)B_ * L_ * D_;   // 12,582,912
  const size_t NW = (size_t)D_ * D_;        // 589,824
  const size_t NA = (size_t)B_ * L_ * L_;   // 16,777,216

  int* maskC = (int*)d_ws;                                      // 64 KB
  unsigned short* Xt = (unsigned short*)((char*)d_ws + 65536);  // 25.17 MB

  // ws layout: maskC | Xt | Wh | Wl | Pl ; alpha16 overlays Wh.. (dead
  // after k_scores; written by k_softmax, read by k_align2).
  const size_t offWh = 65536 + NX * 2;
  const size_t offWl = offWh + NW * 2;
  const size_t offPl = offWl + NW * 2;
  const size_t needProj = offPl + NX * 2;   // ~52.8 MB
  const size_t offA16 = offWh;
  const size_t needA16 = offA16 + NA * 2;   // ~58.9 MB

  hipLaunchKernelGGL(k_mask, dim3(1), dim3(256), 0, stream, mraw, maskC);

  unsigned short* Ph;
  unsigned short* Pl;
  if (ws_size >= needProj) {
    // Xh/Xl in the (dead-until-scores) alpha output region; Pl in ws.
    unsigned short* Xh = (unsigned short*)alpha;
    unsigned short* Xl = Xh + NX;
    unsigned short* Wh = (unsigned short*)((char*)d_ws + offWh);
    unsigned short* Wl = (unsigned short*)((char*)d_ws + offWl);
    Ph = (unsigned short*)align;
    Pl = (unsigned short*)((char*)d_ws + offPl);
    hipLaunchKernelGGL(k_prep, dim3(D_ / 64, L_ / 64, B_), dim3(256), 0, stream,
                       X, Xh, Xl, Xt);
    hipLaunchKernelGGL(k_split, dim3((int)(NW / 8 / 256)), dim3(256), 0, stream,
                       W, Wh, Wl, (int)(NW / 8));
    hipLaunchKernelGGL(k_proj2, dim3(768), dim3(256), 0, stream,
                       Xh, Xl, Wh, Wl, bias, Ph, Pl);
  } else {
    Ph = (unsigned short*)align;
    Pl = Ph + NX;
    hipLaunchKernelGGL(k_prep, dim3(D_ / 64, L_ / 64, B_), dim3(256), 0, stream,
                       X, (unsigned short*)alpha, (unsigned short*)alpha + NX, Xt);
    hipLaunchKernelGGL(k_proj, dim3(768), dim3(256), 0, stream, X, W, bias, Ph, Pl);
  }

  hipLaunchKernelGGL(k_scores, dim3(576), dim3(256), 0, stream, Ph, Pl, maskC, alpha);

  if (ws_size >= needA16) {
    unsigned short* A16 = (unsigned short*)((char*)d_ws + offA16);
    hipLaunchKernelGGL(k_softmax, dim3(B_ * L_), dim3(256), 0, stream, alpha, A16);
    hipLaunchKernelGGL(k_align2, dim3(768), dim3(256), 0, stream, A16, Xt, align);
  } else {
    hipLaunchKernelGGL(k_softmax, dim3(B_ * L_), dim3(256), 0, stream, alpha,
                       (unsigned short*)nullptr);
    hipLaunchKernelGGL(k_align, dim3(768), dim3(256), 0, stream, alpha, Xt, align);
  }
}

// Round 8
// 263.083 us; speedup vs baseline: 1.1912x; 1.0327x over previous
//
#include <hip/hip_runtime.h>
#include <math.h>

// Problem constants
#define B_ 16
#define L_ 1024
#define D_ 768

typedef short bf16x8 __attribute__((ext_vector_type(8)));
typedef float f32x4 __attribute__((ext_vector_type(4)));

// round-to-nearest-even f32 -> bf16 (bit trick; inputs never NaN)
__device__ __forceinline__ unsigned short f2bf(float x) {
  unsigned u = __float_as_uint(x);
  u = (u + 0x7FFFu + ((u >> 16) & 1u)) >> 16;
  return (unsigned short)u;
}
__device__ __forceinline__ float bf2f(unsigned short h) {
  return __uint_as_float(((unsigned)h) << 16);
}

// ---------------------------------------------------------------------------
// K0: canonicalize mask (bool-bytes / int32 / int64 auto-detect). 1 = padding.
// ---------------------------------------------------------------------------
__global__ __launch_bounds__(256) void k_mask(const void* __restrict__ mraw,
                                              int* __restrict__ canon) {
  __shared__ int flags[2];
  if (threadIdx.x < 2) flags[threadIdx.x] = 0;
  __syncthreads();
  const unsigned* m32 = (const unsigned*)mraw;
  int gt = 0, oddnz = 0;
  for (int i = threadIdx.x; i < 4096; i += 256) {
    unsigned v = m32[i];
    if (v > 1u) gt = 1;
    if ((i & 1) && v != 0u) oddnz = 1;
  }
  if (gt) atomicOr(&flags[0], 1);
  if (oddnz) atomicOr(&flags[1], 1);
  __syncthreads();
  const int mode = flags[0] ? 0 : (flags[1] ? 1 : 2);  // 0=u8, 1=i32, 2=i64
  for (int i = threadIdx.x; i < B_ * L_; i += 256) {
    int v;
    if (mode == 0)      v = ((const unsigned char*)mraw)[i];
    else if (mode == 1) v = ((const int*)mraw)[i];
    else                v = (int)(((const long long*)mraw)[i] != 0);
    canon[i] = (v != 0);
  }
}

// ---------------------------------------------------------------------------
// K-prep: ONE pass over X producing Xh, Xl (hi/lo bf16, X layout) and
// Xt (bf16 transposed [b][d][m]).
// ---------------------------------------------------------------------------
__global__ __launch_bounds__(256) void k_prep(const float* __restrict__ X,
                                              unsigned short* __restrict__ Xh,
                                              unsigned short* __restrict__ Xl,
                                              unsigned short* __restrict__ Xt) {
  __shared__ unsigned short t16[64][66];
  const int b = blockIdx.z;
  const int d0 = blockIdx.x * 64, m0 = blockIdx.y * 64;
  const int dd = threadIdx.x & 63, mq = threadIdx.x >> 6;
#pragma unroll
  for (int i = 0; i < 16; ++i) {
    const int m = mq * 16 + i;
    const size_t gidx = ((size_t)b * L_ + m0 + m) * D_ + d0 + dd;
    const float x = X[gidx];
    const unsigned short h = f2bf(x);
    Xh[gidx] = h;
    Xl[gidx] = f2bf(x - bf2f(h));
    t16[dd][m] = h;
  }
  __syncthreads();
  const int mm = threadIdx.x & 63, dq = threadIdx.x >> 6;
#pragma unroll
  for (int i = 0; i < 16; ++i) {
    const int d = dq * 16 + i;
    Xt[((size_t)b * D_ + d0 + d) * L_ + m0 + mm] = t16[d][mm];
  }
}

// ---------------------------------------------------------------------------
// K-split: elementwise f32 -> bf16 hi/lo pair (used for W only).
// ---------------------------------------------------------------------------
__global__ __launch_bounds__(256) void k_split(const float* __restrict__ src,
                                               unsigned short* __restrict__ hi,
                                               unsigned short* __restrict__ lo,
                                               int n8) {
  const int i = blockIdx.x * 256 + threadIdx.x;
  if (i >= n8) return;
  const float4 a = *(const float4*)(src + (size_t)i * 8);
  const float4 b = *(const float4*)(src + (size_t)i * 8 + 4);
  const float xs[8] = {a.x, a.y, a.z, a.w, b.x, b.y, b.z, b.w};
  unsigned short h[8], l[8];
#pragma unroll
  for (int e = 0; e < 8; ++e) {
    h[e] = f2bf(xs[e]);
    l[e] = f2bf(xs[e] - bf2f(h[e]));
  }
  *(ushort4*)(hi + (size_t)i * 8)     = make_ushort4(h[0], h[1], h[2], h[3]);
  *(ushort4*)(hi + (size_t)i * 8 + 4) = make_ushort4(h[4], h[5], h[6], h[7]);
  *(ushort4*)(lo + (size_t)i * 8)     = make_ushort4(l[0], l[1], l[2], l[3]);
  *(ushort4*)(lo + (size_t)i * 8 + 4) = make_ushort4(l[4], l[5], l[6], l[7]);
}

// ---------------------------------------------------------------------------
// Staging helpers: 128-row x 128B LDS panels, 16B slots XOR-swizzled via
// pre-swizzled global source (slot xs = s ^ (row&7)).
// ---------------------------------------------------------------------------
__device__ __forceinline__ void stage_panel(const unsigned short* __restrict__ ph,
                                            const unsigned short* __restrict__ pl,
                                            size_t grow0, int kk,
                                            char* ldsbase, int wave, int lane) {
#pragma unroll
  for (int q = 0; q < 4; ++q) {
    const int s = wave * 4 + q;              // 1KB span: 8 rows x 128B
    const int row = s * 8 + (lane >> 3);
    const int xs = (lane & 7) ^ (row & 7);   // pre-swizzled source slot
    const unsigned short* src = (xs & 4) ? pl : ph;
    const unsigned short* g = src + (grow0 + row) * D_ + kk + (xs & 3) * 8;
    __builtin_amdgcn_global_load_lds(
        (const __attribute__((address_space(1))) void*)g,
        (__attribute__((address_space(3))) void*)(ldsbase + s * 1024),
        16, 0, 0);
  }
}

__device__ __forceinline__ void stage_panel1(const unsigned short* __restrict__ g0,
                                             size_t rstride,
                                             char* ldsbase, int wave, int lane) {
#pragma unroll
  for (int q = 0; q < 4; ++q) {
    const int s = wave * 4 + q;
    const int row = s * 8 + (lane >> 3);
    const int xs = (lane & 7) ^ (row & 7);
    const unsigned short* g = g0 + (size_t)row * rstride + xs * 8;
    __builtin_amdgcn_global_load_lds(
        (const __attribute__((address_space(1))) void*)g,
        (__attribute__((address_space(3))) void*)(ldsbase + s * 1024),
        16, 0, 0);
  }
}

__device__ __forceinline__ bf16x8 ldsfrag(const char* base, int row, int g) {
  return *(const bf16x8*)(base + row * 128 + ((g ^ (row & 7)) * 16));
}

// ---------------------------------------------------------------------------
// K1 v2 (MFMA): P = relu(Xs·Ws^T + b) from pre-split bf16 inputs.
// XCD-local mapping: each XCD owns 16 contiguous m-tiles (6.3MB X slice) and
// iterates the 6 n-tiles INNERMOST -> X fetched ~once, W hi/lo L2-resident.
// ---------------------------------------------------------------------------
__global__ __launch_bounds__(256) void k_proj2(const unsigned short* __restrict__ Xh,
                                               const unsigned short* __restrict__ Xl,
                                               const unsigned short* __restrict__ Wh,
                                               const unsigned short* __restrict__ Wl,
                                               const float* __restrict__ bias,
                                               unsigned short* __restrict__ Ph,
                                               unsigned short* __restrict__ Pl) {
  __shared__ __align__(16) char smem[49152];  // A: 2x16KB @0, B: 16KB @32KB
  const int tid = threadIdx.x;
  const int xcd = (int)blockIdx.x & 7;
  const int li  = (int)blockIdx.x >> 3;        // 0..95 within XCD
  const int m0 = (xcd * 16 + li / 6) * 128;    // 16 m-tiles per XCD, outer
  const int n0 = (li % 6) * 128;               // 6 n-tiles, inner
  const int lane = tid & 63, wave = tid >> 6;
  const int wr = wave >> 1, wc = wave & 1;
  const int fr = lane & 15, kg = lane >> 4;
  f32x4 acc[4][4];
#pragma unroll
  for (int i = 0; i < 4; ++i)
#pragma unroll
    for (int j = 0; j < 4; ++j) acc[i][j] = 0;

  stage_panel(Xh, Xl, (size_t)m0, 0, smem, wave, lane);
  stage_panel(Wh, Wl, (size_t)n0, 0, smem + 32768, wave, lane);
  __syncthreads();

  int cur = 0;
  for (int it = 0; it < D_ / 32; ++it) {
    const char* ab = smem + cur * 16384;
    const char* bb = smem + 32768;
    bf16x8 fah[4], fal[4], fbh[4], fbl[4];
#pragma unroll
    for (int i = 0; i < 4; ++i) {
      const int ra = wr * 64 + i * 16 + fr;
      const int rb = wc * 64 + i * 16 + fr;
      fah[i] = ldsfrag(ab, ra, kg);
      fal[i] = ldsfrag(ab, ra, kg + 4);
      fbh[i] = ldsfrag(bb, rb, kg);
      fbl[i] = ldsfrag(bb, rb, kg + 4);
    }
    __syncthreads();
    if (it + 1 < D_ / 32) {
      stage_panel(Xh, Xl, (size_t)m0, (it + 1) * 32, smem + (cur ^ 1) * 16384, wave, lane);
      stage_panel(Wh, Wl, (size_t)n0, (it + 1) * 32, smem + 32768, wave, lane);
    }
#pragma unroll
    for (int i = 0; i < 4; ++i)
#pragma unroll
      for (int j = 0; j < 4; ++j) {
        acc[i][j] = __builtin_amdgcn_mfma_f32_16x16x32_bf16(fah[i], fbh[j], acc[i][j], 0, 0, 0);
        acc[i][j] = __builtin_amdgcn_mfma_f32_16x16x32_bf16(fah[i], fbl[j], acc[i][j], 0, 0, 0);
        acc[i][j] = __builtin_amdgcn_mfma_f32_16x16x32_bf16(fal[i], fbh[j], acc[i][j], 0, 0, 0);
      }
    __syncthreads();
    cur ^= 1;
  }

  unsigned short* scr = (unsigned short*)smem + wave * 2304;
  const int row = lane >> 2, seg = lane & 3;
  float bj[4];
#pragma unroll
  for (int j = 0; j < 4; ++j) bj[j] = bias[n0 + wc * 64 + j * 16 + fr];
  for (int i = 0; i < 4; ++i) {
    __syncthreads();
#pragma unroll
    for (int j = 0; j < 4; ++j)
#pragma unroll
      for (int r = 0; r < 4; ++r) {
        float v = fmaxf(acc[i][j][r] + bj[j], 0.f);
        const unsigned short h = f2bf(v);
        scr[(kg * 4 + r) * 72 + j * 16 + fr] = h;
        scr[1152 + (kg * 4 + r) * 72 + j * 16 + fr] = f2bf(v - bf2f(h));
      }
    __syncthreads();
    const size_t gr = (size_t)(m0 + wr * 64 + i * 16 + row);
    const int gc0 = n0 + wc * 64 + seg * 16;
    const uint4 h0 = *(const uint4*)&scr[row * 72 + seg * 16];
    const uint4 h1 = *(const uint4*)&scr[row * 72 + seg * 16 + 8];
    const uint4 q0 = *(const uint4*)&scr[1152 + row * 72 + seg * 16];
    const uint4 q1 = *(const uint4*)&scr[1152 + row * 72 + seg * 16 + 8];
    *(uint4*)(Ph + gr * D_ + gc0)     = h0;
    *(uint4*)(Ph + gr * D_ + gc0 + 8) = h1;
    *(uint4*)(Pl + gr * D_ + gc0)     = q0;
    *(uint4*)(Pl + gr * D_ + gc0 + 8) = q1;
  }
}

// ---------------------------------------------------------------------------
// K1 fallback (r5): on-the-fly split proj (used if ws is small).
// ---------------------------------------------------------------------------
__global__ __launch_bounds__(256) void k_proj(const float* __restrict__ X,
                                              const float* __restrict__ W,
                                              const float* __restrict__ bias,
                                              unsigned short* __restrict__ Ph,
                                              unsigned short* __restrict__ Pl) {
  __shared__ __align__(16) unsigned short smem[4 * 128 * 32];
  unsigned short (*Ah)[32] = (unsigned short(*)[32])smem;
  unsigned short (*Al)[32] = (unsigned short(*)[32])(smem + 1 * 128 * 32);
  unsigned short (*Bh)[32] = (unsigned short(*)[32])(smem + 2 * 128 * 32);
  unsigned short (*Bl)[32] = (unsigned short(*)[32])(smem + 3 * 128 * 32);

  const int tid = threadIdx.x;
  const int swz = ((int)blockIdx.x % 8) * 96 + (int)blockIdx.x / 8;
  const int m0 = (swz / 6) * 128, n0 = (swz % 6) * 128;
  const int lane = tid & 63, wave = tid >> 6;
  const int wr = wave >> 1, wc = wave & 1;
  const int fr = lane & 15, kg = lane >> 4;
  f32x4 acc[4][4];
#pragma unroll
  for (int i = 0; i < 4; ++i)
#pragma unroll
    for (int j = 0; j < 4; ++j) acc[i][j] = 0;

  float4 av[4], bv[4];
#pragma unroll
  for (int p = 0; p < 4; ++p) {
    const int f = tid + p * 256, r = f >> 3, c = f & 7;
    av[p] = *(const float4*)(X + (size_t)(m0 + r) * D_ + c * 4);
    bv[p] = *(const float4*)(W + (size_t)(n0 + r) * D_ + c * 4);
  }

  for (int it = 0; it < D_ / 32; ++it) {
    __syncthreads();
#pragma unroll
    for (int p = 0; p < 4; ++p) {
      const int f = tid + p * 256, r = f >> 3, c = f & 7;
      {
        const float x0 = av[p].x, x1 = av[p].y, x2 = av[p].z, x3 = av[p].w;
        const unsigned short h0 = f2bf(x0), h1 = f2bf(x1), h2 = f2bf(x2), h3 = f2bf(x3);
        *(ushort4*)&Ah[r][c * 4] = make_ushort4(h0, h1, h2, h3);
        *(ushort4*)&Al[r][c * 4] = make_ushort4(f2bf(x0 - bf2f(h0)), f2bf(x1 - bf2f(h1)),
                                                f2bf(x2 - bf2f(h2)), f2bf(x3 - bf2f(h3)));
      }
      {
        const float x0 = bv[p].x, x1 = bv[p].y, x2 = bv[p].z, x3 = bv[p].w;
        const unsigned short h0 = f2bf(x0), h1 = f2bf(x1), h2 = f2bf(x2), h3 = f2bf(x3);
        *(ushort4*)&Bh[r][c * 4] = make_ushort4(h0, h1, h2, h3);
        *(ushort4*)&Bl[r][c * 4] = make_ushort4(f2bf(x0 - bf2f(h0)), f2bf(x1 - bf2f(h1)),
                                                f2bf(x2 - bf2f(h2)), f2bf(x3 - bf2f(h3)));
      }
    }
    __syncthreads();
    if (it + 1 < D_ / 32) {
      const int kk = (it + 1) * 32;
#pragma unroll
      for (int p = 0; p < 4; ++p) {
        const int f = tid + p * 256, r = f >> 3, c = f & 7;
        av[p] = *(const float4*)(X + (size_t)(m0 + r) * D_ + kk + c * 4);
        bv[p] = *(const float4*)(W + (size_t)(n0 + r) * D_ + kk + c * 4);
      }
    }
    bf16x8 fah[4], fal[4], fbh[4], fbl[4];
#pragma unroll
    for (int i = 0; i < 4; ++i) {
      fah[i] = *(const bf16x8*)&Ah[wr * 64 + i * 16 + fr][kg * 8];
      fal[i] = *(const bf16x8*)&Al[wr * 64 + i * 16 + fr][kg * 8];
      fbh[i] = *(const bf16x8*)&Bh[wc * 64 + i * 16 + fr][kg * 8];
      fbl[i] = *(const bf16x8*)&Bl[wc * 64 + i * 16 + fr][kg * 8];
    }
#pragma unroll
    for (int i = 0; i < 4; ++i)
#pragma unroll
      for (int j = 0; j < 4; ++j) {
        acc[i][j] = __builtin_amdgcn_mfma_f32_16x16x32_bf16(fah[i], fbh[j], acc[i][j], 0, 0, 0);
        acc[i][j] = __builtin_amdgcn_mfma_f32_16x16x32_bf16(fah[i], fbl[j], acc[i][j], 0, 0, 0);
        acc[i][j] = __builtin_amdgcn_mfma_f32_16x16x32_bf16(fal[i], fbh[j], acc[i][j], 0, 0, 0);
      }
  }

  unsigned short* scr = smem + wave * 2304;
  const int row = lane >> 2, seg = lane & 3;
  float bj[4];
#pragma unroll
  for (int j = 0; j < 4; ++j) bj[j] = bias[n0 + wc * 64 + j * 16 + fr];
  for (int i = 0; i < 4; ++i) {
    __syncthreads();
#pragma unroll
    for (int j = 0; j < 4; ++j)
#pragma unroll
      for (int r = 0; r < 4; ++r) {
        float v = fmaxf(acc[i][j][r] + bj[j], 0.f);
        const unsigned short h = f2bf(v);
        scr[(kg * 4 + r) * 72 + j * 16 + fr] = h;
        scr[1152 + (kg * 4 + r) * 72 + j * 16 + fr] = f2bf(v - bf2f(h));
      }
    __syncthreads();
    const size_t gr = (size_t)(m0 + wr * 64 + i * 16 + row);
    const int gc0 = n0 + wc * 64 + seg * 16;
    const uint4 h0 = *(const uint4*)&scr[row * 72 + seg * 16];
    const uint4 h1 = *(const uint4*)&scr[row * 72 + seg * 16 + 8];
    const uint4 q0 = *(const uint4*)&scr[1152 + row * 72 + seg * 16];
    const uint4 q1 = *(const uint4*)&scr[1152 + row * 72 + seg * 16 + 8];
    *(uint4*)(Ph + gr * D_ + gc0)     = h0;
    *(uint4*)(Ph + gr * D_ + gc0 + 8) = h1;
    *(uint4*)(Pl + gr * D_ + gc0)     = q0;
    *(uint4*)(Pl + gr * D_ + gc0 + 8) = q1;
  }
}

// ---------------------------------------------------------------------------
// K2 (MFMA): S = P·P^T, symmetric pairs, gload_lds double-buffered (r5).
// ---------------------------------------------------------------------------
__global__ __launch_bounds__(256) void k_scores(const unsigned short* __restrict__ Ph,
                                                const unsigned short* __restrict__ Pl,
                                                const int* __restrict__ mask,
                                                float* __restrict__ S) {
  __shared__ __align__(16) char smem[65536];

  const int tid = threadIdx.x;
  const int swz = ((int)blockIdx.x % 8) * 72 + (int)blockIdx.x / 8;
  const int bb = swz / 36;
  const int pr = swz % 36;
  int ti = 0;
  while ((ti + 1) * (ti + 2) / 2 <= pr) ++ti;
  const int tj = pr - ti * (ti + 1) / 2;
  const int l0 = ti * 128, m0 = tj * 128;
  const int lane = tid & 63, wave = tid >> 6;
  const int wr = wave >> 1, wc = wave & 1;
  const int fr = lane & 15, kg = lane >> 4;
  f32x4 acc[4][4];
#pragma unroll
  for (int i = 0; i < 4; ++i)
#pragma unroll
    for (int j = 0; j < 4; ++j) acc[i][j] = 0;

  const size_t arow0 = (size_t)bb * L_ + l0;
  const size_t brow0 = (size_t)bb * L_ + m0;

  stage_panel(Ph, Pl, arow0, 0, smem, wave, lane);
  stage_panel(Ph, Pl, brow0, 0, smem + 16384, wave, lane);
  __syncthreads();

  int cur = 0;
  for (int it = 0; it < D_ / 32; ++it) {
    char* cb = smem + cur * 32768;
    if (it + 1 < D_ / 32) {
      char* nb = smem + (cur ^ 1) * 32768;
      stage_panel(Ph, Pl, arow0, (it + 1) * 32, nb, wave, lane);
      stage_panel(Ph, Pl, brow0, (it + 1) * 32, nb + 16384, wave, lane);
    }
    bf16x8 fah[4], fal[4], fbh[4], fbl[4];
#pragma unroll
    for (int i = 0; i < 4; ++i) {
      const int ra = wr * 64 + i * 16 + fr;
      const int rb = wc * 64 + i * 16 + fr;
      fah[i] = ldsfrag(cb, ra, kg);
      fal[i] = ldsfrag(cb, ra, kg + 4);
      fbh[i] = ldsfrag(cb + 16384, rb, kg);
      fbl[i] = ldsfrag(cb + 16384, rb, kg + 4);
    }
#pragma unroll
    for (int i = 0; i < 4; ++i)
#pragma unroll
      for (int j = 0; j < 4; ++j) {
        acc[i][j] = __builtin_amdgcn_mfma_f32_16x16x32_bf16(fah[i], fbh[j], acc[i][j], 0, 0, 0);
        acc[i][j] = __builtin_amdgcn_mfma_f32_16x16x32_bf16(fah[i], fbl[j], acc[i][j], 0, 0, 0);
        acc[i][j] = __builtin_amdgcn_mfma_f32_16x16x32_bf16(fal[i], fbh[j], acc[i][j], 0, 0, 0);
      }
    __syncthreads();
    cur ^= 1;
  }

  float* scr = (float*)smem + wave * 1280;
  const int row = lane >> 2, seg = lane & 3;
  for (int i = 0; i < 4; ++i) {
    __syncthreads();
#pragma unroll
    for (int j = 0; j < 4; ++j)
#pragma unroll
      for (int r = 0; r < 4; ++r)
        scr[(kg * 4 + r) * 68 + j * 16 + fr] = acc[i][j][r];
    __syncthreads();
    const int gl = l0 + wr * 64 + i * 16 + row;
    const int gm0 = m0 + wc * 64 + seg * 16;
    const size_t sbase = ((size_t)bb * L_ + gl) * L_ + gm0;
#pragma unroll
    for (int t = 0; t < 4; ++t) {
      float4 o = *(const float4*)&scr[row * 68 + seg * 16 + t * 4];
      const int4 mk = *(const int4*)(mask + bb * L_ + gm0 + t * 4);
      float* op = (float*)&o;
      const int* mp = (const int*)&mk;
#pragma unroll
      for (int e = 0; e < 4; ++e) {
        const int gm = gm0 + t * 4 + e;
        if (gm == gl) op[e] = 0.f;
        if (mp[e]) op[e] = -INFINITY;
      }
      *(float4*)(S + sbase + t * 4) = o;
    }
  }

  if (ti != tj) {
    __syncthreads();
#pragma unroll
    for (int j = 0; j < 4; ++j) {
      const int mloc = wc * 64 + j * 16 + fr;
#pragma unroll
      for (int i = 0; i < 4; ++i) {
        const int slot = wr * 16 + i * 4 + kg;
        const int xs = slot ^ (mloc & 7);
        *(f32x4*)(smem + mloc * 512 + xs * 16) = acc[i][j];
      }
    }
    __syncthreads();
    const int mrow = tid >> 1, half = tid & 1;
    const size_t sbase = ((size_t)bb * L_ + m0 + mrow) * L_ + l0;
#pragma unroll
    for (int q = 0; q < 16; ++q) {
      const int slot = half * 16 + q;
      const int xs = slot ^ (mrow & 7);
      float4 o = *(const float4*)(smem + mrow * 512 + xs * 16);
      const int4 mk = *(const int4*)(mask + bb * L_ + l0 + slot * 4);
      if (mk.x) o.x = -INFINITY;
      if (mk.y) o.y = -INFINITY;
      if (mk.z) o.z = -INFINITY;
      if (mk.w) o.w = -INFINITY;
      *(float4*)(S + sbase + slot * 4) = o;
    }
  }
}

// ---------------------------------------------------------------------------
// K3: in-place row softmax; optionally also emits bf16 copy (for k_align2).
// ---------------------------------------------------------------------------
__global__ __launch_bounds__(256) void k_softmax(float* __restrict__ S,
                                                 unsigned short* __restrict__ a16) {
  const size_t row = blockIdx.x;
  float4* rp = (float4*)(S + row * L_);
  float4 v = rp[threadIdx.x];
  float mx = fmaxf(fmaxf(v.x, v.y), fmaxf(v.z, v.w));
#pragma unroll
  for (int o = 32; o > 0; o >>= 1) mx = fmaxf(mx, __shfl_xor(mx, o));
  __shared__ float rmax[4], rsum[4];
  const int wv = threadIdx.x >> 6, ln = threadIdx.x & 63;
  if (ln == 0) rmax[wv] = mx;
  __syncthreads();
  mx = fmaxf(fmaxf(rmax[0], rmax[1]), fmaxf(rmax[2], rmax[3]));
  float4 e;
  e.x = __expf(v.x - mx); e.y = __expf(v.y - mx);
  e.z = __expf(v.z - mx); e.w = __expf(v.w - mx);
  float s = (e.x + e.y) + (e.z + e.w);
#pragma unroll
  for (int o = 32; o > 0; o >>= 1) s += __shfl_xor(s, o);
  if (ln == 0) rsum[wv] = s;
  __syncthreads();
  s = (rsum[0] + rsum[1]) + (rsum[2] + rsum[3]);
  const float inv = 1.0f / s;
  e.x *= inv; e.y *= inv; e.z *= inv; e.w *= inv;
  rp[threadIdx.x] = e;
  if (a16) {
    *(ushort4*)(a16 + row * L_ + threadIdx.x * 4) =
        make_ushort4(f2bf(e.x), f2bf(e.y), f2bf(e.z), f2bf(e.w));
  }
}

// ---------------------------------------------------------------------------
// K5 v2 (MFMA): align = alpha16·Xt^T per batch (bf16 x bf16).
// ---------------------------------------------------------------------------
__global__ __launch_bounds__(256) void k_align2(const unsigned short* __restrict__ A16,
                                                const unsigned short* __restrict__ Xt,
                                                float* __restrict__ O) {
  __shared__ __align__(16) char smem[65536];  // 2 x (A 16KB + B 16KB)
  const int tid = threadIdx.x;
  const int swz = ((int)blockIdx.x % 8) * 96 + (int)blockIdx.x / 8;
  const int bb = swz / 48;
  const int l0 = ((swz / 6) % 8) * 128;
  const int n0 = (swz % 6) * 128;
  const int lane = tid & 63, wave = tid >> 6;
  const int wr = wave >> 1, wc = wave & 1;
  const int fr = lane & 15, kg = lane >> 4;
  f32x4 acc[4][4];
#pragma unroll
  for (int i = 0; i < 4; ++i)
#pragma unroll
    for (int j = 0; j < 4; ++j) acc[i][j] = 0;

  const unsigned short* a0 = A16 + ((size_t)bb * L_ + l0) * L_;
  const unsigned short* b0 = Xt + ((size_t)bb * D_ + n0) * L_;

  stage_panel1(a0, L_, smem, wave, lane);
  stage_panel1(b0, L_, smem + 16384, wave, lane);
  __syncthreads();

  int cur = 0;
  for (int it = 0; it < L_ / 64; ++it) {
    char* cb = smem + cur * 32768;
    if (it + 1 < L_ / 64) {
      char* nb = smem + (cur ^ 1) * 32768;
      stage_panel1(a0 + (it + 1) * 64, L_, nb, wave, lane);
      stage_panel1(b0 + (it + 1) * 64, L_, nb + 16384, wave, lane);
    }
    bf16x8 fa[2][4], fb[2][4];
#pragma unroll
    for (int i = 0; i < 4; ++i) {
      const int ra = wr * 64 + i * 16 + fr;
      const int rb = wc * 64 + i * 16 + fr;
#pragma unroll
      for (int ks = 0; ks < 2; ++ks) {
        fa[ks][i] = ldsfrag(cb, ra, ks * 4 + kg);
        fb[ks][i] = ldsfrag(cb + 16384, rb, ks * 4 + kg);
      }
    }
#pragma unroll
    for (int ks = 0; ks < 2; ++ks)
#pragma unroll
      for (int i = 0; i < 4; ++i)
#pragma unroll
        for (int j = 0; j < 4; ++j)
          acc[i][j] = __builtin_amdgcn_mfma_f32_16x16x32_bf16(fa[ks][i], fb[ks][j],
                                                              acc[i][j], 0, 0, 0);
    __syncthreads();
    cur ^= 1;
  }

  float* scr = (float*)smem + wave * 1280;
  const int row = lane >> 2, seg = lane & 3;
  for (int i = 0; i < 4; ++i) {
    __syncthreads();
#pragma unroll
    for (int j = 0; j < 4; ++j)
#pragma unroll
      for (int r = 0; r < 4; ++r)
        scr[(kg * 4 + r) * 68 + j * 16 + fr] = acc[i][j][r];
    __syncthreads();
    const int gl = l0 + wr * 64 + i * 16 + row;
    const int gc0 = n0 + wc * 64 + seg * 16;
    const size_t obase = ((size_t)bb * L_ + gl) * D_ + gc0;
#pragma unroll
    for (int t = 0; t < 4; ++t) {
      const float4 o = *(const float4*)&scr[row * 68 + seg * 16 + t * 4];
      *(float4*)(O + obase + t * 4) = o;
    }
  }
}

// ---------------------------------------------------------------------------
// K5 fallback (r6): align = alpha(f32)·Xt^T with in-staging conversion.
// ---------------------------------------------------------------------------
__global__ __launch_bounds__(256) void k_align(const float* __restrict__ A,
                                               const unsigned short* __restrict__ Xt,
                                               float* __restrict__ O) {
  __shared__ __align__(16) unsigned short smem[2 * 128 * 32];
  __shared__ __align__(16) float scr_s[4 * 1104];
  unsigned short (*Ab)[32] = (unsigned short(*)[32])smem;
  unsigned short (*Bb)[32] = (unsigned short(*)[32])(smem + 128 * 32);

  const int tid = threadIdx.x;
  const int swz = ((int)blockIdx.x % 8) * 96 + (int)blockIdx.x / 8;
  const int bb = swz / 48;
  const int l0 = ((swz / 6) % 8) * 128;
  const int n0 = (swz % 6) * 128;
  const int lane = tid & 63, wave = tid >> 6;
  const int wr = wave >> 1, wc = wave & 1;
  const int fr = lane & 15, kg = lane >> 4;
  f32x4 acc[4][4];
#pragma unroll
  for (int i = 0; i < 4; ++i)
#pragma unroll
    for (int j = 0; j < 4; ++j) acc[i][j] = 0;

  float4 av[4];
  uint4 bv[2];
#pragma unroll
  for (int p = 0; p < 4; ++p) {
    const int f = tid + p * 256, r = f >> 3, c = f & 7;
    av[p] = *(const float4*)(A + ((size_t)bb * L_ + l0 + r) * L_ + c * 4);
  }
#pragma unroll
  for (int p = 0; p < 2; ++p) {
    const int f = tid + p * 256, r = f >> 2, sl = f & 3;
    bv[p] = *(const uint4*)(Xt + ((size_t)bb * D_ + n0 + r) * L_ + sl * 8);
  }

  for (int it = 0; it < L_ / 32; ++it) {
    __syncthreads();
#pragma unroll
    for (int p = 0; p < 4; ++p) {
      const int f = tid + p * 256, r = f >> 3, c = f & 7;
      *(ushort4*)&Ab[r][c * 4] = make_ushort4(f2bf(av[p].x), f2bf(av[p].y),
                                              f2bf(av[p].z), f2bf(av[p].w));
    }
#pragma unroll
    for (int p = 0; p < 2; ++p) {
      const int f = tid + p * 256, r = f >> 2, sl = f & 3;
      *(uint4*)&Bb[r][sl * 8] = bv[p];
    }
    __syncthreads();
    if (it + 1 < L_ / 32) {
      const int kk = (it + 1) * 32;
#pragma unroll
      for (int p = 0; p < 4; ++p) {
        const int f = tid + p * 256, r = f >> 3, c = f & 7;
        av[p] = *(const float4*)(A + ((size_t)bb * L_ + l0 + r) * L_ + kk + c * 4);
      }
#pragma unroll
      for (int p = 0; p < 2; ++p) {
        const int f = tid + p * 256, r = f >> 2, sl = f & 3;
        bv[p] = *(const uint4*)(Xt + ((size_t)bb * D_ + n0 + r) * L_ + kk + sl * 8);
      }
    }
    bf16x8 fa[4], fb[4];
#pragma unroll
    for (int i = 0; i < 4; ++i) {
      fa[i] = *(const bf16x8*)&Ab[wr * 64 + i * 16 + fr][kg * 8];
      fb[i] = *(const bf16x8*)&Bb[wc * 64 + i * 16 + fr][kg * 8];
    }
#pragma unroll
    for (int i = 0; i < 4; ++i)
#pragma unroll
      for (int j = 0; j < 4; ++j)
        acc[i][j] = __builtin_amdgcn_mfma_f32_16x16x32_bf16(fa[i], fb[j], acc[i][j], 0, 0, 0);
  }

  float* scr = scr_s + wave * 1104;
  const int row = lane >> 2, seg = lane & 3;
  for (int i = 0; i < 4; ++i) {
    __syncthreads();
#pragma unroll
    for (int j = 0; j < 4; ++j)
#pragma unroll
      for (int r = 0; r < 4; ++r)
        scr[(kg * 4 + r) * 68 + j * 16 + fr] = acc[i][j][r];
    __syncthreads();
    const int gl = l0 + wr * 64 + i * 16 + row;
    const int gc0 = n0 + wc * 64 + seg * 16;
    const size_t obase = ((size_t)bb * L_ + gl) * D_ + gc0;
#pragma unroll
    for (int t = 0; t < 4; ++t) {
      const float4 o = *(const float4*)&scr[row * 68 + seg * 16 + t * 4];
      *(float4*)(O + obase + t * 4) = o;
    }
  }
}

// ---------------------------------------------------------------------------
extern "C" void kernel_launch(void* const* d_in, const int* in_sizes, int n_in,
                              void* d_out, int out_size, void* d_ws, size_t ws_size,
                              hipStream_t stream) {
  const float* X    = (const float*)d_in[0];  // [B,L,D]
  const void*  mraw = d_in[1];                // [B,L] bool/int
  const float* W    = (const float*)d_in[2];  // [D,D]
  const float* bias = (const float*)d_in[3];  // [D]

  float* out   = (float*)d_out;
  float* align = out;                          // B*L*D fp32 (48MB)
  float* alpha = out + (size_t)B_ * L_ * D_;   // B*L*L fp32 (64MB)

  const size_t NX = (size_t)B_ * L_ * D_;   // 12,582,912
  const size_t NW = (size_t)D_ * D_;        // 589,824
  const size_t NA = (size_t)B_ * L_ * L_;   // 16,777,216

  int* maskC = (int*)d_ws;                                      // 64 KB
  unsigned short* Xt = (unsigned short*)((char*)d_ws + 65536);  // 25.17 MB

  const size_t offWh = 65536 + NX * 2;
  const size_t offWl = offWh + NW * 2;
  const size_t offPl = offWl + NW * 2;
  const size_t needProj = offPl + NX * 2;   // ~52.8 MB
  const size_t offA16 = offWh;
  const size_t needA16 = offA16 + NA * 2;   // ~58.9 MB

  hipLaunchKernelGGL(k_mask, dim3(1), dim3(256), 0, stream, mraw, maskC);

  unsigned short* Ph;
  unsigned short* Pl;
  if (ws_size >= needProj) {
    unsigned short* Xh = (unsigned short*)alpha;
    unsigned short* Xl = Xh + NX;
    unsigned short* Wh = (unsigned short*)((char*)d_ws + offWh);
    unsigned short* Wl = (unsigned short*)((char*)d_ws + offWl);
    Ph = (unsigned short*)align;
    Pl = (unsigned short*)((char*)d_ws + offPl);
    hipLaunchKernelGGL(k_prep, dim3(D_ / 64, L_ / 64, B_), dim3(256), 0, stream,
                       X, Xh, Xl, Xt);
    hipLaunchKernelGGL(k_split, dim3((int)(NW / 8 / 256)), dim3(256), 0, stream,
                       W, Wh, Wl, (int)(NW / 8));
    hipLaunchKernelGGL(k_proj2, dim3(768), dim3(256), 0, stream,
                       Xh, Xl, Wh, Wl, bias, Ph, Pl);
  } else {
    Ph = (unsigned short*)align;
    Pl = Ph + NX;
    hipLaunchKernelGGL(k_prep, dim3(D_ / 64, L_ / 64, B_), dim3(256), 0, stream,
                       X, (unsigned short*)alpha, (unsigned short*)alpha + NX, Xt);
    hipLaunchKernelGGL(k_proj, dim3(768), dim3(256), 0, stream, X, W, bias, Ph, Pl);
  }

  hipLaunchKernelGGL(k_scores, dim3(576), dim3(256), 0, stream, Ph, Pl, maskC, alpha);

  if (ws_size >= needA16) {
    unsigned short* A16 = (unsigned short*)((char*)d_ws + offA16);
    hipLaunchKernelGGL(k_softmax, dim3(B_ * L_), dim3(256), 0, stream, alpha, A16);
    hipLaunchKernelGGL(k_align2, dim3(768), dim3(256), 0, stream, A16, Xt, align);
  } else {
    hipLaunchKernelGGL(k_softmax, dim3(B_ * L_), dim3(256), 0, stream, alpha,
                       (unsigned short*)nullptr);
    hipLaunchKernelGGL(k_align, dim3(768), dim3(256), 0, stream, alpha, Xt, align);
  }
}

// Round 9
// 226.171 us; speedup vs baseline: 1.3856x; 1.1632x over previous
//
#include <hip/hip_runtime.h>
#include <math.h>

// Problem constants
#define B_ 16
#define L_ 1024
#define D_ 768

typedef short bf16x8 __attribute__((ext_vector_type(8)));
typedef _Float16 half8 __attribute__((ext_vector_type(8)));
typedef float f32x4 __attribute__((ext_vector_type(4)));

// round-to-nearest-even f32 -> bf16 (bit trick; inputs never NaN)
__device__ __forceinline__ unsigned short f2bf(float x) {
  unsigned u = __float_as_uint(x);
  u = (u + 0x7FFFu + ((u >> 16) & 1u)) >> 16;
  return (unsigned short)u;
}
__device__ __forceinline__ float bf2f(unsigned short h) {
  return __uint_as_float(((unsigned)h) << 16);
}
// f32 -> fp16 bits (RTN)
__device__ __forceinline__ unsigned short f2h(float x) {
  union { _Float16 h; unsigned short u; } v;
  v.h = (_Float16)x;
  return v.u;
}

// ---------------------------------------------------------------------------
// K0: canonicalize mask (bool-bytes / int32 / int64 auto-detect). 1 = padding.
// ---------------------------------------------------------------------------
__global__ __launch_bounds__(256) void k_mask(const void* __restrict__ mraw,
                                              int* __restrict__ canon) {
  __shared__ int flags[2];
  if (threadIdx.x < 2) flags[threadIdx.x] = 0;
  __syncthreads();
  const unsigned* m32 = (const unsigned*)mraw;
  int gt = 0, oddnz = 0;
  for (int i = threadIdx.x; i < 4096; i += 256) {
    unsigned v = m32[i];
    if (v > 1u) gt = 1;
    if ((i & 1) && v != 0u) oddnz = 1;
  }
  if (gt) atomicOr(&flags[0], 1);
  if (oddnz) atomicOr(&flags[1], 1);
  __syncthreads();
  const int mode = flags[0] ? 0 : (flags[1] ? 1 : 2);  // 0=u8, 1=i32, 2=i64
  for (int i = threadIdx.x; i < B_ * L_; i += 256) {
    int v;
    if (mode == 0)      v = ((const unsigned char*)mraw)[i];
    else if (mode == 1) v = ((const int*)mraw)[i];
    else                v = (int)(((const long long*)mraw)[i] != 0);
    canon[i] = (v != 0);
  }
}

// ---------------------------------------------------------------------------
// K-prep: ONE pass over X producing Xh, Xl (hi/lo bf16, X layout, for proj)
// and Xt (transposed [b][d][m]; fp16 when xt16=1, else bf16).
// ---------------------------------------------------------------------------
__global__ __launch_bounds__(256) void k_prep(const float* __restrict__ X,
                                              unsigned short* __restrict__ Xh,
                                              unsigned short* __restrict__ Xl,
                                              unsigned short* __restrict__ Xt,
                                              int xt16) {
  __shared__ unsigned short t16[64][66];
  const int b = blockIdx.z;
  const int d0 = blockIdx.x * 64, m0 = blockIdx.y * 64;
  const int dd = threadIdx.x & 63, mq = threadIdx.x >> 6;
#pragma unroll
  for (int i = 0; i < 16; ++i) {
    const int m = mq * 16 + i;
    const size_t gidx = ((size_t)b * L_ + m0 + m) * D_ + d0 + dd;
    const float x = X[gidx];
    const unsigned short h = f2bf(x);
    Xh[gidx] = h;
    Xl[gidx] = f2bf(x - bf2f(h));
    t16[dd][m] = xt16 ? f2h(x) : h;
  }
  __syncthreads();
  const int mm = threadIdx.x & 63, dq = threadIdx.x >> 6;
#pragma unroll
  for (int i = 0; i < 16; ++i) {
    const int d = dq * 16 + i;
    Xt[((size_t)b * D_ + d0 + d) * L_ + m0 + mm] = t16[d][mm];
  }
}

// ---------------------------------------------------------------------------
// K-split: elementwise f32 -> bf16 hi/lo pair (used for W only).
// ---------------------------------------------------------------------------
__global__ __launch_bounds__(256) void k_split(const float* __restrict__ src,
                                               unsigned short* __restrict__ hi,
                                               unsigned short* __restrict__ lo,
                                               int n8) {
  const int i = blockIdx.x * 256 + threadIdx.x;
  if (i >= n8) return;
  const float4 a = *(const float4*)(src + (size_t)i * 8);
  const float4 b = *(const float4*)(src + (size_t)i * 8 + 4);
  const float xs[8] = {a.x, a.y, a.z, a.w, b.x, b.y, b.z, b.w};
  unsigned short h[8], l[8];
#pragma unroll
  for (int e = 0; e < 8; ++e) {
    h[e] = f2bf(xs[e]);
    l[e] = f2bf(xs[e] - bf2f(h[e]));
  }
  *(ushort4*)(hi + (size_t)i * 8)     = make_ushort4(h[0], h[1], h[2], h[3]);
  *(ushort4*)(hi + (size_t)i * 8 + 4) = make_ushort4(h[4], h[5], h[6], h[7]);
  *(ushort4*)(lo + (size_t)i * 8)     = make_ushort4(l[0], l[1], l[2], l[3]);
  *(ushort4*)(lo + (size_t)i * 8 + 4) = make_ushort4(l[4], l[5], l[6], l[7]);
}

// ---------------------------------------------------------------------------
// Staging helpers: 128-row x 128B LDS panels, 16B slots XOR-swizzled via
// pre-swizzled global source (slot xs = s ^ (row&7)).
// ---------------------------------------------------------------------------
__device__ __forceinline__ void stage_panel(const unsigned short* __restrict__ ph,
                                            const unsigned short* __restrict__ pl,
                                            size_t grow0, int kk,
                                            char* ldsbase, int wave, int lane) {
#pragma unroll
  for (int q = 0; q < 4; ++q) {
    const int s = wave * 4 + q;              // 1KB span: 8 rows x 128B
    const int row = s * 8 + (lane >> 3);
    const int xs = (lane & 7) ^ (row & 7);   // pre-swizzled source slot
    const unsigned short* src = (xs & 4) ? pl : ph;
    const unsigned short* g = src + (grow0 + row) * D_ + kk + (xs & 3) * 8;
    __builtin_amdgcn_global_load_lds(
        (const __attribute__((address_space(1))) void*)g,
        (__attribute__((address_space(3))) void*)(ldsbase + s * 1024),
        16, 0, 0);
  }
}

__device__ __forceinline__ void stage_panel1(const unsigned short* __restrict__ g0,
                                             size_t rstride,
                                             char* ldsbase, int wave, int lane) {
#pragma unroll
  for (int q = 0; q < 4; ++q) {
    const int s = wave * 4 + q;
    const int row = s * 8 + (lane >> 3);
    const int xs = (lane & 7) ^ (row & 7);
    const unsigned short* g = g0 + (size_t)row * rstride + xs * 8;
    __builtin_amdgcn_global_load_lds(
        (const __attribute__((address_space(1))) void*)g,
        (__attribute__((address_space(3))) void*)(ldsbase + s * 1024),
        16, 0, 0);
  }
}

__device__ __forceinline__ bf16x8 ldsfrag(const char* base, int row, int g) {
  return *(const bf16x8*)(base + row * 128 + ((g ^ (row & 7)) * 16));
}
__device__ __forceinline__ half8 ldsfrag_h(const char* base, int row, int g) {
  return *(const half8*)(base + row * 128 + ((g ^ (row & 7)) * 16));
}

// ---------------------------------------------------------------------------
// K1 v3 (MFMA): P = relu(Xs·Ws^T + b), 3-pass bf16 hi/lo inputs (fp32-class
// accuracy), output ONE fp16 array Pf. XCD-local m-outer/n-inner mapping.
// ---------------------------------------------------------------------------
__global__ __launch_bounds__(256) void k_proj2(const unsigned short* __restrict__ Xh,
                                               const unsigned short* __restrict__ Xl,
                                               const unsigned short* __restrict__ Wh,
                                               const unsigned short* __restrict__ Wl,
                                               const float* __restrict__ bias,
                                               unsigned short* __restrict__ Pf) {
  __shared__ __align__(16) char smem[49152];  // A: 2x16KB @0, B: 16KB @32KB
  const int tid = threadIdx.x;
  const int xcd = (int)blockIdx.x & 7;
  const int li  = (int)blockIdx.x >> 3;        // 0..95 within XCD
  const int m0 = (xcd * 16 + li / 6) * 128;    // 16 m-tiles per XCD, outer
  const int n0 = (li % 6) * 128;               // 6 n-tiles, inner
  const int lane = tid & 63, wave = tid >> 6;
  const int wr = wave >> 1, wc = wave & 1;
  const int fr = lane & 15, kg = lane >> 4;
  f32x4 acc[4][4];
#pragma unroll
  for (int i = 0; i < 4; ++i)
#pragma unroll
    for (int j = 0; j < 4; ++j) acc[i][j] = 0;

  stage_panel(Xh, Xl, (size_t)m0, 0, smem, wave, lane);
  stage_panel(Wh, Wl, (size_t)n0, 0, smem + 32768, wave, lane);
  __syncthreads();

  int cur = 0;
  for (int it = 0; it < D_ / 32; ++it) {
    const char* ab = smem + cur * 16384;
    const char* bb = smem + 32768;
    bf16x8 fah[4], fal[4], fbh[4], fbl[4];
#pragma unroll
    for (int i = 0; i < 4; ++i) {
      const int ra = wr * 64 + i * 16 + fr;
      const int rb = wc * 64 + i * 16 + fr;
      fah[i] = ldsfrag(ab, ra, kg);
      fal[i] = ldsfrag(ab, ra, kg + 4);
      fbh[i] = ldsfrag(bb, rb, kg);
      fbl[i] = ldsfrag(bb, rb, kg + 4);
    }
    __syncthreads();
    if (it + 1 < D_ / 32) {
      stage_panel(Xh, Xl, (size_t)m0, (it + 1) * 32, smem + (cur ^ 1) * 16384, wave, lane);
      stage_panel(Wh, Wl, (size_t)n0, (it + 1) * 32, smem + 32768, wave, lane);
    }
#pragma unroll
    for (int i = 0; i < 4; ++i)
#pragma unroll
      for (int j = 0; j < 4; ++j) {
        acc[i][j] = __builtin_amdgcn_mfma_f32_16x16x32_bf16(fah[i], fbh[j], acc[i][j], 0, 0, 0);
        acc[i][j] = __builtin_amdgcn_mfma_f32_16x16x32_bf16(fah[i], fbl[j], acc[i][j], 0, 0, 0);
        acc[i][j] = __builtin_amdgcn_mfma_f32_16x16x32_bf16(fal[i], fbh[j], acc[i][j], 0, 0, 0);
      }
    __syncthreads();
    cur ^= 1;
  }

  // Epilogue: bias+relu -> fp16; LDS transpose; 2x uint4 per lane.
  unsigned short* scr = (unsigned short*)smem + wave * 1152;  // [16][72]/wave
  const int row = lane >> 2, seg = lane & 3;
  float bj[4];
#pragma unroll
  for (int j = 0; j < 4; ++j) bj[j] = bias[n0 + wc * 64 + j * 16 + fr];
  for (int i = 0; i < 4; ++i) {
    __syncthreads();
#pragma unroll
    for (int j = 0; j < 4; ++j)
#pragma unroll
      for (int r = 0; r < 4; ++r)
        scr[(kg * 4 + r) * 72 + j * 16 + fr] = f2h(fmaxf(acc[i][j][r] + bj[j], 0.f));
    __syncthreads();
    const size_t gr = (size_t)(m0 + wr * 64 + i * 16 + row);
    const int gc0 = n0 + wc * 64 + seg * 16;
    const uint4 h0 = *(const uint4*)&scr[row * 72 + seg * 16];
    const uint4 h1 = *(const uint4*)&scr[row * 72 + seg * 16 + 8];
    *(uint4*)(Pf + gr * D_ + gc0)     = h0;
    *(uint4*)(Pf + gr * D_ + gc0 + 8) = h1;
  }
}

// ---------------------------------------------------------------------------
// K1 fallback (r5): on-the-fly split proj -> bf16 Ph/Pl (used if ws small).
// ---------------------------------------------------------------------------
__global__ __launch_bounds__(256) void k_proj(const float* __restrict__ X,
                                              const float* __restrict__ W,
                                              const float* __restrict__ bias,
                                              unsigned short* __restrict__ Ph,
                                              unsigned short* __restrict__ Pl) {
  __shared__ __align__(16) unsigned short smem[4 * 128 * 32];
  unsigned short (*Ah)[32] = (unsigned short(*)[32])smem;
  unsigned short (*Al)[32] = (unsigned short(*)[32])(smem + 1 * 128 * 32);
  unsigned short (*Bh)[32] = (unsigned short(*)[32])(smem + 2 * 128 * 32);
  unsigned short (*Bl)[32] = (unsigned short(*)[32])(smem + 3 * 128 * 32);

  const int tid = threadIdx.x;
  const int swz = ((int)blockIdx.x % 8) * 96 + (int)blockIdx.x / 8;
  const int m0 = (swz / 6) * 128, n0 = (swz % 6) * 128;
  const int lane = tid & 63, wave = tid >> 6;
  const int wr = wave >> 1, wc = wave & 1;
  const int fr = lane & 15, kg = lane >> 4;
  f32x4 acc[4][4];
#pragma unroll
  for (int i = 0; i < 4; ++i)
#pragma unroll
    for (int j = 0; j < 4; ++j) acc[i][j] = 0;

  float4 av[4], bv[4];
#pragma unroll
  for (int p = 0; p < 4; ++p) {
    const int f = tid + p * 256, r = f >> 3, c = f & 7;
    av[p] = *(const float4*)(X + (size_t)(m0 + r) * D_ + c * 4);
    bv[p] = *(const float4*)(W + (size_t)(n0 + r) * D_ + c * 4);
  }

  for (int it = 0; it < D_ / 32; ++it) {
    __syncthreads();
#pragma unroll
    for (int p = 0; p < 4; ++p) {
      const int f = tid + p * 256, r = f >> 3, c = f & 7;
      {
        const float x0 = av[p].x, x1 = av[p].y, x2 = av[p].z, x3 = av[p].w;
        const unsigned short h0 = f2bf(x0), h1 = f2bf(x1), h2 = f2bf(x2), h3 = f2bf(x3);
        *(ushort4*)&Ah[r][c * 4] = make_ushort4(h0, h1, h2, h3);
        *(ushort4*)&Al[r][c * 4] = make_ushort4(f2bf(x0 - bf2f(h0)), f2bf(x1 - bf2f(h1)),
                                                f2bf(x2 - bf2f(h2)), f2bf(x3 - bf2f(h3)));
      }
      {
        const float x0 = bv[p].x, x1 = bv[p].y, x2 = bv[p].z, x3 = bv[p].w;
        const unsigned short h0 = f2bf(x0), h1 = f2bf(x1), h2 = f2bf(x2), h3 = f2bf(x3);
        *(ushort4*)&Bh[r][c * 4] = make_ushort4(h0, h1, h2, h3);
        *(ushort4*)&Bl[r][c * 4] = make_ushort4(f2bf(x0 - bf2f(h0)), f2bf(x1 - bf2f(h1)),
                                                f2bf(x2 - bf2f(h2)), f2bf(x3 - bf2f(h3)));
      }
    }
    __syncthreads();
    if (it + 1 < D_ / 32) {
      const int kk = (it + 1) * 32;
#pragma unroll
      for (int p = 0; p < 4; ++p) {
        const int f = tid + p * 256, r = f >> 3, c = f & 7;
        av[p] = *(const float4*)(X + (size_t)(m0 + r) * D_ + kk + c * 4);
        bv[p] = *(const float4*)(W + (size_t)(n0 + r) * D_ + kk + c * 4);
      }
    }
    bf16x8 fah[4], fal[4], fbh[4], fbl[4];
#pragma unroll
    for (int i = 0; i < 4; ++i) {
      fah[i] = *(const bf16x8*)&Ah[wr * 64 + i * 16 + fr][kg * 8];
      fal[i] = *(const bf16x8*)&Al[wr * 64 + i * 16 + fr][kg * 8];
      fbh[i] = *(const bf16x8*)&Bh[wc * 64 + i * 16 + fr][kg * 8];
      fbl[i] = *(const bf16x8*)&Bl[wc * 64 + i * 16 + fr][kg * 8];
    }
#pragma unroll
    for (int i = 0; i < 4; ++i)
#pragma unroll
      for (int j = 0; j < 4; ++j) {
        acc[i][j] = __builtin_amdgcn_mfma_f32_16x16x32_bf16(fah[i], fbh[j], acc[i][j], 0, 0, 0);
        acc[i][j] = __builtin_amdgcn_mfma_f32_16x16x32_bf16(fah[i], fbl[j], acc[i][j], 0, 0, 0);
        acc[i][j] = __builtin_amdgcn_mfma_f32_16x16x32_bf16(fal[i], fbh[j], acc[i][j], 0, 0, 0);
      }
  }

  unsigned short* scr = smem + wave * 2304;
  const int row = lane >> 2, seg = lane & 3;
  float bj[4];
#pragma unroll
  for (int j = 0; j < 4; ++j) bj[j] = bias[n0 + wc * 64 + j * 16 + fr];
  for (int i = 0; i < 4; ++i) {
    __syncthreads();
#pragma unroll
    for (int j = 0; j < 4; ++j)
#pragma unroll
      for (int r = 0; r < 4; ++r) {
        float v = fmaxf(acc[i][j][r] + bj[j], 0.f);
        const unsigned short h = f2bf(v);
        scr[(kg * 4 + r) * 72 + j * 16 + fr] = h;
        scr[1152 + (kg * 4 + r) * 72 + j * 16 + fr] = f2bf(v - bf2f(h));
      }
    __syncthreads();
    const size_t gr = (size_t)(m0 + wr * 64 + i * 16 + row);
    const int gc0 = n0 + wc * 64 + seg * 16;
    const uint4 h0 = *(const uint4*)&scr[row * 72 + seg * 16];
    const uint4 h1 = *(const uint4*)&scr[row * 72 + seg * 16 + 8];
    const uint4 q0 = *(const uint4*)&scr[1152 + row * 72 + seg * 16];
    const uint4 q1 = *(const uint4*)&scr[1152 + row * 72 + seg * 16 + 8];
    *(uint4*)(Ph + gr * D_ + gc0)     = h0;
    *(uint4*)(Ph + gr * D_ + gc0 + 8) = h1;
    *(uint4*)(Pl + gr * D_ + gc0)     = q0;
    *(uint4*)(Pl + gr * D_ + gc0 + 8) = q1;
  }
}

// ---------------------------------------------------------------------------
// K2 v2 (MFMA): S = Pf·Pf^T, SINGLE fp16 pass (MFMA accumulates exactly in
// f32; input rounding error ~2e-3 on scores -> <1% alpha rel error).
// Symmetric pairs, K-tile 64, 12 iters, double-buffered gload_lds.
// ---------------------------------------------------------------------------
__global__ __launch_bounds__(256) void k_scores(const unsigned short* __restrict__ Pf,
                                                const int* __restrict__ mask,
                                                float* __restrict__ S) {
  __shared__ __align__(16) char smem[65536];

  const int tid = threadIdx.x;
  const int swz = ((int)blockIdx.x % 8) * 72 + (int)blockIdx.x / 8;
  const int bb = swz / 36;
  const int pr = swz % 36;
  int ti = 0;
  while ((ti + 1) * (ti + 2) / 2 <= pr) ++ti;
  const int tj = pr - ti * (ti + 1) / 2;
  const int l0 = ti * 128, m0 = tj * 128;
  const int lane = tid & 63, wave = tid >> 6;
  const int wr = wave >> 1, wc = wave & 1;
  const int fr = lane & 15, kg = lane >> 4;
  f32x4 acc[4][4];
#pragma unroll
  for (int i = 0; i < 4; ++i)
#pragma unroll
    for (int j = 0; j < 4; ++j) acc[i][j] = 0;

  const unsigned short* a0 = Pf + ((size_t)bb * L_ + l0) * D_;
  const unsigned short* b0 = Pf + ((size_t)bb * L_ + m0) * D_;

  stage_panel1(a0, D_, smem, wave, lane);
  stage_panel1(b0, D_, smem + 16384, wave, lane);
  __syncthreads();

  int cur = 0;
  for (int it = 0; it < D_ / 64; ++it) {
    char* cb = smem + cur * 32768;
    if (it + 1 < D_ / 64) {
      char* nb = smem + (cur ^ 1) * 32768;
      stage_panel1(a0 + (it + 1) * 64, D_, nb, wave, lane);
      stage_panel1(b0 + (it + 1) * 64, D_, nb + 16384, wave, lane);
    }
    half8 fa[2][4], fb[2][4];
#pragma unroll
    for (int i = 0; i < 4; ++i) {
      const int ra = wr * 64 + i * 16 + fr;
      const int rb = wc * 64 + i * 16 + fr;
#pragma unroll
      for (int ks = 0; ks < 2; ++ks) {
        fa[ks][i] = ldsfrag_h(cb, ra, ks * 4 + kg);
        fb[ks][i] = ldsfrag_h(cb + 16384, rb, ks * 4 + kg);
      }
    }
#pragma unroll
    for (int ks = 0; ks < 2; ++ks)
#pragma unroll
      for (int i = 0; i < 4; ++i)
#pragma unroll
        for (int j = 0; j < 4; ++j)
          acc[i][j] = __builtin_amdgcn_mfma_f32_16x16x32_f16(fa[ks][i], fb[ks][j],
                                                             acc[i][j], 0, 0, 0);
    __syncthreads();
    cur ^= 1;
  }

  // ---- main tile epilogue: LDS transpose -> 64B/lane coalesced rows ----
  float* scr = (float*)smem + wave * 1280;
  const int row = lane >> 2, seg = lane & 3;
  for (int i = 0; i < 4; ++i) {
    __syncthreads();
#pragma unroll
    for (int j = 0; j < 4; ++j)
#pragma unroll
      for (int r = 0; r < 4; ++r)
        scr[(kg * 4 + r) * 68 + j * 16 + fr] = acc[i][j][r];
    __syncthreads();
    const int gl = l0 + wr * 64 + i * 16 + row;
    const int gm0 = m0 + wc * 64 + seg * 16;
    const size_t sbase = ((size_t)bb * L_ + gl) * L_ + gm0;
#pragma unroll
    for (int t = 0; t < 4; ++t) {
      float4 o = *(const float4*)&scr[row * 68 + seg * 16 + t * 4];
      const int4 mk = *(const int4*)(mask + bb * L_ + gm0 + t * 4);
      float* op = (float*)&o;
      const int* mp = (const int*)&mk;
#pragma unroll
      for (int e = 0; e < 4; ++e) {
        const int gm = gm0 + t * 4 + e;
        if (gm == gl) op[e] = 0.f;
        if (mp[e]) op[e] = -INFINITY;
      }
      *(float4*)(S + sbase + t * 4) = o;
    }
  }

  // ---- mirror tile: full 128x128 staged in LDS, 512B-contiguous rows ----
  if (ti != tj) {
    __syncthreads();
#pragma unroll
    for (int j = 0; j < 4; ++j) {
      const int mloc = wc * 64 + j * 16 + fr;
#pragma unroll
      for (int i = 0; i < 4; ++i) {
        const int slot = wr * 16 + i * 4 + kg;
        const int xs = slot ^ (mloc & 7);
        *(f32x4*)(smem + mloc * 512 + xs * 16) = acc[i][j];
      }
    }
    __syncthreads();
    const int mrow = tid >> 1, half = tid & 1;
    const size_t sbase = ((size_t)bb * L_ + m0 + mrow) * L_ + l0;
#pragma unroll
    for (int q = 0; q < 16; ++q) {
      const int slot = half * 16 + q;
      const int xs = slot ^ (mrow & 7);
      float4 o = *(const float4*)(smem + mrow * 512 + xs * 16);
      const int4 mk = *(const int4*)(mask + bb * L_ + l0 + slot * 4);
      if (mk.x) o.x = -INFINITY;
      if (mk.y) o.y = -INFINITY;
      if (mk.z) o.z = -INFINITY;
      if (mk.w) o.w = -INFINITY;
      *(float4*)(S + sbase + slot * 4) = o;
    }
  }
}

// ---------------------------------------------------------------------------
// K2 fallback (r5): S = P·P^T from bf16 hi/lo Ph/Pl, 3-pass.
// ---------------------------------------------------------------------------
__global__ __launch_bounds__(256) void k_scores_bf(const unsigned short* __restrict__ Ph,
                                                   const unsigned short* __restrict__ Pl,
                                                   const int* __restrict__ mask,
                                                   float* __restrict__ S) {
  __shared__ __align__(16) char smem[65536];

  const int tid = threadIdx.x;
  const int swz = ((int)blockIdx.x % 8) * 72 + (int)blockIdx.x / 8;
  const int bb = swz / 36;
  const int pr = swz % 36;
  int ti = 0;
  while ((ti + 1) * (ti + 2) / 2 <= pr) ++ti;
  const int tj = pr - ti * (ti + 1) / 2;
  const int l0 = ti * 128, m0 = tj * 128;
  const int lane = tid & 63, wave = tid >> 6;
  const int wr = wave >> 1, wc = wave & 1;
  const int fr = lane & 15, kg = lane >> 4;
  f32x4 acc[4][4];
#pragma unroll
  for (int i = 0; i < 4; ++i)
#pragma unroll
    for (int j = 0; j < 4; ++j) acc[i][j] = 0;

  const size_t arow0 = (size_t)bb * L_ + l0;
  const size_t brow0 = (size_t)bb * L_ + m0;

  stage_panel(Ph, Pl, arow0, 0, smem, wave, lane);
  stage_panel(Ph, Pl, brow0, 0, smem + 16384, wave, lane);
  __syncthreads();

  int cur = 0;
  for (int it = 0; it < D_ / 32; ++it) {
    char* cb = smem + cur * 32768;
    if (it + 1 < D_ / 32) {
      char* nb = smem + (cur ^ 1) * 32768;
      stage_panel(Ph, Pl, arow0, (it + 1) * 32, nb, wave, lane);
      stage_panel(Ph, Pl, brow0, (it + 1) * 32, nb + 16384, wave, lane);
    }
    bf16x8 fah[4], fal[4], fbh[4], fbl[4];
#pragma unroll
    for (int i = 0; i < 4; ++i) {
      const int ra = wr * 64 + i * 16 + fr;
      const int rb = wc * 64 + i * 16 + fr;
      fah[i] = ldsfrag(cb, ra, kg);
      fal[i] = ldsfrag(cb, ra, kg + 4);
      fbh[i] = ldsfrag(cb + 16384, rb, kg);
      fbl[i] = ldsfrag(cb + 16384, rb, kg + 4);
    }
#pragma unroll
    for (int i = 0; i < 4; ++i)
#pragma unroll
      for (int j = 0; j < 4; ++j) {
        acc[i][j] = __builtin_amdgcn_mfma_f32_16x16x32_bf16(fah[i], fbh[j], acc[i][j], 0, 0, 0);
        acc[i][j] = __builtin_amdgcn_mfma_f32_16x16x32_bf16(fah[i], fbl[j], acc[i][j], 0, 0, 0);
        acc[i][j] = __builtin_amdgcn_mfma_f32_16x16x32_bf16(fal[i], fbh[j], acc[i][j], 0, 0, 0);
      }
    __syncthreads();
    cur ^= 1;
  }

  float* scr = (float*)smem + wave * 1280;
  const int row = lane >> 2, seg = lane & 3;
  for (int i = 0; i < 4; ++i) {
    __syncthreads();
#pragma unroll
    for (int j = 0; j < 4; ++j)
#pragma unroll
      for (int r = 0; r < 4; ++r)
        scr[(kg * 4 + r) * 68 + j * 16 + fr] = acc[i][j][r];
    __syncthreads();
    const int gl = l0 + wr * 64 + i * 16 + row;
    const int gm0 = m0 + wc * 64 + seg * 16;
    const size_t sbase = ((size_t)bb * L_ + gl) * L_ + gm0;
#pragma unroll
    for (int t = 0; t < 4; ++t) {
      float4 o = *(const float4*)&scr[row * 68 + seg * 16 + t * 4];
      const int4 mk = *(const int4*)(mask + bb * L_ + gm0 + t * 4);
      float* op = (float*)&o;
      const int* mp = (const int*)&mk;
#pragma unroll
      for (int e = 0; e < 4; ++e) {
        const int gm = gm0 + t * 4 + e;
        if (gm == gl) op[e] = 0.f;
        if (mp[e]) op[e] = -INFINITY;
      }
      *(float4*)(S + sbase + t * 4) = o;
    }
  }

  if (ti != tj) {
    __syncthreads();
#pragma unroll
    for (int j = 0; j < 4; ++j) {
      const int mloc = wc * 64 + j * 16 + fr;
#pragma unroll
      for (int i = 0; i < 4; ++i) {
        const int slot = wr * 16 + i * 4 + kg;
        const int xs = slot ^ (mloc & 7);
        *(f32x4*)(smem + mloc * 512 + xs * 16) = acc[i][j];
      }
    }
    __syncthreads();
    const int mrow = tid >> 1, half = tid & 1;
    const size_t sbase = ((size_t)bb * L_ + m0 + mrow) * L_ + l0;
#pragma unroll
    for (int q = 0; q < 16; ++q) {
      const int slot = half * 16 + q;
      const int xs = slot ^ (mrow & 7);
      float4 o = *(const float4*)(smem + mrow * 512 + xs * 16);
      const int4 mk = *(const int4*)(mask + bb * L_ + l0 + slot * 4);
      if (mk.x) o.x = -INFINITY;
      if (mk.y) o.y = -INFINITY;
      if (mk.z) o.z = -INFINITY;
      if (mk.w) o.w = -INFINITY;
      *(float4*)(S + sbase + slot * 4) = o;
    }
  }
}

// ---------------------------------------------------------------------------
// K3: in-place row softmax; optionally emits fp16 copy (for k_align2).
// ---------------------------------------------------------------------------
__global__ __launch_bounds__(256) void k_softmax(float* __restrict__ S,
                                                 unsigned short* __restrict__ a16) {
  const size_t row = blockIdx.x;
  float4* rp = (float4*)(S + row * L_);
  float4 v = rp[threadIdx.x];
  float mx = fmaxf(fmaxf(v.x, v.y), fmaxf(v.z, v.w));
#pragma unroll
  for (int o = 32; o > 0; o >>= 1) mx = fmaxf(mx, __shfl_xor(mx, o));
  __shared__ float rmax[4], rsum[4];
  const int wv = threadIdx.x >> 6, ln = threadIdx.x & 63;
  if (ln == 0) rmax[wv] = mx;
  __syncthreads();
  mx = fmaxf(fmaxf(rmax[0], rmax[1]), fmaxf(rmax[2], rmax[3]));
  float4 e;
  e.x = __expf(v.x - mx); e.y = __expf(v.y - mx);
  e.z = __expf(v.z - mx); e.w = __expf(v.w - mx);
  float s = (e.x + e.y) + (e.z + e.w);
#pragma unroll
  for (int o = 32; o > 0; o >>= 1) s += __shfl_xor(s, o);
  if (ln == 0) rsum[wv] = s;
  __syncthreads();
  s = (rsum[0] + rsum[1]) + (rsum[2] + rsum[3]);
  const float inv = 1.0f / s;
  e.x *= inv; e.y *= inv; e.z *= inv; e.w *= inv;
  rp[threadIdx.x] = e;
  if (a16) {
    *(ushort4*)(a16 + row * L_ + threadIdx.x * 4) =
        make_ushort4(f2h(e.x), f2h(e.y), f2h(e.z), f2h(e.w));
  }
}

// ---------------------------------------------------------------------------
// K5 v3 (MFMA): align = alpha16·Xt^T per batch, all-fp16 inputs.
// ---------------------------------------------------------------------------
__global__ __launch_bounds__(256) void k_align2(const unsigned short* __restrict__ A16,
                                                const unsigned short* __restrict__ Xt,
                                                float* __restrict__ O) {
  __shared__ __align__(16) char smem[65536];  // 2 x (A 16KB + B 16KB)
  const int tid = threadIdx.x;
  const int swz = ((int)blockIdx.x % 8) * 96 + (int)blockIdx.x / 8;
  const int bb = swz / 48;
  const int l0 = ((swz / 6) % 8) * 128;
  const int n0 = (swz % 6) * 128;
  const int lane = tid & 63, wave = tid >> 6;
  const int wr = wave >> 1, wc = wave & 1;
  const int fr = lane & 15, kg = lane >> 4;
  f32x4 acc[4][4];
#pragma unroll
  for (int i = 0; i < 4; ++i)
#pragma unroll
    for (int j = 0; j < 4; ++j) acc[i][j] = 0;

  const unsigned short* a0 = A16 + ((size_t)bb * L_ + l0) * L_;
  const unsigned short* b0 = Xt + ((size_t)bb * D_ + n0) * L_;

  stage_panel1(a0, L_, smem, wave, lane);
  stage_panel1(b0, L_, smem + 16384, wave, lane);
  __syncthreads();

  int cur = 0;
  for (int it = 0; it < L_ / 64; ++it) {
    char* cb = smem + cur * 32768;
    if (it + 1 < L_ / 64) {
      char* nb = smem + (cur ^ 1) * 32768;
      stage_panel1(a0 + (it + 1) * 64, L_, nb, wave, lane);
      stage_panel1(b0 + (it + 1) * 64, L_, nb + 16384, wave, lane);
    }
    half8 fa[2][4], fb[2][4];
#pragma unroll
    for (int i = 0; i < 4; ++i) {
      const int ra = wr * 64 + i * 16 + fr;
      const int rb = wc * 64 + i * 16 + fr;
#pragma unroll
      for (int ks = 0; ks < 2; ++ks) {
        fa[ks][i] = ldsfrag_h(cb, ra, ks * 4 + kg);
        fb[ks][i] = ldsfrag_h(cb + 16384, rb, ks * 4 + kg);
      }
    }
#pragma unroll
    for (int ks = 0; ks < 2; ++ks)
#pragma unroll
      for (int i = 0; i < 4; ++i)
#pragma unroll
        for (int j = 0; j < 4; ++j)
          acc[i][j] = __builtin_amdgcn_mfma_f32_16x16x32_f16(fa[ks][i], fb[ks][j],
                                                             acc[i][j], 0, 0, 0);
    __syncthreads();
    cur ^= 1;
  }

  float* scr = (float*)smem + wave * 1280;
  const int row = lane >> 2, seg = lane & 3;
  for (int i = 0; i < 4; ++i) {
    __syncthreads();
#pragma unroll
    for (int j = 0; j < 4; ++j)
#pragma unroll
      for (int r = 0; r < 4; ++r)
        scr[(kg * 4 + r) * 68 + j * 16 + fr] = acc[i][j][r];
    __syncthreads();
    const int gl = l0 + wr * 64 + i * 16 + row;
    const int gc0 = n0 + wc * 64 + seg * 16;
    const size_t obase = ((size_t)bb * L_ + gl) * D_ + gc0;
#pragma unroll
    for (int t = 0; t < 4; ++t) {
      const float4 o = *(const float4*)&scr[row * 68 + seg * 16 + t * 4];
      *(float4*)(O + obase + t * 4) = o;
    }
  }
}

// ---------------------------------------------------------------------------
// K5 fallback (r6): align = alpha(f32)·Xt^T (bf16 Xt), staging conversion.
// ---------------------------------------------------------------------------
__global__ __launch_bounds__(256) void k_align(const float* __restrict__ A,
                                               const unsigned short* __restrict__ Xt,
                                               float* __restrict__ O) {
  __shared__ __align__(16) unsigned short smem[2 * 128 * 32];
  __shared__ __align__(16) float scr_s[4 * 1104];
  unsigned short (*Ab)[32] = (unsigned short(*)[32])smem;
  unsigned short (*Bb)[32] = (unsigned short(*)[32])(smem + 128 * 32);

  const int tid = threadIdx.x;
  const int swz = ((int)blockIdx.x % 8) * 96 + (int)blockIdx.x / 8;
  const int bb = swz / 48;
  const int l0 = ((swz / 6) % 8) * 128;
  const int n0 = (swz % 6) * 128;
  const int lane = tid & 63, wave = tid >> 6;
  const int wr = wave >> 1, wc = wave & 1;
  const int fr = lane & 15, kg = lane >> 4;
  f32x4 acc[4][4];
#pragma unroll
  for (int i = 0; i < 4; ++i)
#pragma unroll
    for (int j = 0; j < 4; ++j) acc[i][j] = 0;

  float4 av[4];
  uint4 bv[2];
#pragma unroll
  for (int p = 0; p < 4; ++p) {
    const int f = tid + p * 256, r = f >> 3, c = f & 7;
    av[p] = *(const float4*)(A + ((size_t)bb * L_ + l0 + r) * L_ + c * 4);
  }
#pragma unroll
  for (int p = 0; p < 2; ++p) {
    const int f = tid + p * 256, r = f >> 2, sl = f & 3;
    bv[p] = *(const uint4*)(Xt + ((size_t)bb * D_ + n0 + r) * L_ + sl * 8);
  }

  for (int it = 0; it < L_ / 32; ++it) {
    __syncthreads();
#pragma unroll
    for (int p = 0; p < 4; ++p) {
      const int f = tid + p * 256, r = f >> 3, c = f & 7;
      *(ushort4*)&Ab[r][c * 4] = make_ushort4(f2bf(av[p].x), f2bf(av[p].y),
                                              f2bf(av[p].z), f2bf(av[p].w));
    }
#pragma unroll
    for (int p = 0; p < 2; ++p) {
      const int f = tid + p * 256, r = f >> 2, sl = f & 3;
      *(uint4*)&Bb[r][sl * 8] = bv[p];
    }
    __syncthreads();
    if (it + 1 < L_ / 32) {
      const int kk = (it + 1) * 32;
#pragma unroll
      for (int p = 0; p < 4; ++p) {
        const int f = tid + p * 256, r = f >> 3, c = f & 7;
        av[p] = *(const float4*)(A + ((size_t)bb * L_ + l0 + r) * L_ + kk + c * 4);
      }
#pragma unroll
      for (int p = 0; p < 2; ++p) {
        const int f = tid + p * 256, r = f >> 2, sl = f & 3;
        bv[p] = *(const uint4*)(Xt + ((size_t)bb * D_ + n0 + r) * L_ + kk + sl * 8);
      }
    }
    bf16x8 fa[4], fb[4];
#pragma unroll
    for (int i = 0; i < 4; ++i) {
      fa[i] = *(const bf16x8*)&Ab[wr * 64 + i * 16 + fr][kg * 8];
      fb[i] = *(const bf16x8*)&Bb[wc * 64 + i * 16 + fr][kg * 8];
    }
#pragma unroll
    for (int i = 0; i < 4; ++i)
#pragma unroll
      for (int j = 0; j < 4; ++j)
        acc[i][j] = __builtin_amdgcn_mfma_f32_16x16x32_bf16(fa[i], fb[j], acc[i][j], 0, 0, 0);
  }

  float* scr = scr_s + wave * 1104;
  const int row = lane >> 2, seg = lane & 3;
  for (int i = 0; i < 4; ++i) {
    __syncthreads();
#pragma unroll
    for (int j = 0; j < 4; ++j)
#pragma unroll
      for (int r = 0; r < 4; ++r)
        scr[(kg * 4 + r) * 68 + j * 16 + fr] = acc[i][j][r];
    __syncthreads();
    const int gl = l0 + wr * 64 + i * 16 + row;
    const int gc0 = n0 + wc * 64 + seg * 16;
    const size_t obase = ((size_t)bb * L_ + gl) * D_ + gc0;
#pragma unroll
    for (int t = 0; t < 4; ++t) {
      const float4 o = *(const float4*)&scr[row * 68 + seg * 16 + t * 4];
      *(float4*)(O + obase + t * 4) = o;
    }
  }
}

// ---------------------------------------------------------------------------
extern "C" void kernel_launch(void* const* d_in, const int* in_sizes, int n_in,
                              void* d_out, int out_size, void* d_ws, size_t ws_size,
                              hipStream_t stream) {
  const float* X    = (const float*)d_in[0];  // [B,L,D]
  const void*  mraw = d_in[1];                // [B,L] bool/int
  const float* W    = (const float*)d_in[2];  // [D,D]
  const float* bias = (const float*)d_in[3];  // [D]

  float* out   = (float*)d_out;
  float* align = out;                          // B*L*D fp32 (48MB)
  float* alpha = out + (size_t)B_ * L_ * D_;   // B*L*L fp32 (64MB)

  const size_t NX = (size_t)B_ * L_ * D_;   // 12,582,912
  const size_t NW = (size_t)D_ * D_;        // 589,824
  const size_t NA = (size_t)B_ * L_ * L_;   // 16,777,216

  int* maskC = (int*)d_ws;                                      // 64 KB
  unsigned short* Xt = (unsigned short*)((char*)d_ws + 65536);  // 25.17 MB

  // fast-path ws: maskC | Xt | Wh | Wl ; a16 overlays Wh/Wl (dead after proj)
  const size_t offWh = 65536 + NX * 2;
  const size_t offWl = offWh + NW * 2;
  const size_t offA16 = offWh;
  const size_t need = offA16 + NA * 2;  // ~58.8 MB (same as r7/r8, proven OK)

  hipLaunchKernelGGL(k_mask, dim3(1), dim3(256), 0, stream, mraw, maskC);

  if (ws_size >= need) {
    // Xh/Xl in the (dead-until-scores) alpha region; Pf in align region
    // (dead until k_align2 writes it).
    unsigned short* Xh = (unsigned short*)alpha;
    unsigned short* Xl = Xh + NX;
    unsigned short* Wh = (unsigned short*)((char*)d_ws + offWh);
    unsigned short* Wl = (unsigned short*)((char*)d_ws + offWl);
    unsigned short* Pf = (unsigned short*)align;
    unsigned short* A16 = (unsigned short*)((char*)d_ws + offA16);
    hipLaunchKernelGGL(k_prep, dim3(D_ / 64, L_ / 64, B_), dim3(256), 0, stream,
                       X, Xh, Xl, Xt, 1);
    hipLaunchKernelGGL(k_split, dim3((int)(NW / 8 / 256)), dim3(256), 0, stream,
                       W, Wh, Wl, (int)(NW / 8));
    hipLaunchKernelGGL(k_proj2, dim3(768), dim3(256), 0, stream,
                       Xh, Xl, Wh, Wl, bias, Pf);
    hipLaunchKernelGGL(k_scores, dim3(576), dim3(256), 0, stream, Pf, maskC, alpha);
    hipLaunchKernelGGL(k_softmax, dim3(B_ * L_), dim3(256), 0, stream, alpha, A16);
    hipLaunchKernelGGL(k_align2, dim3(768), dim3(256), 0, stream, A16, Xt, align);
  } else {
    // fallback: full bf16 path (r5/r6 kernels), bf16 Xt.
    unsigned short* Ph = (unsigned short*)align;
    unsigned short* Pl = Ph + NX;
    hipLaunchKernelGGL(k_prep, dim3(D_ / 64, L_ / 64, B_), dim3(256), 0, stream,
                       X, (unsigned short*)alpha, (unsigned short*)alpha + NX, Xt, 0);
    hipLaunchKernelGGL(k_proj, dim3(768), dim3(256), 0, stream, X, W, bias, Ph, Pl);
    hipLaunchKernelGGL(k_scores_bf, dim3(576), dim3(256), 0, stream, Ph, Pl, maskC, alpha);
    hipLaunchKernelGGL(k_softmax, dim3(B_ * L_), dim3(256), 0, stream, alpha,
                       (unsigned short*)nullptr);
    hipLaunchKernelGGL(k_align, dim3(768), dim3(256), 0, stream, alpha, Xt, align);
  }
}

// Round 10
// 212.481 us; speedup vs baseline: 1.4749x; 1.0644x over previous
//
#include <hip/hip_runtime.h>
#include <math.h>

// Problem constants
#define B_ 16
#define L_ 1024
#define D_ 768

typedef short bf16x8 __attribute__((ext_vector_type(8)));
typedef _Float16 half8 __attribute__((ext_vector_type(8)));
typedef float f32x4 __attribute__((ext_vector_type(4)));

// round-to-nearest-even f32 -> bf16 (bit trick; inputs never NaN)
__device__ __forceinline__ unsigned short f2bf(float x) {
  unsigned u = __float_as_uint(x);
  u = (u + 0x7FFFu + ((u >> 16) & 1u)) >> 16;
  return (unsigned short)u;
}
__device__ __forceinline__ float bf2f(unsigned short h) {
  return __uint_as_float(((unsigned)h) << 16);
}
// f32 -> fp16 bits (RTN)
__device__ __forceinline__ unsigned short f2h(float x) {
  union { _Float16 h; unsigned short u; } v;
  v.h = (_Float16)x;
  return v.u;
}

// ---------------------------------------------------------------------------
// K0 v2: canonicalize mask (dtype auto-detect) AND per-batch validity
// prefix-sum (psum, exclusive) + kinfo[b]=nt tiles, kinfo[16+b]=valid count.
// 16 blocks (one per batch), 256 threads, 4 elems/thread, LDS scan.
// ---------------------------------------------------------------------------
__global__ __launch_bounds__(256) void k_mask2(const void* __restrict__ mraw,
                                               int* __restrict__ canon,
                                               int* __restrict__ psum,
                                               int* __restrict__ kinfo) {
  __shared__ int flags[2];
  __shared__ int tsum[256];
  const int b = blockIdx.x;
  const int tid = threadIdx.x;
  if (tid < 2) flags[tid] = 0;
  __syncthreads();
  // dtype detection on the full 16KB (global property; same result all blocks)
  const unsigned* m32 = (const unsigned*)mraw;
  int gt = 0, oddnz = 0;
  for (int i = tid; i < 4096; i += 256) {
    unsigned v = m32[i];
    if (v > 1u) gt = 1;
    if ((i & 1) && v != 0u) oddnz = 1;
  }
  if (gt) atomicOr(&flags[0], 1);
  if (oddnz) atomicOr(&flags[1], 1);
  __syncthreads();
  const int mode = flags[0] ? 0 : (flags[1] ? 1 : 2);  // 0=u8, 1=i32, 2=i64
  int v[4];
#pragma unroll
  for (int e = 0; e < 4; ++e) {
    const int i = b * L_ + tid * 4 + e;
    int mv;
    if (mode == 0)      mv = ((const unsigned char*)mraw)[i];
    else if (mode == 1) mv = ((const int*)mraw)[i];
    else                mv = (int)(((const long long*)mraw)[i] != 0);
    v[e] = (mv != 0);          // 1 = padding
    canon[i] = v[e];
  }
  const int vc = (1 - v[0]) + (1 - v[1]) + (1 - v[2]) + (1 - v[3]);  // valid cnt
  tsum[tid] = vc;
  __syncthreads();
  for (int off = 1; off < 256; off <<= 1) {
    const int t = (tid >= off) ? tsum[tid - off] : 0;
    __syncthreads();
    tsum[tid] += t;
    __syncthreads();
  }
  int run = tsum[tid] - vc;  // exclusive prefix
#pragma unroll
  for (int e = 0; e < 4; ++e) {
    psum[b * L_ + tid * 4 + e] = run;
    run += 1 - v[e];
  }
  if (tid == 255) {
    const int tot = tsum[255];
    kinfo[b] = (tot + 63) >> 6;   // nt = K-tiles of 64
    kinfo[16 + b] = tot;          // valid count
  }
}

// ---------------------------------------------------------------------------
// K-prep: ONE pass over X producing Xh, Xl (hi/lo bf16, X layout, for proj)
// and Xt (transposed [b][d][*]); when compact=1, Xt columns are the COMPACTED
// valid-token indices (fp16); else full bf16/fp16 per xt16.
// ---------------------------------------------------------------------------
__global__ __launch_bounds__(256) void k_prep(const float* __restrict__ X,
                                              unsigned short* __restrict__ Xh,
                                              unsigned short* __restrict__ Xl,
                                              unsigned short* __restrict__ Xt,
                                              const int* __restrict__ psum,
                                              const int* __restrict__ canon,
                                              int xt16, int compact) {
  __shared__ unsigned short t16[64][66];
  const int b = blockIdx.z;
  const int d0 = blockIdx.x * 64, m0 = blockIdx.y * 64;
  const int dd = threadIdx.x & 63, mq = threadIdx.x >> 6;
#pragma unroll
  for (int i = 0; i < 16; ++i) {
    const int m = mq * 16 + i;
    const size_t gidx = ((size_t)b * L_ + m0 + m) * D_ + d0 + dd;
    const float x = X[gidx];
    const unsigned short h = f2bf(x);
    Xh[gidx] = h;
    Xl[gidx] = f2bf(x - bf2f(h));
    t16[dd][m] = xt16 ? f2h(x) : h;
  }
  __syncthreads();
  const int mm = threadIdx.x & 63, dq = threadIdx.x >> 6;
  if (compact) {
    const int gm = m0 + mm;
    if (!canon[b * L_ + gm]) {        // valid token -> compacted column
      const int j = psum[b * L_ + gm];
#pragma unroll
      for (int i = 0; i < 16; ++i) {
        const int d = dq * 16 + i;
        Xt[((size_t)b * D_ + d0 + d) * L_ + j] = t16[d][mm];
      }
    }
  } else {
#pragma unroll
    for (int i = 0; i < 16; ++i) {
      const int d = dq * 16 + i;
      Xt[((size_t)b * D_ + d0 + d) * L_ + m0 + mm] = t16[d][mm];
    }
  }
}

// ---------------------------------------------------------------------------
// K-pad: zero the [kvalid, nt*64) column tails of Xtc (768 rows/b) and
// a16c (1024 rows/b) so the padded K-tiles contribute exactly zero.
// grid (16, 28): 28 chunks x 64 rows cover 768+1024 rows per batch.
// ---------------------------------------------------------------------------
__global__ __launch_bounds__(256) void k_pad(unsigned short* __restrict__ Xtc,
                                             unsigned short* __restrict__ a16c,
                                             const int* __restrict__ kinfo) {
  const int b = blockIdx.x;
  const int nt64 = kinfo[b] * 64;
  const int kv = kinfo[16 + b];
  if (kv >= nt64) return;
  const int r = blockIdx.y * 64 + (threadIdx.x >> 2);
  const int cg = threadIdx.x & 3;
  unsigned short* base = (r < 768)
      ? Xtc + ((size_t)b * D_ + r) * L_
      : a16c + ((size_t)b * L_ + (r - 768)) * L_;
#pragma unroll
  for (int q = 0; q < 16; ++q) {
    const int c = kv + cg * 16 + q;
    if (c < nt64) base[c] = 0;
  }
}

// ---------------------------------------------------------------------------
// K-split: elementwise f32 -> bf16 hi/lo pair (used for W only).
// ---------------------------------------------------------------------------
__global__ __launch_bounds__(256) void k_split(const float* __restrict__ src,
                                               unsigned short* __restrict__ hi,
                                               unsigned short* __restrict__ lo,
                                               int n8) {
  const int i = blockIdx.x * 256 + threadIdx.x;
  if (i >= n8) return;
  const float4 a = *(const float4*)(src + (size_t)i * 8);
  const float4 b = *(const float4*)(src + (size_t)i * 8 + 4);
  const float xs[8] = {a.x, a.y, a.z, a.w, b.x, b.y, b.z, b.w};
  unsigned short h[8], l[8];
#pragma unroll
  for (int e = 0; e < 8; ++e) {
    h[e] = f2bf(xs[e]);
    l[e] = f2bf(xs[e] - bf2f(h[e]));
  }
  *(ushort4*)(hi + (size_t)i * 8)     = make_ushort4(h[0], h[1], h[2], h[3]);
  *(ushort4*)(hi + (size_t)i * 8 + 4) = make_ushort4(h[4], h[5], h[6], h[7]);
  *(ushort4*)(lo + (size_t)i * 8)     = make_ushort4(l[0], l[1], l[2], l[3]);
  *(ushort4*)(lo + (size_t)i * 8 + 4) = make_ushort4(l[4], l[5], l[6], l[7]);
}

// ---------------------------------------------------------------------------
// Staging helpers: 128-row x 128B LDS panels, 16B slots XOR-swizzled via
// pre-swizzled global source (slot xs = s ^ (row&7)).
// ---------------------------------------------------------------------------
__device__ __forceinline__ void stage_panel(const unsigned short* __restrict__ ph,
                                            const unsigned short* __restrict__ pl,
                                            size_t grow0, int kk,
                                            char* ldsbase, int wave, int lane) {
#pragma unroll
  for (int q = 0; q < 4; ++q) {
    const int s = wave * 4 + q;              // 1KB span: 8 rows x 128B
    const int row = s * 8 + (lane >> 3);
    const int xs = (lane & 7) ^ (row & 7);   // pre-swizzled source slot
    const unsigned short* src = (xs & 4) ? pl : ph;
    const unsigned short* g = src + (grow0 + row) * D_ + kk + (xs & 3) * 8;
    __builtin_amdgcn_global_load_lds(
        (const __attribute__((address_space(1))) void*)g,
        (__attribute__((address_space(3))) void*)(ldsbase + s * 1024),
        16, 0, 0);
  }
}

__device__ __forceinline__ void stage_panel1(const unsigned short* __restrict__ g0,
                                             size_t rstride,
                                             char* ldsbase, int wave, int lane) {
#pragma unroll
  for (int q = 0; q < 4; ++q) {
    const int s = wave * 4 + q;
    const int row = s * 8 + (lane >> 3);
    const int xs = (lane & 7) ^ (row & 7);
    const unsigned short* g = g0 + (size_t)row * rstride + xs * 8;
    __builtin_amdgcn_global_load_lds(
        (const __attribute__((address_space(1))) void*)g,
        (__attribute__((address_space(3))) void*)(ldsbase + s * 1024),
        16, 0, 0);
  }
}

__device__ __forceinline__ bf16x8 ldsfrag(const char* base, int row, int g) {
  return *(const bf16x8*)(base + row * 128 + ((g ^ (row & 7)) * 16));
}
__device__ __forceinline__ half8 ldsfrag_h(const char* base, int row, int g) {
  return *(const half8*)(base + row * 128 + ((g ^ (row & 7)) * 16));
}

// ---------------------------------------------------------------------------
// K1 v3 (MFMA): P = relu(Xs·Ws^T + b), 3-pass bf16 hi/lo inputs (fp32-class
// accuracy), output ONE fp16 array Pf. XCD-local m-outer/n-inner mapping.
// ---------------------------------------------------------------------------
__global__ __launch_bounds__(256) void k_proj2(const unsigned short* __restrict__ Xh,
                                               const unsigned short* __restrict__ Xl,
                                               const unsigned short* __restrict__ Wh,
                                               const unsigned short* __restrict__ Wl,
                                               const float* __restrict__ bias,
                                               unsigned short* __restrict__ Pf) {
  __shared__ __align__(16) char smem[49152];  // A: 2x16KB @0, B: 16KB @32KB
  const int tid = threadIdx.x;
  const int xcd = (int)blockIdx.x & 7;
  const int li  = (int)blockIdx.x >> 3;
  const int m0 = (xcd * 16 + li / 6) * 128;
  const int n0 = (li % 6) * 128;
  const int lane = tid & 63, wave = tid >> 6;
  const int wr = wave >> 1, wc = wave & 1;
  const int fr = lane & 15, kg = lane >> 4;
  f32x4 acc[4][4];
#pragma unroll
  for (int i = 0; i < 4; ++i)
#pragma unroll
    for (int j = 0; j < 4; ++j) acc[i][j] = 0;

  stage_panel(Xh, Xl, (size_t)m0, 0, smem, wave, lane);
  stage_panel(Wh, Wl, (size_t)n0, 0, smem + 32768, wave, lane);
  __syncthreads();

  int cur = 0;
  for (int it = 0; it < D_ / 32; ++it) {
    const char* ab = smem + cur * 16384;
    const char* bb = smem + 32768;
    bf16x8 fah[4], fal[4], fbh[4], fbl[4];
#pragma unroll
    for (int i = 0; i < 4; ++i) {
      const int ra = wr * 64 + i * 16 + fr;
      const int rb = wc * 64 + i * 16 + fr;
      fah[i] = ldsfrag(ab, ra, kg);
      fal[i] = ldsfrag(ab, ra, kg + 4);
      fbh[i] = ldsfrag(bb, rb, kg);
      fbl[i] = ldsfrag(bb, rb, kg + 4);
    }
    __syncthreads();
    if (it + 1 < D_ / 32) {
      stage_panel(Xh, Xl, (size_t)m0, (it + 1) * 32, smem + (cur ^ 1) * 16384, wave, lane);
      stage_panel(Wh, Wl, (size_t)n0, (it + 1) * 32, smem + 32768, wave, lane);
    }
#pragma unroll
    for (int i = 0; i < 4; ++i)
#pragma unroll
      for (int j = 0; j < 4; ++j) {
        acc[i][j] = __builtin_amdgcn_mfma_f32_16x16x32_bf16(fah[i], fbh[j], acc[i][j], 0, 0, 0);
        acc[i][j] = __builtin_amdgcn_mfma_f32_16x16x32_bf16(fah[i], fbl[j], acc[i][j], 0, 0, 0);
        acc[i][j] = __builtin_amdgcn_mfma_f32_16x16x32_bf16(fal[i], fbh[j], acc[i][j], 0, 0, 0);
      }
    __syncthreads();
    cur ^= 1;
  }

  unsigned short* scr = (unsigned short*)smem + wave * 1152;
  const int row = lane >> 2, seg = lane & 3;
  float bj[4];
#pragma unroll
  for (int j = 0; j < 4; ++j) bj[j] = bias[n0 + wc * 64 + j * 16 + fr];
  for (int i = 0; i < 4; ++i) {
    __syncthreads();
#pragma unroll
    for (int j = 0; j < 4; ++j)
#pragma unroll
      for (int r = 0; r < 4; ++r)
        scr[(kg * 4 + r) * 72 + j * 16 + fr] = f2h(fmaxf(acc[i][j][r] + bj[j], 0.f));
    __syncthreads();
    const size_t gr = (size_t)(m0 + wr * 64 + i * 16 + row);
    const int gc0 = n0 + wc * 64 + seg * 16;
    const uint4 h0 = *(const uint4*)&scr[row * 72 + seg * 16];
    const uint4 h1 = *(const uint4*)&scr[row * 72 + seg * 16 + 8];
    *(uint4*)(Pf + gr * D_ + gc0)     = h0;
    *(uint4*)(Pf + gr * D_ + gc0 + 8) = h1;
  }
}

// ---------------------------------------------------------------------------
// K1 fallback (r5): on-the-fly split proj -> bf16 Ph/Pl (used if ws small).
// ---------------------------------------------------------------------------
__global__ __launch_bounds__(256) void k_proj(const float* __restrict__ X,
                                              const float* __restrict__ W,
                                              const float* __restrict__ bias,
                                              unsigned short* __restrict__ Ph,
                                              unsigned short* __restrict__ Pl) {
  __shared__ __align__(16) unsigned short smem[4 * 128 * 32];
  unsigned short (*Ah)[32] = (unsigned short(*)[32])smem;
  unsigned short (*Al)[32] = (unsigned short(*)[32])(smem + 1 * 128 * 32);
  unsigned short (*Bh)[32] = (unsigned short(*)[32])(smem + 2 * 128 * 32);
  unsigned short (*Bl)[32] = (unsigned short(*)[32])(smem + 3 * 128 * 32);

  const int tid = threadIdx.x;
  const int swz = ((int)blockIdx.x % 8) * 96 + (int)blockIdx.x / 8;
  const int m0 = (swz / 6) * 128, n0 = (swz % 6) * 128;
  const int lane = tid & 63, wave = tid >> 6;
  const int wr = wave >> 1, wc = wave & 1;
  const int fr = lane & 15, kg = lane >> 4;
  f32x4 acc[4][4];
#pragma unroll
  for (int i = 0; i < 4; ++i)
#pragma unroll
    for (int j = 0; j < 4; ++j) acc[i][j] = 0;

  float4 av[4], bv[4];
#pragma unroll
  for (int p = 0; p < 4; ++p) {
    const int f = tid + p * 256, r = f >> 3, c = f & 7;
    av[p] = *(const float4*)(X + (size_t)(m0 + r) * D_ + c * 4);
    bv[p] = *(const float4*)(W + (size_t)(n0 + r) * D_ + c * 4);
  }

  for (int it = 0; it < D_ / 32; ++it) {
    __syncthreads();
#pragma unroll
    for (int p = 0; p < 4; ++p) {
      const int f = tid + p * 256, r = f >> 3, c = f & 7;
      {
        const float x0 = av[p].x, x1 = av[p].y, x2 = av[p].z, x3 = av[p].w;
        const unsigned short h0 = f2bf(x0), h1 = f2bf(x1), h2 = f2bf(x2), h3 = f2bf(x3);
        *(ushort4*)&Ah[r][c * 4] = make_ushort4(h0, h1, h2, h3);
        *(ushort4*)&Al[r][c * 4] = make_ushort4(f2bf(x0 - bf2f(h0)), f2bf(x1 - bf2f(h1)),
                                                f2bf(x2 - bf2f(h2)), f2bf(x3 - bf2f(h3)));
      }
      {
        const float x0 = bv[p].x, x1 = bv[p].y, x2 = bv[p].z, x3 = bv[p].w;
        const unsigned short h0 = f2bf(x0), h1 = f2bf(x1), h2 = f2bf(x2), h3 = f2bf(x3);
        *(ushort4*)&Bh[r][c * 4] = make_ushort4(h0, h1, h2, h3);
        *(ushort4*)&Bl[r][c * 4] = make_ushort4(f2bf(x0 - bf2f(h0)), f2bf(x1 - bf2f(h1)),
                                                f2bf(x2 - bf2f(h2)), f2bf(x3 - bf2f(h3)));
      }
    }
    __syncthreads();
    if (it + 1 < D_ / 32) {
      const int kk = (it + 1) * 32;
#pragma unroll
      for (int p = 0; p < 4; ++p) {
        const int f = tid + p * 256, r = f >> 3, c = f & 7;
        av[p] = *(const float4*)(X + (size_t)(m0 + r) * D_ + kk + c * 4);
        bv[p] = *(const float4*)(W + (size_t)(n0 + r) * D_ + kk + c * 4);
      }
    }
    bf16x8 fah[4], fal[4], fbh[4], fbl[4];
#pragma unroll
    for (int i = 0; i < 4; ++i) {
      fah[i] = *(const bf16x8*)&Ah[wr * 64 + i * 16 + fr][kg * 8];
      fal[i] = *(const bf16x8*)&Al[wr * 64 + i * 16 + fr][kg * 8];
      fbh[i] = *(const bf16x8*)&Bh[wc * 64 + i * 16 + fr][kg * 8];
      fbl[i] = *(const bf16x8*)&Bl[wc * 64 + i * 16 + fr][kg * 8];
    }
#pragma unroll
    for (int i = 0; i < 4; ++i)
#pragma unroll
      for (int j = 0; j < 4; ++j) {
        acc[i][j] = __builtin_amdgcn_mfma_f32_16x16x32_bf16(fah[i], fbh[j], acc[i][j], 0, 0, 0);
        acc[i][j] = __builtin_amdgcn_mfma_f32_16x16x32_bf16(fah[i], fbl[j], acc[i][j], 0, 0, 0);
        acc[i][j] = __builtin_amdgcn_mfma_f32_16x16x32_bf16(fal[i], fbh[j], acc[i][j], 0, 0, 0);
      }
  }

  unsigned short* scr = smem + wave * 2304;
  const int row = lane >> 2, seg = lane & 3;
  float bj[4];
#pragma unroll
  for (int j = 0; j < 4; ++j) bj[j] = bias[n0 + wc * 64 + j * 16 + fr];
  for (int i = 0; i < 4; ++i) {
    __syncthreads();
#pragma unroll
    for (int j = 0; j < 4; ++j)
#pragma unroll
      for (int r = 0; r < 4; ++r) {
        float v = fmaxf(acc[i][j][r] + bj[j], 0.f);
        const unsigned short h = f2bf(v);
        scr[(kg * 4 + r) * 72 + j * 16 + fr] = h;
        scr[1152 + (kg * 4 + r) * 72 + j * 16 + fr] = f2bf(v - bf2f(h));
      }
    __syncthreads();
    const size_t gr = (size_t)(m0 + wr * 64 + i * 16 + row);
    const int gc0 = n0 + wc * 64 + seg * 16;
    const uint4 h0 = *(const uint4*)&scr[row * 72 + seg * 16];
    const uint4 h1 = *(const uint4*)&scr[row * 72 + seg * 16 + 8];
    const uint4 q0 = *(const uint4*)&scr[1152 + row * 72 + seg * 16];
    const uint4 q1 = *(const uint4*)&scr[1152 + row * 72 + seg * 16 + 8];
    *(uint4*)(Ph + gr * D_ + gc0)     = h0;
    *(uint4*)(Ph + gr * D_ + gc0 + 8) = h1;
    *(uint4*)(Pl + gr * D_ + gc0)     = q0;
    *(uint4*)(Pl + gr * D_ + gc0 + 8) = q1;
  }
}

// ---------------------------------------------------------------------------
// K2 v2 (MFMA): S = Pf·Pf^T, single fp16 pass, symmetric pairs, K-tile 64.
// ---------------------------------------------------------------------------
__global__ __launch_bounds__(256) void k_scores(const unsigned short* __restrict__ Pf,
                                                const int* __restrict__ mask,
                                                float* __restrict__ S) {
  __shared__ __align__(16) char smem[65536];

  const int tid = threadIdx.x;
  const int swz = ((int)blockIdx.x % 8) * 72 + (int)blockIdx.x / 8;
  const int bb = swz / 36;
  const int pr = swz % 36;
  int ti = 0;
  while ((ti + 1) * (ti + 2) / 2 <= pr) ++ti;
  const int tj = pr - ti * (ti + 1) / 2;
  const int l0 = ti * 128, m0 = tj * 128;
  const int lane = tid & 63, wave = tid >> 6;
  const int wr = wave >> 1, wc = wave & 1;
  const int fr = lane & 15, kg = lane >> 4;
  f32x4 acc[4][4];
#pragma unroll
  for (int i = 0; i < 4; ++i)
#pragma unroll
    for (int j = 0; j < 4; ++j) acc[i][j] = 0;

  const unsigned short* a0 = Pf + ((size_t)bb * L_ + l0) * D_;
  const unsigned short* b0 = Pf + ((size_t)bb * L_ + m0) * D_;

  stage_panel1(a0, D_, smem, wave, lane);
  stage_panel1(b0, D_, smem + 16384, wave, lane);
  __syncthreads();

  int cur = 0;
  for (int it = 0; it < D_ / 64; ++it) {
    char* cb = smem + cur * 32768;
    if (it + 1 < D_ / 64) {
      char* nb = smem + (cur ^ 1) * 32768;
      stage_panel1(a0 + (it + 1) * 64, D_, nb, wave, lane);
      stage_panel1(b0 + (it + 1) * 64, D_, nb + 16384, wave, lane);
    }
    half8 fa[2][4], fb[2][4];
#pragma unroll
    for (int i = 0; i < 4; ++i) {
      const int ra = wr * 64 + i * 16 + fr;
      const int rb = wc * 64 + i * 16 + fr;
#pragma unroll
      for (int ks = 0; ks < 2; ++ks) {
        fa[ks][i] = ldsfrag_h(cb, ra, ks * 4 + kg);
        fb[ks][i] = ldsfrag_h(cb + 16384, rb, ks * 4 + kg);
      }
    }
#pragma unroll
    for (int ks = 0; ks < 2; ++ks)
#pragma unroll
      for (int i = 0; i < 4; ++i)
#pragma unroll
        for (int j = 0; j < 4; ++j)
          acc[i][j] = __builtin_amdgcn_mfma_f32_16x16x32_f16(fa[ks][i], fb[ks][j],
                                                             acc[i][j], 0, 0, 0);
    __syncthreads();
    cur ^= 1;
  }

  float* scr = (float*)smem + wave * 1280;
  const int row = lane >> 2, seg = lane & 3;
  for (int i = 0; i < 4; ++i) {
    __syncthreads();
#pragma unroll
    for (int j = 0; j < 4; ++j)
#pragma unroll
      for (int r = 0; r < 4; ++r)
        scr[(kg * 4 + r) * 68 + j * 16 + fr] = acc[i][j][r];
    __syncthreads();
    const int gl = l0 + wr * 64 + i * 16 + row;
    const int gm0 = m0 + wc * 64 + seg * 16;
    const size_t sbase = ((size_t)bb * L_ + gl) * L_ + gm0;
#pragma unroll
    for (int t = 0; t < 4; ++t) {
      float4 o = *(const float4*)&scr[row * 68 + seg * 16 + t * 4];
      const int4 mk = *(const int4*)(mask + bb * L_ + gm0 + t * 4);
      float* op = (float*)&o;
      const int* mp = (const int*)&mk;
#pragma unroll
      for (int e = 0; e < 4; ++e) {
        const int gm = gm0 + t * 4 + e;
        if (gm == gl) op[e] = 0.f;
        if (mp[e]) op[e] = -INFINITY;
      }
      *(float4*)(S + sbase + t * 4) = o;
    }
  }

  if (ti != tj) {
    __syncthreads();
#pragma unroll
    for (int j = 0; j < 4; ++j) {
      const int mloc = wc * 64 + j * 16 + fr;
#pragma unroll
      for (int i = 0; i < 4; ++i) {
        const int slot = wr * 16 + i * 4 + kg;
        const int xs = slot ^ (mloc & 7);
        *(f32x4*)(smem + mloc * 512 + xs * 16) = acc[i][j];
      }
    }
    __syncthreads();
    const int mrow = tid >> 1, half = tid & 1;
    const size_t sbase = ((size_t)bb * L_ + m0 + mrow) * L_ + l0;
#pragma unroll
    for (int q = 0; q < 16; ++q) {
      const int slot = half * 16 + q;
      const int xs = slot ^ (mrow & 7);
      float4 o = *(const float4*)(smem + mrow * 512 + xs * 16);
      const int4 mk = *(const int4*)(mask + bb * L_ + l0 + slot * 4);
      if (mk.x) o.x = -INFINITY;
      if (mk.y) o.y = -INFINITY;
      if (mk.z) o.z = -INFINITY;
      if (mk.w) o.w = -INFINITY;
      *(float4*)(S + sbase + slot * 4) = o;
    }
  }
}

// ---------------------------------------------------------------------------
// K2 fallback (r5): S = P·P^T from bf16 hi/lo Ph/Pl, 3-pass.
// ---------------------------------------------------------------------------
__global__ __launch_bounds__(256) void k_scores_bf(const unsigned short* __restrict__ Ph,
                                                   const unsigned short* __restrict__ Pl,
                                                   const int* __restrict__ mask,
                                                   float* __restrict__ S) {
  __shared__ __align__(16) char smem[65536];

  const int tid = threadIdx.x;
  const int swz = ((int)blockIdx.x % 8) * 72 + (int)blockIdx.x / 8;
  const int bb = swz / 36;
  const int pr = swz % 36;
  int ti = 0;
  while ((ti + 1) * (ti + 2) / 2 <= pr) ++ti;
  const int tj = pr - ti * (ti + 1) / 2;
  const int l0 = ti * 128, m0 = tj * 128;
  const int lane = tid & 63, wave = tid >> 6;
  const int wr = wave >> 1, wc = wave & 1;
  const int fr = lane & 15, kg = lane >> 4;
  f32x4 acc[4][4];
#pragma unroll
  for (int i = 0; i < 4; ++i)
#pragma unroll
    for (int j = 0; j < 4; ++j) acc[i][j] = 0;

  const size_t arow0 = (size_t)bb * L_ + l0;
  const size_t brow0 = (size_t)bb * L_ + m0;

  stage_panel(Ph, Pl, arow0, 0, smem, wave, lane);
  stage_panel(Ph, Pl, brow0, 0, smem + 16384, wave, lane);
  __syncthreads();

  int cur = 0;
  for (int it = 0; it < D_ / 32; ++it) {
    char* cb = smem + cur * 32768;
    if (it + 1 < D_ / 32) {
      char* nb = smem + (cur ^ 1) * 32768;
      stage_panel(Ph, Pl, arow0, (it + 1) * 32, nb, wave, lane);
      stage_panel(Ph, Pl, brow0, (it + 1) * 32, nb + 16384, wave, lane);
    }
    bf16x8 fah[4], fal[4], fbh[4], fbl[4];
#pragma unroll
    for (int i = 0; i < 4; ++i) {
      const int ra = wr * 64 + i * 16 + fr;
      const int rb = wc * 64 + i * 16 + fr;
      fah[i] = ldsfrag(cb, ra, kg);
      fal[i] = ldsfrag(cb, ra, kg + 4);
      fbh[i] = ldsfrag(cb + 16384, rb, kg);
      fbl[i] = ldsfrag(cb + 16384, rb, kg + 4);
    }
#pragma unroll
    for (int i = 0; i < 4; ++i)
#pragma unroll
      for (int j = 0; j < 4; ++j) {
        acc[i][j] = __builtin_amdgcn_mfma_f32_16x16x32_bf16(fah[i], fbh[j], acc[i][j], 0, 0, 0);
        acc[i][j] = __builtin_amdgcn_mfma_f32_16x16x32_bf16(fah[i], fbl[j], acc[i][j], 0, 0, 0);
        acc[i][j] = __builtin_amdgcn_mfma_f32_16x16x32_bf16(fal[i], fbh[j], acc[i][j], 0, 0, 0);
      }
    __syncthreads();
    cur ^= 1;
  }

  float* scr = (float*)smem + wave * 1280;
  const int row = lane >> 2, seg = lane & 3;
  for (int i = 0; i < 4; ++i) {
    __syncthreads();
#pragma unroll
    for (int j = 0; j < 4; ++j)
#pragma unroll
      for (int r = 0; r < 4; ++r)
        scr[(kg * 4 + r) * 68 + j * 16 + fr] = acc[i][j][r];
    __syncthreads();
    const int gl = l0 + wr * 64 + i * 16 + row;
    const int gm0 = m0 + wc * 64 + seg * 16;
    const size_t sbase = ((size_t)bb * L_ + gl) * L_ + gm0;
#pragma unroll
    for (int t = 0; t < 4; ++t) {
      float4 o = *(const float4*)&scr[row * 68 + seg * 16 + t * 4];
      const int4 mk = *(const int4*)(mask + bb * L_ + gm0 + t * 4);
      float* op = (float*)&o;
      const int* mp = (const int*)&mk;
#pragma unroll
      for (int e = 0; e < 4; ++e) {
        const int gm = gm0 + t * 4 + e;
        if (gm == gl) op[e] = 0.f;
        if (mp[e]) op[e] = -INFINITY;
      }
      *(float4*)(S + sbase + t * 4) = o;
    }
  }

  if (ti != tj) {
    __syncthreads();
#pragma unroll
    for (int j = 0; j < 4; ++j) {
      const int mloc = wc * 64 + j * 16 + fr;
#pragma unroll
      for (int i = 0; i < 4; ++i) {
        const int slot = wr * 16 + i * 4 + kg;
        const int xs = slot ^ (mloc & 7);
        *(f32x4*)(smem + mloc * 512 + xs * 16) = acc[i][j];
      }
    }
    __syncthreads();
    const int mrow = tid >> 1, half = tid & 1;
    const size_t sbase = ((size_t)bb * L_ + m0 + mrow) * L_ + l0;
#pragma unroll
    for (int q = 0; q < 16; ++q) {
      const int slot = half * 16 + q;
      const int xs = slot ^ (mrow & 7);
      float4 o = *(const float4*)(smem + mrow * 512 + xs * 16);
      const int4 mk = *(const int4*)(mask + bb * L_ + l0 + slot * 4);
      if (mk.x) o.x = -INFINITY;
      if (mk.y) o.y = -INFINITY;
      if (mk.z) o.z = -INFINITY;
      if (mk.w) o.w = -INFINITY;
      *(float4*)(S + sbase + slot * 4) = o;
    }
  }
}

// ---------------------------------------------------------------------------
// K3: in-place row softmax; when a16 != null, scatter-writes the COMPACTED
// fp16 alpha (valid columns only, at psum positions).
// ---------------------------------------------------------------------------
__global__ __launch_bounds__(256) void k_softmax(float* __restrict__ S,
                                                 unsigned short* __restrict__ a16,
                                                 const int* __restrict__ psum,
                                                 const int* __restrict__ canon) {
  const size_t row = blockIdx.x;
  float4* rp = (float4*)(S + row * L_);
  float4 v = rp[threadIdx.x];
  float mx = fmaxf(fmaxf(v.x, v.y), fmaxf(v.z, v.w));
#pragma unroll
  for (int o = 32; o > 0; o >>= 1) mx = fmaxf(mx, __shfl_xor(mx, o));
  __shared__ float rmax[4], rsum[4];
  const int wv = threadIdx.x >> 6, ln = threadIdx.x & 63;
  if (ln == 0) rmax[wv] = mx;
  __syncthreads();
  mx = fmaxf(fmaxf(rmax[0], rmax[1]), fmaxf(rmax[2], rmax[3]));
  float4 e;
  e.x = __expf(v.x - mx); e.y = __expf(v.y - mx);
  e.z = __expf(v.z - mx); e.w = __expf(v.w - mx);
  float s = (e.x + e.y) + (e.z + e.w);
#pragma unroll
  for (int o = 32; o > 0; o >>= 1) s += __shfl_xor(s, o);
  if (ln == 0) rsum[wv] = s;
  __syncthreads();
  s = (rsum[0] + rsum[1]) + (rsum[2] + rsum[3]);
  const float inv = 1.0f / s;
  e.x *= inv; e.y *= inv; e.z *= inv; e.w *= inv;
  rp[threadIdx.x] = e;
  if (a16) {
    const int bbat = (int)(row >> 10);
    const int m0 = threadIdx.x * 4;
    const int4 mk = *(const int4*)(canon + bbat * L_ + m0);
    const int4 ps = *(const int4*)(psum + bbat * L_ + m0);
    unsigned short* arow = a16 + row * L_;
    if (!mk.x) arow[ps.x] = f2h(e.x);
    if (!mk.y) arow[ps.y] = f2h(e.y);
    if (!mk.z) arow[ps.z] = f2h(e.z);
    if (!mk.w) arow[ps.w] = f2h(e.w);
  }
}

// ---------------------------------------------------------------------------
// K5 v4 (MFMA): align = a16c·Xtc^T per batch, COMPACTED K (valid tokens only,
// zero-padded to nt*64). Dynamic K-loop bound from kinfo. Exact transform.
// ---------------------------------------------------------------------------
__global__ __launch_bounds__(256) void k_align2(const unsigned short* __restrict__ A16,
                                                const unsigned short* __restrict__ Xt,
                                                const int* __restrict__ kinfo,
                                                float* __restrict__ O) {
  __shared__ __align__(16) char smem[65536];
  const int tid = threadIdx.x;
  const int swz = ((int)blockIdx.x % 8) * 96 + (int)blockIdx.x / 8;
  const int bb = swz / 48;
  const int l0 = ((swz / 6) % 8) * 128;
  const int n0 = (swz % 6) * 128;
  const int nt = kinfo[bb];
  const int lane = tid & 63, wave = tid >> 6;
  const int wr = wave >> 1, wc = wave & 1;
  const int fr = lane & 15, kg = lane >> 4;
  f32x4 acc[4][4];
#pragma unroll
  for (int i = 0; i < 4; ++i)
#pragma unroll
    for (int j = 0; j < 4; ++j) acc[i][j] = 0;

  const unsigned short* a0 = A16 + ((size_t)bb * L_ + l0) * L_;
  const unsigned short* b0 = Xt + ((size_t)bb * D_ + n0) * L_;

  if (nt > 0) {
    stage_panel1(a0, L_, smem, wave, lane);
    stage_panel1(b0, L_, smem + 16384, wave, lane);
  }
  __syncthreads();

  int cur = 0;
  for (int it = 0; it < nt; ++it) {
    char* cb = smem + cur * 32768;
    if (it + 1 < nt) {
      char* nb = smem + (cur ^ 1) * 32768;
      stage_panel1(a0 + (it + 1) * 64, L_, nb, wave, lane);
      stage_panel1(b0 + (it + 1) * 64, L_, nb + 16384, wave, lane);
    }
    half8 fa[2][4], fb[2][4];
#pragma unroll
    for (int i = 0; i < 4; ++i) {
      const int ra = wr * 64 + i * 16 + fr;
      const int rb = wc * 64 + i * 16 + fr;
#pragma unroll
      for (int ks = 0; ks < 2; ++ks) {
        fa[ks][i] = ldsfrag_h(cb, ra, ks * 4 + kg);
        fb[ks][i] = ldsfrag_h(cb + 16384, rb, ks * 4 + kg);
      }
    }
#pragma unroll
    for (int ks = 0; ks < 2; ++ks)
#pragma unroll
      for (int i = 0; i < 4; ++i)
#pragma unroll
        for (int j = 0; j < 4; ++j)
          acc[i][j] = __builtin_amdgcn_mfma_f32_16x16x32_f16(fa[ks][i], fb[ks][j],
                                                             acc[i][j], 0, 0, 0);
    __syncthreads();
    cur ^= 1;
  }

  float* scr = (float*)smem + wave * 1280;
  const int row = lane >> 2, seg = lane & 3;
  for (int i = 0; i < 4; ++i) {
    __syncthreads();
#pragma unroll
    for (int j = 0; j < 4; ++j)
#pragma unroll
      for (int r = 0; r < 4; ++r)
        scr[(kg * 4 + r) * 68 + j * 16 + fr] = acc[i][j][r];
    __syncthreads();
    const int gl = l0 + wr * 64 + i * 16 + row;
    const int gc0 = n0 + wc * 64 + seg * 16;
    const size_t obase = ((size_t)bb * L_ + gl) * D_ + gc0;
#pragma unroll
    for (int t = 0; t < 4; ++t) {
      const float4 o = *(const float4*)&scr[row * 68 + seg * 16 + t * 4];
      *(float4*)(O + obase + t * 4) = o;
    }
  }
}

// ---------------------------------------------------------------------------
// K5 fallback (r6): align = alpha(f32)·Xt^T (bf16 Xt), staging conversion.
// ---------------------------------------------------------------------------
__global__ __launch_bounds__(256) void k_align(const float* __restrict__ A,
                                               const unsigned short* __restrict__ Xt,
                                               float* __restrict__ O) {
  __shared__ __align__(16) unsigned short smem[2 * 128 * 32];
  __shared__ __align__(16) float scr_s[4 * 1104];
  unsigned short (*Ab)[32] = (unsigned short(*)[32])smem;
  unsigned short (*Bb)[32] = (unsigned short(*)[32])(smem + 128 * 32);

  const int tid = threadIdx.x;
  const int swz = ((int)blockIdx.x % 8) * 96 + (int)blockIdx.x / 8;
  const int bb = swz / 48;
  const int l0 = ((swz / 6) % 8) * 128;
  const int n0 = (swz % 6) * 128;
  const int lane = tid & 63, wave = tid >> 6;
  const int wr = wave >> 1, wc = wave & 1;
  const int fr = lane & 15, kg = lane >> 4;
  f32x4 acc[4][4];
#pragma unroll
  for (int i = 0; i < 4; ++i)
#pragma unroll
    for (int j = 0; j < 4; ++j) acc[i][j] = 0;

  float4 av[4];
  uint4 bv[2];
#pragma unroll
  for (int p = 0; p < 4; ++p) {
    const int f = tid + p * 256, r = f >> 3, c = f & 7;
    av[p] = *(const float4*)(A + ((size_t)bb * L_ + l0 + r) * L_ + c * 4);
  }
#pragma unroll
  for (int p = 0; p < 2; ++p) {
    const int f = tid + p * 256, r = f >> 2, sl = f & 3;
    bv[p] = *(const uint4*)(Xt + ((size_t)bb * D_ + n0 + r) * L_ + sl * 8);
  }

  for (int it = 0; it < L_ / 32; ++it) {
    __syncthreads();
#pragma unroll
    for (int p = 0; p < 4; ++p) {
      const int f = tid + p * 256, r = f >> 3, c = f & 7;
      *(ushort4*)&Ab[r][c * 4] = make_ushort4(f2bf(av[p].x), f2bf(av[p].y),
                                              f2bf(av[p].z), f2bf(av[p].w));
    }
#pragma unroll
    for (int p = 0; p < 2; ++p) {
      const int f = tid + p * 256, r = f >> 2, sl = f & 3;
      *(uint4*)&Bb[r][sl * 8] = bv[p];
    }
    __syncthreads();
    if (it + 1 < L_ / 32) {
      const int kk = (it + 1) * 32;
#pragma unroll
      for (int p = 0; p < 4; ++p) {
        const int f = tid + p * 256, r = f >> 3, c = f & 7;
        av[p] = *(const float4*)(A + ((size_t)bb * L_ + l0 + r) * L_ + kk + c * 4);
      }
#pragma unroll
      for (int p = 0; p < 2; ++p) {
        const int f = tid + p * 256, r = f >> 2, sl = f & 3;
        bv[p] = *(const uint4*)(Xt + ((size_t)bb * D_ + n0 + r) * L_ + kk + sl * 8);
      }
    }
    bf16x8 fa[4], fb[4];
#pragma unroll
    for (int i = 0; i < 4; ++i) {
      fa[i] = *(const bf16x8*)&Ab[wr * 64 + i * 16 + fr][kg * 8];
      fb[i] = *(const bf16x8*)&Bb[wc * 64 + i * 16 + fr][kg * 8];
    }
#pragma unroll
    for (int i = 0; i < 4; ++i)
#pragma unroll
      for (int j = 0; j < 4; ++j)
        acc[i][j] = __builtin_amdgcn_mfma_f32_16x16x32_bf16(fa[i], fb[j], acc[i][j], 0, 0, 0);
  }

  float* scr = scr_s + wave * 1104;
  const int row = lane >> 2, seg = lane & 3;
  for (int i = 0; i < 4; ++i) {
    __syncthreads();
#pragma unroll
    for (int j = 0; j < 4; ++j)
#pragma unroll
      for (int r = 0; r < 4; ++r)
        scr[(kg * 4 + r) * 68 + j * 16 + fr] = acc[i][j][r];
    __syncthreads();
    const int gl = l0 + wr * 64 + i * 16 + row;
    const int gc0 = n0 + wc * 64 + seg * 16;
    const size_t obase = ((size_t)bb * L_ + gl) * D_ + gc0;
#pragma unroll
    for (int t = 0; t < 4; ++t) {
      const float4 o = *(const float4*)&scr[row * 68 + seg * 16 + t * 4];
      *(float4*)(O + obase + t * 4) = o;
    }
  }
}

// ---------------------------------------------------------------------------
extern "C" void kernel_launch(void* const* d_in, const int* in_sizes, int n_in,
                              void* d_out, int out_size, void* d_ws, size_t ws_size,
                              hipStream_t stream) {
  const float* X    = (const float*)d_in[0];  // [B,L,D]
  const void*  mraw = d_in[1];                // [B,L] bool/int
  const float* W    = (const float*)d_in[2];  // [D,D]
  const float* bias = (const float*)d_in[3];  // [D]

  float* out   = (float*)d_out;
  float* align = out;                          // B*L*D fp32 (48MB)
  float* alpha = out + (size_t)B_ * L_ * D_;   // B*L*L fp32 (64MB)

  const size_t NX = (size_t)B_ * L_ * D_;   // 12,582,912
  const size_t NW = (size_t)D_ * D_;        // 589,824
  const size_t NA = (size_t)B_ * L_ * L_;   // 16,777,216

  // ws layout: maskC(64K) | psum(64K) | kinfo(4K) | Xtc | Wh | Wl ;
  // a16c overlays Wh/Wl (dead after proj2).
  int* maskC = (int*)d_ws;
  int* psum  = (int*)((char*)d_ws + 65536);
  int* kinfo = (int*)((char*)d_ws + 131072);
  const size_t offXt = 135168;
  unsigned short* Xt = (unsigned short*)((char*)d_ws + offXt);
  const size_t offWh = offXt + NX * 2;
  const size_t offWl = offWh + NW * 2;
  const size_t offA16 = offWh;
  const size_t need = offA16 + NA * 2;  // ~58.9 MB

  hipLaunchKernelGGL(k_mask2, dim3(16), dim3(256), 0, stream, mraw, maskC, psum, kinfo);

  if (ws_size >= need) {
    unsigned short* Xh = (unsigned short*)alpha;   // alpha region dead until scores
    unsigned short* Xl = Xh + NX;
    unsigned short* Wh = (unsigned short*)((char*)d_ws + offWh);
    unsigned short* Wl = (unsigned short*)((char*)d_ws + offWl);
    unsigned short* Pf = (unsigned short*)align;   // align region dead until k_align2
    unsigned short* A16 = (unsigned short*)((char*)d_ws + offA16);
    hipLaunchKernelGGL(k_prep, dim3(D_ / 64, L_ / 64, B_), dim3(256), 0, stream,
                       X, Xh, Xl, Xt, psum, maskC, 1, 1);
    hipLaunchKernelGGL(k_split, dim3((int)(NW / 8 / 256)), dim3(256), 0, stream,
                       W, Wh, Wl, (int)(NW / 8));
    hipLaunchKernelGGL(k_proj2, dim3(768), dim3(256), 0, stream,
                       Xh, Xl, Wh, Wl, bias, Pf);
    hipLaunchKernelGGL(k_scores, dim3(576), dim3(256), 0, stream, Pf, maskC, alpha);
    hipLaunchKernelGGL(k_softmax, dim3(B_ * L_), dim3(256), 0, stream,
                       alpha, A16, psum, maskC);
    // pad AFTER proj2 (a16c overlays Wh/Wl) and before align2 reads.
    hipLaunchKernelGGL(k_pad, dim3(16, 28), dim3(256), 0, stream, Xt, A16, kinfo);
    hipLaunchKernelGGL(k_align2, dim3(768), dim3(256), 0, stream, A16, Xt, kinfo, align);
  } else {
    // fallback: full bf16 path, non-compacted Xt.
    unsigned short* Ph = (unsigned short*)align;
    unsigned short* Pl = Ph + NX;
    hipLaunchKernelGGL(k_prep, dim3(D_ / 64, L_ / 64, B_), dim3(256), 0, stream,
                       X, (unsigned short*)alpha, (unsigned short*)alpha + NX, Xt,
                       psum, maskC, 0, 0);
    hipLaunchKernelGGL(k_proj, dim3(768), dim3(256), 0, stream, X, W, bias, Ph, Pl);
    hipLaunchKernelGGL(k_scores_bf, dim3(576), dim3(256), 0, stream, Ph, Pl, maskC, alpha);
    hipLaunchKernelGGL(k_softmax, dim3(B_ * L_), dim3(256), 0, stream,
                       alpha, (unsigned short*)nullptr, psum, maskC);
    hipLaunchKernelGGL(k_align, dim3(768), dim3(256), 0, stream, alpha, Xt, align);
  }
}

// Round 11
// 167.450 us; speedup vs baseline: 1.8716x; 1.2689x over previous
//
#include <hip/hip_runtime.h>
#include <math.h>

// Problem constants
#define B_ 16
#define L_ 1024
#define D_ 768

typedef short bf16x8 __attribute__((ext_vector_type(8)));
typedef _Float16 half8 __attribute__((ext_vector_type(8)));
typedef float f32x4 __attribute__((ext_vector_type(4)));

// round-to-nearest-even f32 -> bf16 (bit trick; inputs never NaN)
__device__ __forceinline__ unsigned short f2bf(float x) {
  unsigned u = __float_as_uint(x);
  u = (u + 0x7FFFu + ((u >> 16) & 1u)) >> 16;
  return (unsigned short)u;
}
__device__ __forceinline__ float bf2f(unsigned short h) {
  return __uint_as_float(((unsigned)h) << 16);
}
// f32 -> fp16 bits (RTN)
__device__ __forceinline__ unsigned short f2h(float x) {
  union { _Float16 h; unsigned short u; } v;
  v.h = (_Float16)x;
  return v.u;
}

// ---------------------------------------------------------------------------
// K0 v2: canonicalize mask (dtype auto-detect) AND per-batch validity
// prefix-sum (psum, exclusive) + kinfo[b]=nt tiles, kinfo[16+b]=valid count.
// ---------------------------------------------------------------------------
__global__ __launch_bounds__(256) void k_mask2(const void* __restrict__ mraw,
                                               int* __restrict__ canon,
                                               int* __restrict__ psum,
                                               int* __restrict__ kinfo) {
  __shared__ int flags[2];
  __shared__ int tsum[256];
  const int b = blockIdx.x;
  const int tid = threadIdx.x;
  if (tid < 2) flags[tid] = 0;
  __syncthreads();
  const unsigned* m32 = (const unsigned*)mraw;
  int gt = 0, oddnz = 0;
  for (int i = tid; i < 4096; i += 256) {
    unsigned v = m32[i];
    if (v > 1u) gt = 1;
    if ((i & 1) && v != 0u) oddnz = 1;
  }
  if (gt) atomicOr(&flags[0], 1);
  if (oddnz) atomicOr(&flags[1], 1);
  __syncthreads();
  const int mode = flags[0] ? 0 : (flags[1] ? 1 : 2);  // 0=u8, 1=i32, 2=i64
  int v[4];
#pragma unroll
  for (int e = 0; e < 4; ++e) {
    const int i = b * L_ + tid * 4 + e;
    int mv;
    if (mode == 0)      mv = ((const unsigned char*)mraw)[i];
    else if (mode == 1) mv = ((const int*)mraw)[i];
    else                mv = (int)(((const long long*)mraw)[i] != 0);
    v[e] = (mv != 0);          // 1 = padding
    canon[i] = v[e];
  }
  const int vc = (1 - v[0]) + (1 - v[1]) + (1 - v[2]) + (1 - v[3]);
  tsum[tid] = vc;
  __syncthreads();
  for (int off = 1; off < 256; off <<= 1) {
    const int t = (tid >= off) ? tsum[tid - off] : 0;
    __syncthreads();
    tsum[tid] += t;
    __syncthreads();
  }
  int run = tsum[tid] - vc;  // exclusive prefix
#pragma unroll
  for (int e = 0; e < 4; ++e) {
    psum[b * L_ + tid * 4 + e] = run;
    run += 1 - v[e];
  }
  if (tid == 255) {
    const int tot = tsum[255];
    kinfo[b] = (tot + 63) >> 6;
    kinfo[16 + b] = tot;
  }
}

// ---------------------------------------------------------------------------
// K-prep16 (fast path): one pass over X -> Xf (fp16, X layout) and Xtc
// (fp16 transposed, compacted valid columns).
// ---------------------------------------------------------------------------
__global__ __launch_bounds__(256) void k_prep16(const float* __restrict__ X,
                                                unsigned short* __restrict__ Xf,
                                                unsigned short* __restrict__ Xt,
                                                const int* __restrict__ psum,
                                                const int* __restrict__ canon) {
  __shared__ unsigned short t16[64][66];
  const int b = blockIdx.z;
  const int d0 = blockIdx.x * 64, m0 = blockIdx.y * 64;
  const int dd = threadIdx.x & 63, mq = threadIdx.x >> 6;
#pragma unroll
  for (int i = 0; i < 16; ++i) {
    const int m = mq * 16 + i;
    const size_t gidx = ((size_t)b * L_ + m0 + m) * D_ + d0 + dd;
    const unsigned short h = f2h(X[gidx]);
    Xf[gidx] = h;
    t16[dd][m] = h;
  }
  __syncthreads();
  const int mm = threadIdx.x & 63, dq = threadIdx.x >> 6;
  const int gm = m0 + mm;
  if (!canon[b * L_ + gm]) {        // valid token -> compacted column
    const int j = psum[b * L_ + gm];
#pragma unroll
    for (int i = 0; i < 16; ++i) {
      const int d = dq * 16 + i;
      Xt[((size_t)b * D_ + d0 + d) * L_ + j] = t16[d][mm];
    }
  }
}

// ---------------------------------------------------------------------------
// K-prep (fallback): X -> Xh/Xl bf16 hi/lo + full bf16 Xt.
// ---------------------------------------------------------------------------
__global__ __launch_bounds__(256) void k_prep(const float* __restrict__ X,
                                              unsigned short* __restrict__ Xh,
                                              unsigned short* __restrict__ Xl,
                                              unsigned short* __restrict__ Xt) {
  __shared__ unsigned short t16[64][66];
  const int b = blockIdx.z;
  const int d0 = blockIdx.x * 64, m0 = blockIdx.y * 64;
  const int dd = threadIdx.x & 63, mq = threadIdx.x >> 6;
#pragma unroll
  for (int i = 0; i < 16; ++i) {
    const int m = mq * 16 + i;
    const size_t gidx = ((size_t)b * L_ + m0 + m) * D_ + d0 + dd;
    const float x = X[gidx];
    const unsigned short h = f2bf(x);
    Xh[gidx] = h;
    Xl[gidx] = f2bf(x - bf2f(h));
    t16[dd][m] = h;
  }
  __syncthreads();
  const int mm = threadIdx.x & 63, dq = threadIdx.x >> 6;
#pragma unroll
  for (int i = 0; i < 16; ++i) {
    const int d = dq * 16 + i;
    Xt[((size_t)b * D_ + d0 + d) * L_ + m0 + mm] = t16[d][mm];
  }
}

// ---------------------------------------------------------------------------
// K-pad: zero the [kvalid, nt*64) column tails of Xtc and a16c.
// ---------------------------------------------------------------------------
__global__ __launch_bounds__(256) void k_pad(unsigned short* __restrict__ Xtc,
                                             unsigned short* __restrict__ a16c,
                                             const int* __restrict__ kinfo) {
  const int b = blockIdx.x;
  const int nt64 = kinfo[b] * 64;
  const int kv = kinfo[16 + b];
  if (kv >= nt64) return;
  const int r = blockIdx.y * 64 + (threadIdx.x >> 2);
  const int cg = threadIdx.x & 3;
  unsigned short* base = (r < 768)
      ? Xtc + ((size_t)b * D_ + r) * L_
      : a16c + ((size_t)b * L_ + (r - 768)) * L_;
#pragma unroll
  for (int q = 0; q < 16; ++q) {
    const int c = kv + cg * 16 + q;
    if (c < nt64) base[c] = 0;
  }
}

// ---------------------------------------------------------------------------
// K-castW: W f32 -> fp16, 8 elems/thread.
// ---------------------------------------------------------------------------
__global__ __launch_bounds__(256) void k_castW(const float* __restrict__ W,
                                               unsigned short* __restrict__ Wf,
                                               int n8) {
  const int i = blockIdx.x * 256 + threadIdx.x;
  if (i >= n8) return;
  const float4 a = *(const float4*)(W + (size_t)i * 8);
  const float4 b = *(const float4*)(W + (size_t)i * 8 + 4);
  *(ushort4*)(Wf + (size_t)i * 8)     = make_ushort4(f2h(a.x), f2h(a.y), f2h(a.z), f2h(a.w));
  *(ushort4*)(Wf + (size_t)i * 8 + 4) = make_ushort4(f2h(b.x), f2h(b.y), f2h(b.z), f2h(b.w));
}

// ---------------------------------------------------------------------------
// Staging helpers: 128-row x 128B LDS panels, 16B slots XOR-swizzled via
// pre-swizzled global source (slot xs = s ^ (row&7)).
// ---------------------------------------------------------------------------
__device__ __forceinline__ void stage_panel(const unsigned short* __restrict__ ph,
                                            const unsigned short* __restrict__ pl,
                                            size_t grow0, int kk,
                                            char* ldsbase, int wave, int lane) {
#pragma unroll
  for (int q = 0; q < 4; ++q) {
    const int s = wave * 4 + q;
    const int row = s * 8 + (lane >> 3);
    const int xs = (lane & 7) ^ (row & 7);
    const unsigned short* src = (xs & 4) ? pl : ph;
    const unsigned short* g = src + (grow0 + row) * D_ + kk + (xs & 3) * 8;
    __builtin_amdgcn_global_load_lds(
        (const __attribute__((address_space(1))) void*)g,
        (__attribute__((address_space(3))) void*)(ldsbase + s * 1024),
        16, 0, 0);
  }
}

__device__ __forceinline__ void stage_panel1(const unsigned short* __restrict__ g0,
                                             size_t rstride,
                                             char* ldsbase, int wave, int lane) {
#pragma unroll
  for (int q = 0; q < 4; ++q) {
    const int s = wave * 4 + q;
    const int row = s * 8 + (lane >> 3);
    const int xs = (lane & 7) ^ (row & 7);
    const unsigned short* g = g0 + (size_t)row * rstride + xs * 8;
    __builtin_amdgcn_global_load_lds(
        (const __attribute__((address_space(1))) void*)g,
        (__attribute__((address_space(3))) void*)(ldsbase + s * 1024),
        16, 0, 0);
  }
}

__device__ __forceinline__ bf16x8 ldsfrag(const char* base, int row, int g) {
  return *(const bf16x8*)(base + row * 128 + ((g ^ (row & 7)) * 16));
}
__device__ __forceinline__ half8 ldsfrag_h(const char* base, int row, int g) {
  return *(const half8*)(base + row * 128 + ((g ^ (row & 7)) * 16));
}

// ---------------------------------------------------------------------------
// K1 v4 (MFMA): P = relu(Xf·Wf^T + b), SINGLE fp16 pass (P is stored fp16
// downstream anyway; compute rounding adds only ~2x to dS ~0.02, far under
// the 0.1 threshold). K-tile 64, 12 iters, 48KB LDS (A dbuf + B single),
// XCD-local m-outer/n-inner mapping.
// ---------------------------------------------------------------------------
__global__ __launch_bounds__(256) void k_proj3(const unsigned short* __restrict__ Xf,
                                               const unsigned short* __restrict__ Wf,
                                               const float* __restrict__ bias,
                                               unsigned short* __restrict__ Pf) {
  __shared__ __align__(16) char smem[49152];  // A: 2x16KB @0, B: 16KB @32KB
  const int tid = threadIdx.x;
  const int xcd = (int)blockIdx.x & 7;
  const int li  = (int)blockIdx.x >> 3;
  const int m0 = (xcd * 16 + li / 6) * 128;
  const int n0 = (li % 6) * 128;
  const int lane = tid & 63, wave = tid >> 6;
  const int wr = wave >> 1, wc = wave & 1;
  const int fr = lane & 15, kg = lane >> 4;
  f32x4 acc[4][4];
#pragma unroll
  for (int i = 0; i < 4; ++i)
#pragma unroll
    for (int j = 0; j < 4; ++j) acc[i][j] = 0;

  const unsigned short* a0 = Xf + (size_t)m0 * D_;
  const unsigned short* b0 = Wf + (size_t)n0 * D_;

  stage_panel1(a0, D_, smem, wave, lane);
  stage_panel1(b0, D_, smem + 32768, wave, lane);
  __syncthreads();

  int cur = 0;
  for (int it = 0; it < D_ / 64; ++it) {
    const char* ab = smem + cur * 16384;
    const char* bb = smem + 32768;
    half8 fa[2][4], fb[2][4];
#pragma unroll
    for (int i = 0; i < 4; ++i) {
      const int ra = wr * 64 + i * 16 + fr;
      const int rb = wc * 64 + i * 16 + fr;
#pragma unroll
      for (int ks = 0; ks < 2; ++ks) {
        fa[ks][i] = ldsfrag_h(ab, ra, ks * 4 + kg);
        fb[ks][i] = ldsfrag_h(bb, rb, ks * 4 + kg);
      }
    }
    __syncthreads();  // all reads done -> safe to overwrite B / stage next A
    if (it + 1 < D_ / 64) {
      stage_panel1(a0 + (it + 1) * 64, D_, smem + (cur ^ 1) * 16384, wave, lane);
      stage_panel1(b0 + (it + 1) * 64, D_, smem + 32768, wave, lane);
    }
#pragma unroll
    for (int ks = 0; ks < 2; ++ks)
#pragma unroll
      for (int i = 0; i < 4; ++i)
#pragma unroll
        for (int j = 0; j < 4; ++j)
          acc[i][j] = __builtin_amdgcn_mfma_f32_16x16x32_f16(fa[ks][i], fb[ks][j],
                                                             acc[i][j], 0, 0, 0);
    __syncthreads();  // drains vmcnt -> next buffers ready
    cur ^= 1;
  }

  // Epilogue: bias+relu -> fp16; LDS transpose; 2x uint4 per lane.
  unsigned short* scr = (unsigned short*)smem + wave * 1152;  // [16][72]/wave
  const int row = lane >> 2, seg = lane & 3;
  float bj[4];
#pragma unroll
  for (int j = 0; j < 4; ++j) bj[j] = bias[n0 + wc * 64 + j * 16 + fr];
  for (int i = 0; i < 4; ++i) {
    __syncthreads();
#pragma unroll
    for (int j = 0; j < 4; ++j)
#pragma unroll
      for (int r = 0; r < 4; ++r)
        scr[(kg * 4 + r) * 72 + j * 16 + fr] = f2h(fmaxf(acc[i][j][r] + bj[j], 0.f));
    __syncthreads();
    const size_t gr = (size_t)(m0 + wr * 64 + i * 16 + row);
    const int gc0 = n0 + wc * 64 + seg * 16;
    const uint4 h0 = *(const uint4*)&scr[row * 72 + seg * 16];
    const uint4 h1 = *(const uint4*)&scr[row * 72 + seg * 16 + 8];
    *(uint4*)(Pf + gr * D_ + gc0)     = h0;
    *(uint4*)(Pf + gr * D_ + gc0 + 8) = h1;
  }
}

// ---------------------------------------------------------------------------
// K1 fallback (r5): on-the-fly split proj -> bf16 Ph/Pl (used if ws small).
// ---------------------------------------------------------------------------
__global__ __launch_bounds__(256) void k_proj(const float* __restrict__ X,
                                              const float* __restrict__ W,
                                              const float* __restrict__ bias,
                                              unsigned short* __restrict__ Ph,
                                              unsigned short* __restrict__ Pl) {
  __shared__ __align__(16) unsigned short smem[4 * 128 * 32];
  unsigned short (*Ah)[32] = (unsigned short(*)[32])smem;
  unsigned short (*Al)[32] = (unsigned short(*)[32])(smem + 1 * 128 * 32);
  unsigned short (*Bh)[32] = (unsigned short(*)[32])(smem + 2 * 128 * 32);
  unsigned short (*Bl)[32] = (unsigned short(*)[32])(smem + 3 * 128 * 32);

  const int tid = threadIdx.x;
  const int swz = ((int)blockIdx.x % 8) * 96 + (int)blockIdx.x / 8;
  const int m0 = (swz / 6) * 128, n0 = (swz % 6) * 128;
  const int lane = tid & 63, wave = tid >> 6;
  const int wr = wave >> 1, wc = wave & 1;
  const int fr = lane & 15, kg = lane >> 4;
  f32x4 acc[4][4];
#pragma unroll
  for (int i = 0; i < 4; ++i)
#pragma unroll
    for (int j = 0; j < 4; ++j) acc[i][j] = 0;

  float4 av[4], bv[4];
#pragma unroll
  for (int p = 0; p < 4; ++p) {
    const int f = tid + p * 256, r = f >> 3, c = f & 7;
    av[p] = *(const float4*)(X + (size_t)(m0 + r) * D_ + c * 4);
    bv[p] = *(const float4*)(W + (size_t)(n0 + r) * D_ + c * 4);
  }

  for (int it = 0; it < D_ / 32; ++it) {
    __syncthreads();
#pragma unroll
    for (int p = 0; p < 4; ++p) {
      const int f = tid + p * 256, r = f >> 3, c = f & 7;
      {
        const float x0 = av[p].x, x1 = av[p].y, x2 = av[p].z, x3 = av[p].w;
        const unsigned short h0 = f2bf(x0), h1 = f2bf(x1), h2 = f2bf(x2), h3 = f2bf(x3);
        *(ushort4*)&Ah[r][c * 4] = make_ushort4(h0, h1, h2, h3);
        *(ushort4*)&Al[r][c * 4] = make_ushort4(f2bf(x0 - bf2f(h0)), f2bf(x1 - bf2f(h1)),
                                                f2bf(x2 - bf2f(h2)), f2bf(x3 - bf2f(h3)));
      }
      {
        const float x0 = bv[p].x, x1 = bv[p].y, x2 = bv[p].z, x3 = bv[p].w;
        const unsigned short h0 = f2bf(x0), h1 = f2bf(x1), h2 = f2bf(x2), h3 = f2bf(x3);
        *(ushort4*)&Bh[r][c * 4] = make_ushort4(h0, h1, h2, h3);
        *(ushort4*)&Bl[r][c * 4] = make_ushort4(f2bf(x0 - bf2f(h0)), f2bf(x1 - bf2f(h1)),
                                                f2bf(x2 - bf2f(h2)), f2bf(x3 - bf2f(h3)));
      }
    }
    __syncthreads();
    if (it + 1 < D_ / 32) {
      const int kk = (it + 1) * 32;
#pragma unroll
      for (int p = 0; p < 4; ++p) {
        const int f = tid + p * 256, r = f >> 3, c = f & 7;
        av[p] = *(const float4*)(X + (size_t)(m0 + r) * D_ + kk + c * 4);
        bv[p] = *(const float4*)(W + (size_t)(n0 + r) * D_ + kk + c * 4);
      }
    }
    bf16x8 fah[4], fal[4], fbh[4], fbl[4];
#pragma unroll
    for (int i = 0; i < 4; ++i) {
      fah[i] = *(const bf16x8*)&Ah[wr * 64 + i * 16 + fr][kg * 8];
      fal[i] = *(const bf16x8*)&Al[wr * 64 + i * 16 + fr][kg * 8];
      fbh[i] = *(const bf16x8*)&Bh[wc * 64 + i * 16 + fr][kg * 8];
      fbl[i] = *(const bf16x8*)&Bl[wc * 64 + i * 16 + fr][kg * 8];
    }
#pragma unroll
    for (int i = 0; i < 4; ++i)
#pragma unroll
      for (int j = 0; j < 4; ++j) {
        acc[i][j] = __builtin_amdgcn_mfma_f32_16x16x32_bf16(fah[i], fbh[j], acc[i][j], 0, 0, 0);
        acc[i][j] = __builtin_amdgcn_mfma_f32_16x16x32_bf16(fah[i], fbl[j], acc[i][j], 0, 0, 0);
        acc[i][j] = __builtin_amdgcn_mfma_f32_16x16x32_bf16(fal[i], fbh[j], acc[i][j], 0, 0, 0);
      }
  }

  unsigned short* scr = smem + wave * 2304;
  const int row = lane >> 2, seg = lane & 3;
  float bj[4];
#pragma unroll
  for (int j = 0; j < 4; ++j) bj[j] = bias[n0 + wc * 64 + j * 16 + fr];
  for (int i = 0; i < 4; ++i) {
    __syncthreads();
#pragma unroll
    for (int j = 0; j < 4; ++j)
#pragma unroll
      for (int r = 0; r < 4; ++r) {
        float v = fmaxf(acc[i][j][r] + bj[j], 0.f);
        const unsigned short h = f2bf(v);
        scr[(kg * 4 + r) * 72 + j * 16 + fr] = h;
        scr[1152 + (kg * 4 + r) * 72 + j * 16 + fr] = f2bf(v - bf2f(h));
      }
    __syncthreads();
    const size_t gr = (size_t)(m0 + wr * 64 + i * 16 + row);
    const int gc0 = n0 + wc * 64 + seg * 16;
    const uint4 h0 = *(const uint4*)&scr[row * 72 + seg * 16];
    const uint4 h1 = *(const uint4*)&scr[row * 72 + seg * 16 + 8];
    const uint4 q0 = *(const uint4*)&scr[1152 + row * 72 + seg * 16];
    const uint4 q1 = *(const uint4*)&scr[1152 + row * 72 + seg * 16 + 8];
    *(uint4*)(Ph + gr * D_ + gc0)     = h0;
    *(uint4*)(Ph + gr * D_ + gc0 + 8) = h1;
    *(uint4*)(Pl + gr * D_ + gc0)     = q0;
    *(uint4*)(Pl + gr * D_ + gc0 + 8) = q1;
  }
}

// ---------------------------------------------------------------------------
// K2 v2 (MFMA): S = Pf·Pf^T, single fp16 pass, symmetric pairs, K-tile 64.
// ---------------------------------------------------------------------------
__global__ __launch_bounds__(256) void k_scores(const unsigned short* __restrict__ Pf,
                                                const int* __restrict__ mask,
                                                float* __restrict__ S) {
  __shared__ __align__(16) char smem[65536];

  const int tid = threadIdx.x;
  const int swz = ((int)blockIdx.x % 8) * 72 + (int)blockIdx.x / 8;
  const int bb = swz / 36;
  const int pr = swz % 36;
  int ti = 0;
  while ((ti + 1) * (ti + 2) / 2 <= pr) ++ti;
  const int tj = pr - ti * (ti + 1) / 2;
  const int l0 = ti * 128, m0 = tj * 128;
  const int lane = tid & 63, wave = tid >> 6;
  const int wr = wave >> 1, wc = wave & 1;
  const int fr = lane & 15, kg = lane >> 4;
  f32x4 acc[4][4];
#pragma unroll
  for (int i = 0; i < 4; ++i)
#pragma unroll
    for (int j = 0; j < 4; ++j) acc[i][j] = 0;

  const unsigned short* a0 = Pf + ((size_t)bb * L_ + l0) * D_;
  const unsigned short* b0 = Pf + ((size_t)bb * L_ + m0) * D_;

  stage_panel1(a0, D_, smem, wave, lane);
  stage_panel1(b0, D_, smem + 16384, wave, lane);
  __syncthreads();

  int cur = 0;
  for (int it = 0; it < D_ / 64; ++it) {
    char* cb = smem + cur * 32768;
    if (it + 1 < D_ / 64) {
      char* nb = smem + (cur ^ 1) * 32768;
      stage_panel1(a0 + (it + 1) * 64, D_, nb, wave, lane);
      stage_panel1(b0 + (it + 1) * 64, D_, nb + 16384, wave, lane);
    }
    half8 fa[2][4], fb[2][4];
#pragma unroll
    for (int i = 0; i < 4; ++i) {
      const int ra = wr * 64 + i * 16 + fr;
      const int rb = wc * 64 + i * 16 + fr;
#pragma unroll
      for (int ks = 0; ks < 2; ++ks) {
        fa[ks][i] = ldsfrag_h(cb, ra, ks * 4 + kg);
        fb[ks][i] = ldsfrag_h(cb + 16384, rb, ks * 4 + kg);
      }
    }
#pragma unroll
    for (int ks = 0; ks < 2; ++ks)
#pragma unroll
      for (int i = 0; i < 4; ++i)
#pragma unroll
        for (int j = 0; j < 4; ++j)
          acc[i][j] = __builtin_amdgcn_mfma_f32_16x16x32_f16(fa[ks][i], fb[ks][j],
                                                             acc[i][j], 0, 0, 0);
    __syncthreads();
    cur ^= 1;
  }

  float* scr = (float*)smem + wave * 1280;
  const int row = lane >> 2, seg = lane & 3;
  for (int i = 0; i < 4; ++i) {
    __syncthreads();
#pragma unroll
    for (int j = 0; j < 4; ++j)
#pragma unroll
      for (int r = 0; r < 4; ++r)
        scr[(kg * 4 + r) * 68 + j * 16 + fr] = acc[i][j][r];
    __syncthreads();
    const int gl = l0 + wr * 64 + i * 16 + row;
    const int gm0 = m0 + wc * 64 + seg * 16;
    const size_t sbase = ((size_t)bb * L_ + gl) * L_ + gm0;
#pragma unroll
    for (int t = 0; t < 4; ++t) {
      float4 o = *(const float4*)&scr[row * 68 + seg * 16 + t * 4];
      const int4 mk = *(const int4*)(mask + bb * L_ + gm0 + t * 4);
      float* op = (float*)&o;
      const int* mp = (const int*)&mk;
#pragma unroll
      for (int e = 0; e < 4; ++e) {
        const int gm = gm0 + t * 4 + e;
        if (gm == gl) op[e] = 0.f;
        if (mp[e]) op[e] = -INFINITY;
      }
      *(float4*)(S + sbase + t * 4) = o;
    }
  }

  if (ti != tj) {
    __syncthreads();
#pragma unroll
    for (int j = 0; j < 4; ++j) {
      const int mloc = wc * 64 + j * 16 + fr;
#pragma unroll
      for (int i = 0; i < 4; ++i) {
        const int slot = wr * 16 + i * 4 + kg;
        const int xs = slot ^ (mloc & 7);
        *(f32x4*)(smem + mloc * 512 + xs * 16) = acc[i][j];
      }
    }
    __syncthreads();
    const int mrow = tid >> 1, half = tid & 1;
    const size_t sbase = ((size_t)bb * L_ + m0 + mrow) * L_ + l0;
#pragma unroll
    for (int q = 0; q < 16; ++q) {
      const int slot = half * 16 + q;
      const int xs = slot ^ (mrow & 7);
      float4 o = *(const float4*)(smem + mrow * 512 + xs * 16);
      const int4 mk = *(const int4*)(mask + bb * L_ + l0 + slot * 4);
      if (mk.x) o.x = -INFINITY;
      if (mk.y) o.y = -INFINITY;
      if (mk.z) o.z = -INFINITY;
      if (mk.w) o.w = -INFINITY;
      *(float4*)(S + sbase + slot * 4) = o;
    }
  }
}

// ---------------------------------------------------------------------------
// K2 fallback (r5): S = P·P^T from bf16 hi/lo Ph/Pl, 3-pass.
// ---------------------------------------------------------------------------
__global__ __launch_bounds__(256) void k_scores_bf(const unsigned short* __restrict__ Ph,
                                                   const unsigned short* __restrict__ Pl,
                                                   const int* __restrict__ mask,
                                                   float* __restrict__ S) {
  __shared__ __align__(16) char smem[65536];

  const int tid = threadIdx.x;
  const int swz = ((int)blockIdx.x % 8) * 72 + (int)blockIdx.x / 8;
  const int bb = swz / 36;
  const int pr = swz % 36;
  int ti = 0;
  while ((ti + 1) * (ti + 2) / 2 <= pr) ++ti;
  const int tj = pr - ti * (ti + 1) / 2;
  const int l0 = ti * 128, m0 = tj * 128;
  const int lane = tid & 63, wave = tid >> 6;
  const int wr = wave >> 1, wc = wave & 1;
  const int fr = lane & 15, kg = lane >> 4;
  f32x4 acc[4][4];
#pragma unroll
  for (int i = 0; i < 4; ++i)
#pragma unroll
    for (int j = 0; j < 4; ++j) acc[i][j] = 0;

  const size_t arow0 = (size_t)bb * L_ + l0;
  const size_t brow0 = (size_t)bb * L_ + m0;

  stage_panel(Ph, Pl, arow0, 0, smem, wave, lane);
  stage_panel(Ph, Pl, brow0, 0, smem + 16384, wave, lane);
  __syncthreads();

  int cur = 0;
  for (int it = 0; it < D_ / 32; ++it) {
    char* cb = smem + cur * 32768;
    if (it + 1 < D_ / 32) {
      char* nb = smem + (cur ^ 1) * 32768;
      stage_panel(Ph, Pl, arow0, (it + 1) * 32, nb, wave, lane);
      stage_panel(Ph, Pl, brow0, (it + 1) * 32, nb + 16384, wave, lane);
    }
    bf16x8 fah[4], fal[4], fbh[4], fbl[4];
#pragma unroll
    for (int i = 0; i < 4; ++i) {
      const int ra = wr * 64 + i * 16 + fr;
      const int rb = wc * 64 + i * 16 + fr;
      fah[i] = ldsfrag(cb, ra, kg);
      fal[i] = ldsfrag(cb, ra, kg + 4);
      fbh[i] = ldsfrag(cb + 16384, rb, kg);
      fbl[i] = ldsfrag(cb + 16384, rb, kg + 4);
    }
#pragma unroll
    for (int i = 0; i < 4; ++i)
#pragma unroll
      for (int j = 0; j < 4; ++j) {
        acc[i][j] = __builtin_amdgcn_mfma_f32_16x16x32_bf16(fah[i], fbh[j], acc[i][j], 0, 0, 0);
        acc[i][j] = __builtin_amdgcn_mfma_f32_16x16x32_bf16(fah[i], fbl[j], acc[i][j], 0, 0, 0);
        acc[i][j] = __builtin_amdgcn_mfma_f32_16x16x32_bf16(fal[i], fbh[j], acc[i][j], 0, 0, 0);
      }
    __syncthreads();
    cur ^= 1;
  }

  float* scr = (float*)smem + wave * 1280;
  const int row = lane >> 2, seg = lane & 3;
  for (int i = 0; i < 4; ++i) {
    __syncthreads();
#pragma unroll
    for (int j = 0; j < 4; ++j)
#pragma unroll
      for (int r = 0; r < 4; ++r)
        scr[(kg * 4 + r) * 68 + j * 16 + fr] = acc[i][j][r];
    __syncthreads();
    const int gl = l0 + wr * 64 + i * 16 + row;
    const int gm0 = m0 + wc * 64 + seg * 16;
    const size_t sbase = ((size_t)bb * L_ + gl) * L_ + gm0;
#pragma unroll
    for (int t = 0; t < 4; ++t) {
      float4 o = *(const float4*)&scr[row * 68 + seg * 16 + t * 4];
      const int4 mk = *(const int4*)(mask + bb * L_ + gm0 + t * 4);
      float* op = (float*)&o;
      const int* mp = (const int*)&mk;
#pragma unroll
      for (int e = 0; e < 4; ++e) {
        const int gm = gm0 + t * 4 + e;
        if (gm == gl) op[e] = 0.f;
        if (mp[e]) op[e] = -INFINITY;
      }
      *(float4*)(S + sbase + t * 4) = o;
    }
  }

  if (ti != tj) {
    __syncthreads();
#pragma unroll
    for (int j = 0; j < 4; ++j) {
      const int mloc = wc * 64 + j * 16 + fr;
#pragma unroll
      for (int i = 0; i < 4; ++i) {
        const int slot = wr * 16 + i * 4 + kg;
        const int xs = slot ^ (mloc & 7);
        *(f32x4*)(smem + mloc * 512 + xs * 16) = acc[i][j];
      }
    }
    __syncthreads();
    const int mrow = tid >> 1, half = tid & 1;
    const size_t sbase = ((size_t)bb * L_ + m0 + mrow) * L_ + l0;
#pragma unroll
    for (int q = 0; q < 16; ++q) {
      const int slot = half * 16 + q;
      const int xs = slot ^ (mrow & 7);
      float4 o = *(const float4*)(smem + mrow * 512 + xs * 16);
      const int4 mk = *(const int4*)(mask + bb * L_ + l0 + slot * 4);
      if (mk.x) o.x = -INFINITY;
      if (mk.y) o.y = -INFINITY;
      if (mk.z) o.z = -INFINITY;
      if (mk.w) o.w = -INFINITY;
      *(float4*)(S + sbase + slot * 4) = o;
    }
  }
}

// ---------------------------------------------------------------------------
// K3: in-place row softmax; when a16 != null, scatter-writes the COMPACTED
// fp16 alpha (valid columns only, at psum positions).
// ---------------------------------------------------------------------------
__global__ __launch_bounds__(256) void k_softmax(float* __restrict__ S,
                                                 unsigned short* __restrict__ a16,
                                                 const int* __restrict__ psum,
                                                 const int* __restrict__ canon) {
  const size_t row = blockIdx.x;
  float4* rp = (float4*)(S + row * L_);
  float4 v = rp[threadIdx.x];
  float mx = fmaxf(fmaxf(v.x, v.y), fmaxf(v.z, v.w));
#pragma unroll
  for (int o = 32; o > 0; o >>= 1) mx = fmaxf(mx, __shfl_xor(mx, o));
  __shared__ float rmax[4], rsum[4];
  const int wv = threadIdx.x >> 6, ln = threadIdx.x & 63;
  if (ln == 0) rmax[wv] = mx;
  __syncthreads();
  mx = fmaxf(fmaxf(rmax[0], rmax[1]), fmaxf(rmax[2], rmax[3]));
  float4 e;
  e.x = __expf(v.x - mx); e.y = __expf(v.y - mx);
  e.z = __expf(v.z - mx); e.w = __expf(v.w - mx);
  float s = (e.x + e.y) + (e.z + e.w);
#pragma unroll
  for (int o = 32; o > 0; o >>= 1) s += __shfl_xor(s, o);
  if (ln == 0) rsum[wv] = s;
  __syncthreads();
  s = (rsum[0] + rsum[1]) + (rsum[2] + rsum[3]);
  const float inv = 1.0f / s;
  e.x *= inv; e.y *= inv; e.z *= inv; e.w *= inv;
  rp[threadIdx.x] = e;
  if (a16) {
    const int bbat = (int)(row >> 10);
    const int m0 = threadIdx.x * 4;
    const int4 mk = *(const int4*)(canon + bbat * L_ + m0);
    const int4 ps = *(const int4*)(psum + bbat * L_ + m0);
    unsigned short* arow = a16 + row * L_;
    if (!mk.x) arow[ps.x] = f2h(e.x);
    if (!mk.y) arow[ps.y] = f2h(e.y);
    if (!mk.z) arow[ps.z] = f2h(e.z);
    if (!mk.w) arow[ps.w] = f2h(e.w);
  }
}

// ---------------------------------------------------------------------------
// K5 v4 (MFMA): align = a16c·Xtc^T per batch, COMPACTED K, dynamic K-loop.
// ---------------------------------------------------------------------------
__global__ __launch_bounds__(256) void k_align2(const unsigned short* __restrict__ A16,
                                                const unsigned short* __restrict__ Xt,
                                                const int* __restrict__ kinfo,
                                                float* __restrict__ O) {
  __shared__ __align__(16) char smem[65536];
  const int tid = threadIdx.x;
  const int swz = ((int)blockIdx.x % 8) * 96 + (int)blockIdx.x / 8;
  const int bb = swz / 48;
  const int l0 = ((swz / 6) % 8) * 128;
  const int n0 = (swz % 6) * 128;
  const int nt = kinfo[bb];
  const int lane = tid & 63, wave = tid >> 6;
  const int wr = wave >> 1, wc = wave & 1;
  const int fr = lane & 15, kg = lane >> 4;
  f32x4 acc[4][4];
#pragma unroll
  for (int i = 0; i < 4; ++i)
#pragma unroll
    for (int j = 0; j < 4; ++j) acc[i][j] = 0;

  const unsigned short* a0 = A16 + ((size_t)bb * L_ + l0) * L_;
  const unsigned short* b0 = Xt + ((size_t)bb * D_ + n0) * L_;

  if (nt > 0) {
    stage_panel1(a0, L_, smem, wave, lane);
    stage_panel1(b0, L_, smem + 16384, wave, lane);
  }
  __syncthreads();

  int cur = 0;
  for (int it = 0; it < nt; ++it) {
    char* cb = smem + cur * 32768;
    if (it + 1 < nt) {
      char* nb = smem + (cur ^ 1) * 32768;
      stage_panel1(a0 + (it + 1) * 64, L_, nb, wave, lane);
      stage_panel1(b0 + (it + 1) * 64, L_, nb + 16384, wave, lane);
    }
    half8 fa[2][4], fb[2][4];
#pragma unroll
    for (int i = 0; i < 4; ++i) {
      const int ra = wr * 64 + i * 16 + fr;
      const int rb = wc * 64 + i * 16 + fr;
#pragma unroll
      for (int ks = 0; ks < 2; ++ks) {
        fa[ks][i] = ldsfrag_h(cb, ra, ks * 4 + kg);
        fb[ks][i] = ldsfrag_h(cb + 16384, rb, ks * 4 + kg);
      }
    }
#pragma unroll
    for (int ks = 0; ks < 2; ++ks)
#pragma unroll
      for (int i = 0; i < 4; ++i)
#pragma unroll
        for (int j = 0; j < 4; ++j)
          acc[i][j] = __builtin_amdgcn_mfma_f32_16x16x32_f16(fa[ks][i], fb[ks][j],
                                                             acc[i][j], 0, 0, 0);
    __syncthreads();
    cur ^= 1;
  }

  float* scr = (float*)smem + wave * 1280;
  const int row = lane >> 2, seg = lane & 3;
  for (int i = 0; i < 4; ++i) {
    __syncthreads();
#pragma unroll
    for (int j = 0; j < 4; ++j)
#pragma unroll
      for (int r = 0; r < 4; ++r)
        scr[(kg * 4 + r) * 68 + j * 16 + fr] = acc[i][j][r];
    __syncthreads();
    const int gl = l0 + wr * 64 + i * 16 + row;
    const int gc0 = n0 + wc * 64 + seg * 16;
    const size_t obase = ((size_t)bb * L_ + gl) * D_ + gc0;
#pragma unroll
    for (int t = 0; t < 4; ++t) {
      const float4 o = *(const float4*)&scr[row * 68 + seg * 16 + t * 4];
      *(float4*)(O + obase + t * 4) = o;
    }
  }
}

// ---------------------------------------------------------------------------
// K5 fallback (r6): align = alpha(f32)·Xt^T (bf16 Xt), staging conversion.
// ---------------------------------------------------------------------------
__global__ __launch_bounds__(256) void k_align(const float* __restrict__ A,
                                               const unsigned short* __restrict__ Xt,
                                               float* __restrict__ O) {
  __shared__ __align__(16) unsigned short smem[2 * 128 * 32];
  __shared__ __align__(16) float scr_s[4 * 1104];
  unsigned short (*Ab)[32] = (unsigned short(*)[32])smem;
  unsigned short (*Bb)[32] = (unsigned short(*)[32])(smem + 128 * 32);

  const int tid = threadIdx.x;
  const int swz = ((int)blockIdx.x % 8) * 96 + (int)blockIdx.x / 8;
  const int bb = swz / 48;
  const int l0 = ((swz / 6) % 8) * 128;
  const int n0 = (swz % 6) * 128;
  const int lane = tid & 63, wave = tid >> 6;
  const int wr = wave >> 1, wc = wave & 1;
  const int fr = lane & 15, kg = lane >> 4;
  f32x4 acc[4][4];
#pragma unroll
  for (int i = 0; i < 4; ++i)
#pragma unroll
    for (int j = 0; j < 4; ++j) acc[i][j] = 0;

  float4 av[4];
  uint4 bv[2];
#pragma unroll
  for (int p = 0; p < 4; ++p) {
    const int f = tid + p * 256, r = f >> 3, c = f & 7;
    av[p] = *(const float4*)(A + ((size_t)bb * L_ + l0 + r) * L_ + c * 4);
  }
#pragma unroll
  for (int p = 0; p < 2; ++p) {
    const int f = tid + p * 256, r = f >> 2, sl = f & 3;
    bv[p] = *(const uint4*)(Xt + ((size_t)bb * D_ + n0 + r) * L_ + sl * 8);
  }

  for (int it = 0; it < L_ / 32; ++it) {
    __syncthreads();
#pragma unroll
    for (int p = 0; p < 4; ++p) {
      const int f = tid + p * 256, r = f >> 3, c = f & 7;
      *(ushort4*)&Ab[r][c * 4] = make_ushort4(f2bf(av[p].x), f2bf(av[p].y),
                                              f2bf(av[p].z), f2bf(av[p].w));
    }
#pragma unroll
    for (int p = 0; p < 2; ++p) {
      const int f = tid + p * 256, r = f >> 2, sl = f & 3;
      *(uint4*)&Bb[r][sl * 8] = bv[p];
    }
    __syncthreads();
    if (it + 1 < L_ / 32) {
      const int kk = (it + 1) * 32;
#pragma unroll
      for (int p = 0; p < 4; ++p) {
        const int f = tid + p * 256, r = f >> 3, c = f & 7;
        av[p] = *(const float4*)(A + ((size_t)bb * L_ + l0 + r) * L_ + kk + c * 4);
      }
#pragma unroll
      for (int p = 0; p < 2; ++p) {
        const int f = tid + p * 256, r = f >> 2, sl = f & 3;
        bv[p] = *(const uint4*)(Xt + ((size_t)bb * D_ + n0 + r) * L_ + kk + sl * 8);
      }
    }
    bf16x8 fa[4], fb[4];
#pragma unroll
    for (int i = 0; i < 4; ++i) {
      fa[i] = *(const bf16x8*)&Ab[wr * 64 + i * 16 + fr][kg * 8];
      fb[i] = *(const bf16x8*)&Bb[wc * 64 + i * 16 + fr][kg * 8];
    }
#pragma unroll
    for (int i = 0; i < 4; ++i)
#pragma unroll
      for (int j = 0; j < 4; ++j)
        acc[i][j] = __builtin_amdgcn_mfma_f32_16x16x32_bf16(fa[i], fb[j], acc[i][j], 0, 0, 0);
  }

  float* scr = scr_s + wave * 1104;
  const int row = lane >> 2, seg = lane & 3;
  for (int i = 0; i < 4; ++i) {
    __syncthreads();
#pragma unroll
    for (int j = 0; j < 4; ++j)
#pragma unroll
      for (int r = 0; r < 4; ++r)
        scr[(kg * 4 + r) * 68 + j * 16 + fr] = acc[i][j][r];
    __syncthreads();
    const int gl = l0 + wr * 64 + i * 16 + row;
    const int gc0 = n0 + wc * 64 + seg * 16;
    const size_t obase = ((size_t)bb * L_ + gl) * D_ + gc0;
#pragma unroll
    for (int t = 0; t < 4; ++t) {
      const float4 o = *(const float4*)&scr[row * 68 + seg * 16 + t * 4];
      *(float4*)(O + obase + t * 4) = o;
    }
  }
}

// ---------------------------------------------------------------------------
extern "C" void kernel_launch(void* const* d_in, const int* in_sizes, int n_in,
                              void* d_out, int out_size, void* d_ws, size_t ws_size,
                              hipStream_t stream) {
  const float* X    = (const float*)d_in[0];  // [B,L,D]
  const void*  mraw = d_in[1];                // [B,L] bool/int
  const float* W    = (const float*)d_in[2];  // [D,D]
  const float* bias = (const float*)d_in[3];  // [D]

  float* out   = (float*)d_out;
  float* align = out;                          // B*L*D fp32 (48MB)
  float* alpha = out + (size_t)B_ * L_ * D_;   // B*L*L fp32 (64MB)

  const size_t NX = (size_t)B_ * L_ * D_;   // 12,582,912
  const size_t NW = (size_t)D_ * D_;        // 589,824
  const size_t NA = (size_t)B_ * L_ * L_;   // 16,777,216

  // ws layout: maskC(64K) | psum(64K) | kinfo(4K) | Xtc | Wf/a16c overlay
  int* maskC = (int*)d_ws;
  int* psum  = (int*)((char*)d_ws + 65536);
  int* kinfo = (int*)((char*)d_ws + 131072);
  const size_t offXt = 135168;
  unsigned short* Xt = (unsigned short*)((char*)d_ws + offXt);
  const size_t offWf = offXt + NX * 2;
  const size_t offA16 = offWf;              // a16c overlays Wf (dead after proj3)
  const size_t need = offA16 + NA * 2;      // ~58.9 MB (same as r10, proven OK)

  hipLaunchKernelGGL(k_mask2, dim3(16), dim3(256), 0, stream, mraw, maskC, psum, kinfo);

  if (ws_size >= need) {
    // Xf (fp16, 25MB) in the (dead-until-scores) alpha region; Pf in align
    // region (dead until k_align2 writes it).
    unsigned short* Xf = (unsigned short*)alpha;
    unsigned short* Wf = (unsigned short*)((char*)d_ws + offWf);
    unsigned short* Pf = (unsigned short*)align;
    unsigned short* A16 = (unsigned short*)((char*)d_ws + offA16);
    hipLaunchKernelGGL(k_prep16, dim3(D_ / 64, L_ / 64, B_), dim3(256), 0, stream,
                       X, Xf, Xt, psum, maskC);
    hipLaunchKernelGGL(k_castW, dim3((int)(NW / 8 / 256)), dim3(256), 0, stream,
                       W, Wf, (int)(NW / 8));
    hipLaunchKernelGGL(k_proj3, dim3(768), dim3(256), 0, stream, Xf, Wf, bias, Pf);
    hipLaunchKernelGGL(k_scores, dim3(576), dim3(256), 0, stream, Pf, maskC, alpha);
    hipLaunchKernelGGL(k_softmax, dim3(B_ * L_), dim3(256), 0, stream,
                       alpha, A16, psum, maskC);
    hipLaunchKernelGGL(k_pad, dim3(16, 28), dim3(256), 0, stream, Xt, A16, kinfo);
    hipLaunchKernelGGL(k_align2, dim3(768), dim3(256), 0, stream, A16, Xt, kinfo, align);
  } else {
    // fallback: full bf16 path, non-compacted Xt.
    unsigned short* Ph = (unsigned short*)align;
    unsigned short* Pl = Ph + NX;
    hipLaunchKernelGGL(k_prep, dim3(D_ / 64, L_ / 64, B_), dim3(256), 0, stream,
                       X, (unsigned short*)alpha, (unsigned short*)alpha + NX, Xt);
    hipLaunchKernelGGL(k_proj, dim3(768), dim3(256), 0, stream, X, W, bias, Ph, Pl);
    hipLaunchKernelGGL(k_scores_bf, dim3(576), dim3(256), 0, stream, Ph, Pl, maskC, alpha);
    hipLaunchKernelGGL(k_softmax, dim3(B_ * L_), dim3(256), 0, stream,
                       alpha, (unsigned short*)nullptr, psum, maskC);
    hipLaunchKernelGGL(k_align, dim3(768), dim3(256), 0, stream, alpha, Xt, align);
  }
}

// Round 12
// 162.405 us; speedup vs baseline: 1.9297x; 1.0311x over previous
//
#include <hip/hip_runtime.h>
#include <math.h>

// Problem constants
#define B_ 16
#define L_ 1024
#define D_ 768

typedef short bf16x8 __attribute__((ext_vector_type(8)));
typedef _Float16 half8 __attribute__((ext_vector_type(8)));
typedef float f32x4 __attribute__((ext_vector_type(4)));

// round-to-nearest-even f32 -> bf16 (bit trick; inputs never NaN)
__device__ __forceinline__ unsigned short f2bf(float x) {
  unsigned u = __float_as_uint(x);
  u = (u + 0x7FFFu + ((u >> 16) & 1u)) >> 16;
  return (unsigned short)u;
}
__device__ __forceinline__ float bf2f(unsigned short h) {
  return __uint_as_float(((unsigned)h) << 16);
}
// f32 -> fp16 bits (RTN)
__device__ __forceinline__ unsigned short f2h(float x) {
  union { _Float16 h; unsigned short u; } v;
  v.h = (_Float16)x;
  return v.u;
}

// ---------------------------------------------------------------------------
// K0 v2: canonicalize mask (dtype auto-detect) AND per-batch validity
// prefix-sum (psum, exclusive) + kinfo[b]=nt tiles, kinfo[16+b]=valid count.
// ---------------------------------------------------------------------------
__global__ __launch_bounds__(256) void k_mask2(const void* __restrict__ mraw,
                                               int* __restrict__ canon,
                                               int* __restrict__ psum,
                                               int* __restrict__ kinfo) {
  __shared__ int flags[2];
  __shared__ int tsum[256];
  const int b = blockIdx.x;
  const int tid = threadIdx.x;
  if (tid < 2) flags[tid] = 0;
  __syncthreads();
  const unsigned* m32 = (const unsigned*)mraw;
  int gt = 0, oddnz = 0;
  for (int i = tid; i < 4096; i += 256) {
    unsigned v = m32[i];
    if (v > 1u) gt = 1;
    if ((i & 1) && v != 0u) oddnz = 1;
  }
  if (gt) atomicOr(&flags[0], 1);
  if (oddnz) atomicOr(&flags[1], 1);
  __syncthreads();
  const int mode = flags[0] ? 0 : (flags[1] ? 1 : 2);  // 0=u8, 1=i32, 2=i64
  int v[4];
#pragma unroll
  for (int e = 0; e < 4; ++e) {
    const int i = b * L_ + tid * 4 + e;
    int mv;
    if (mode == 0)      mv = ((const unsigned char*)mraw)[i];
    else if (mode == 1) mv = ((const int*)mraw)[i];
    else                mv = (int)(((const long long*)mraw)[i] != 0);
    v[e] = (mv != 0);          // 1 = padding
    canon[i] = v[e];
  }
  const int vc = (1 - v[0]) + (1 - v[1]) + (1 - v[2]) + (1 - v[3]);
  tsum[tid] = vc;
  __syncthreads();
  for (int off = 1; off < 256; off <<= 1) {
    const int t = (tid >= off) ? tsum[tid - off] : 0;
    __syncthreads();
    tsum[tid] += t;
    __syncthreads();
  }
  int run = tsum[tid] - vc;  // exclusive prefix
#pragma unroll
  for (int e = 0; e < 4; ++e) {
    psum[b * L_ + tid * 4 + e] = run;
    run += 1 - v[e];
  }
  if (tid == 255) {
    const int tot = tsum[255];
    kinfo[b] = (tot + 63) >> 6;
    kinfo[16 + b] = tot;
  }
}

// ---------------------------------------------------------------------------
// K-prep16 (fast path): one pass over X -> Xf (fp16, X layout) and Xtc
// (fp16 transposed, compacted valid columns). Last m-tile blocks also zero
// the Xtc column tails [kv, nt*64) for their d-rows (replaces k_pad half).
// ---------------------------------------------------------------------------
__global__ __launch_bounds__(256) void k_prep16(const float* __restrict__ X,
                                                unsigned short* __restrict__ Xf,
                                                unsigned short* __restrict__ Xt,
                                                const int* __restrict__ psum,
                                                const int* __restrict__ canon,
                                                const int* __restrict__ kinfo) {
  __shared__ unsigned short t16[64][66];
  const int b = blockIdx.z;
  const int d0 = blockIdx.x * 64, m0 = blockIdx.y * 64;
  const int dd = threadIdx.x & 63, mq = threadIdx.x >> 6;
#pragma unroll
  for (int i = 0; i < 16; ++i) {
    const int m = mq * 16 + i;
    const size_t gidx = ((size_t)b * L_ + m0 + m) * D_ + d0 + dd;
    const unsigned short h = f2h(X[gidx]);
    Xf[gidx] = h;
    t16[dd][m] = h;
  }
  __syncthreads();
  const int mm = threadIdx.x & 63, dq = threadIdx.x >> 6;
  const int gm = m0 + mm;
  if (!canon[b * L_ + gm]) {        // valid token -> compacted column
    const int j = psum[b * L_ + gm];
#pragma unroll
    for (int i = 0; i < 16; ++i) {
      const int d = dq * 16 + i;
      Xt[((size_t)b * D_ + d0 + d) * L_ + j] = t16[d][mm];
    }
  }
  // Xtc tail zero: [kv, nt*64) for the 64 d-rows of this block.
  if (blockIdx.y == 15) {
    const int nt64 = kinfo[b] * 64;
    const int kv = kinfo[16 + b];
    if (kv < nt64) {
      const int rr = threadIdx.x >> 2, cg = threadIdx.x & 3;
      unsigned short* base = Xt + ((size_t)b * D_ + d0 + rr) * L_;
#pragma unroll
      for (int q = 0; q < 16; ++q) {
        const int c = kv + cg * 16 + q;
        if (c < nt64) base[c] = 0;
      }
    }
  }
}

// ---------------------------------------------------------------------------
// K-prep (fallback): X -> Xh/Xl bf16 hi/lo + full bf16 Xt.
// ---------------------------------------------------------------------------
__global__ __launch_bounds__(256) void k_prep(const float* __restrict__ X,
                                              unsigned short* __restrict__ Xh,
                                              unsigned short* __restrict__ Xl,
                                              unsigned short* __restrict__ Xt) {
  __shared__ unsigned short t16[64][66];
  const int b = blockIdx.z;
  const int d0 = blockIdx.x * 64, m0 = blockIdx.y * 64;
  const int dd = threadIdx.x & 63, mq = threadIdx.x >> 6;
#pragma unroll
  for (int i = 0; i < 16; ++i) {
    const int m = mq * 16 + i;
    const size_t gidx = ((size_t)b * L_ + m0 + m) * D_ + d0 + dd;
    const float x = X[gidx];
    const unsigned short h = f2bf(x);
    Xh[gidx] = h;
    Xl[gidx] = f2bf(x - bf2f(h));
    t16[dd][m] = h;
  }
  __syncthreads();
  const int mm = threadIdx.x & 63, dq = threadIdx.x >> 6;
#pragma unroll
  for (int i = 0; i < 16; ++i) {
    const int d = dq * 16 + i;
    Xt[((size_t)b * D_ + d0 + d) * L_ + m0 + mm] = t16[d][mm];
  }
}

// ---------------------------------------------------------------------------
// K-castW: W f32 -> fp16, 8 elems/thread.
// ---------------------------------------------------------------------------
__global__ __launch_bounds__(256) void k_castW(const float* __restrict__ W,
                                               unsigned short* __restrict__ Wf,
                                               int n8) {
  const int i = blockIdx.x * 256 + threadIdx.x;
  if (i >= n8) return;
  const float4 a = *(const float4*)(W + (size_t)i * 8);
  const float4 b = *(const float4*)(W + (size_t)i * 8 + 4);
  *(ushort4*)(Wf + (size_t)i * 8)     = make_ushort4(f2h(a.x), f2h(a.y), f2h(a.z), f2h(a.w));
  *(ushort4*)(Wf + (size_t)i * 8 + 4) = make_ushort4(f2h(b.x), f2h(b.y), f2h(b.z), f2h(b.w));
}

// ---------------------------------------------------------------------------
// Staging helpers: 128-row x 128B LDS panels, 16B slots XOR-swizzled via
// pre-swizzled global source (slot xs = s ^ (row&7)).
// ---------------------------------------------------------------------------
__device__ __forceinline__ void stage_panel(const unsigned short* __restrict__ ph,
                                            const unsigned short* __restrict__ pl,
                                            size_t grow0, int kk,
                                            char* ldsbase, int wave, int lane) {
#pragma unroll
  for (int q = 0; q < 4; ++q) {
    const int s = wave * 4 + q;
    const int row = s * 8 + (lane >> 3);
    const int xs = (lane & 7) ^ (row & 7);
    const unsigned short* src = (xs & 4) ? pl : ph;
    const unsigned short* g = src + (grow0 + row) * D_ + kk + (xs & 3) * 8;
    __builtin_amdgcn_global_load_lds(
        (const __attribute__((address_space(1))) void*)g,
        (__attribute__((address_space(3))) void*)(ldsbase + s * 1024),
        16, 0, 0);
  }
}

__device__ __forceinline__ void stage_panel1(const unsigned short* __restrict__ g0,
                                             size_t rstride,
                                             char* ldsbase, int wave, int lane) {
#pragma unroll
  for (int q = 0; q < 4; ++q) {
    const int s = wave * 4 + q;
    const int row = s * 8 + (lane >> 3);
    const int xs = (lane & 7) ^ (row & 7);
    const unsigned short* g = g0 + (size_t)row * rstride + xs * 8;
    __builtin_amdgcn_global_load_lds(
        (const __attribute__((address_space(1))) void*)g,
        (__attribute__((address_space(3))) void*)(ldsbase + s * 1024),
        16, 0, 0);
  }
}

__device__ __forceinline__ bf16x8 ldsfrag(const char* base, int row, int g) {
  return *(const bf16x8*)(base + row * 128 + ((g ^ (row & 7)) * 16));
}
__device__ __forceinline__ half8 ldsfrag_h(const char* base, int row, int g) {
  return *(const half8*)(base + row * 128 + ((g ^ (row & 7)) * 16));
}

// ---------------------------------------------------------------------------
// K1 v4 (MFMA): P = relu(Xf·Wf^T + b), single fp16 pass. K-tile 64, 12 iters,
// 48KB LDS (A dbuf + B single), XCD-local m-outer/n-inner mapping.
// ---------------------------------------------------------------------------
__global__ __launch_bounds__(256) void k_proj3(const unsigned short* __restrict__ Xf,
                                               const unsigned short* __restrict__ Wf,
                                               const float* __restrict__ bias,
                                               unsigned short* __restrict__ Pf) {
  __shared__ __align__(16) char smem[49152];  // A: 2x16KB @0, B: 16KB @32KB
  const int tid = threadIdx.x;
  const int xcd = (int)blockIdx.x & 7;
  const int li  = (int)blockIdx.x >> 3;
  const int m0 = (xcd * 16 + li / 6) * 128;
  const int n0 = (li % 6) * 128;
  const int lane = tid & 63, wave = tid >> 6;
  const int wr = wave >> 1, wc = wave & 1;
  const int fr = lane & 15, kg = lane >> 4;
  f32x4 acc[4][4];
#pragma unroll
  for (int i = 0; i < 4; ++i)
#pragma unroll
    for (int j = 0; j < 4; ++j) acc[i][j] = 0;

  const unsigned short* a0 = Xf + (size_t)m0 * D_;
  const unsigned short* b0 = Wf + (size_t)n0 * D_;

  stage_panel1(a0, D_, smem, wave, lane);
  stage_panel1(b0, D_, smem + 32768, wave, lane);
  __syncthreads();

  int cur = 0;
  for (int it = 0; it < D_ / 64; ++it) {
    const char* ab = smem + cur * 16384;
    const char* bb = smem + 32768;
    half8 fa[2][4], fb[2][4];
#pragma unroll
    for (int i = 0; i < 4; ++i) {
      const int ra = wr * 64 + i * 16 + fr;
      const int rb = wc * 64 + i * 16 + fr;
#pragma unroll
      for (int ks = 0; ks < 2; ++ks) {
        fa[ks][i] = ldsfrag_h(ab, ra, ks * 4 + kg);
        fb[ks][i] = ldsfrag_h(bb, rb, ks * 4 + kg);
      }
    }
    __syncthreads();  // all reads done -> safe to overwrite B / stage next A
    if (it + 1 < D_ / 64) {
      stage_panel1(a0 + (it + 1) * 64, D_, smem + (cur ^ 1) * 16384, wave, lane);
      stage_panel1(b0 + (it + 1) * 64, D_, smem + 32768, wave, lane);
    }
#pragma unroll
    for (int ks = 0; ks < 2; ++ks)
#pragma unroll
      for (int i = 0; i < 4; ++i)
#pragma unroll
        for (int j = 0; j < 4; ++j)
          acc[i][j] = __builtin_amdgcn_mfma_f32_16x16x32_f16(fa[ks][i], fb[ks][j],
                                                             acc[i][j], 0, 0, 0);
    __syncthreads();  // drains vmcnt -> next buffers ready
    cur ^= 1;
  }

  // Epilogue: bias+relu -> fp16; LDS transpose; 2x uint4 per lane.
  unsigned short* scr = (unsigned short*)smem + wave * 1152;  // [16][72]/wave
  const int row = lane >> 2, seg = lane & 3;
  float bj[4];
#pragma unroll
  for (int j = 0; j < 4; ++j) bj[j] = bias[n0 + wc * 64 + j * 16 + fr];
  for (int i = 0; i < 4; ++i) {
    __syncthreads();
#pragma unroll
    for (int j = 0; j < 4; ++j)
#pragma unroll
      for (int r = 0; r < 4; ++r)
        scr[(kg * 4 + r) * 72 + j * 16 + fr] = f2h(fmaxf(acc[i][j][r] + bj[j], 0.f));
    __syncthreads();
    const size_t gr = (size_t)(m0 + wr * 64 + i * 16 + row);
    const int gc0 = n0 + wc * 64 + seg * 16;
    const uint4 h0 = *(const uint4*)&scr[row * 72 + seg * 16];
    const uint4 h1 = *(const uint4*)&scr[row * 72 + seg * 16 + 8];
    *(uint4*)(Pf + gr * D_ + gc0)     = h0;
    *(uint4*)(Pf + gr * D_ + gc0 + 8) = h1;
  }
}

// ---------------------------------------------------------------------------
// K1 fallback (r5): on-the-fly split proj -> bf16 Ph/Pl (used if ws small).
// ---------------------------------------------------------------------------
__global__ __launch_bounds__(256) void k_proj(const float* __restrict__ X,
                                              const float* __restrict__ W,
                                              const float* __restrict__ bias,
                                              unsigned short* __restrict__ Ph,
                                              unsigned short* __restrict__ Pl) {
  __shared__ __align__(16) unsigned short smem[4 * 128 * 32];
  unsigned short (*Ah)[32] = (unsigned short(*)[32])smem;
  unsigned short (*Al)[32] = (unsigned short(*)[32])(smem + 1 * 128 * 32);
  unsigned short (*Bh)[32] = (unsigned short(*)[32])(smem + 2 * 128 * 32);
  unsigned short (*Bl)[32] = (unsigned short(*)[32])(smem + 3 * 128 * 32);

  const int tid = threadIdx.x;
  const int swz = ((int)blockIdx.x % 8) * 96 + (int)blockIdx.x / 8;
  const int m0 = (swz / 6) * 128, n0 = (swz % 6) * 128;
  const int lane = tid & 63, wave = tid >> 6;
  const int wr = wave >> 1, wc = wave & 1;
  const int fr = lane & 15, kg = lane >> 4;
  f32x4 acc[4][4];
#pragma unroll
  for (int i = 0; i < 4; ++i)
#pragma unroll
    for (int j = 0; j < 4; ++j) acc[i][j] = 0;

  float4 av[4], bv[4];
#pragma unroll
  for (int p = 0; p < 4; ++p) {
    const int f = tid + p * 256, r = f >> 3, c = f & 7;
    av[p] = *(const float4*)(X + (size_t)(m0 + r) * D_ + c * 4);
    bv[p] = *(const float4*)(W + (size_t)(n0 + r) * D_ + c * 4);
  }

  for (int it = 0; it < D_ / 32; ++it) {
    __syncthreads();
#pragma unroll
    for (int p = 0; p < 4; ++p) {
      const int f = tid + p * 256, r = f >> 3, c = f & 7;
      {
        const float x0 = av[p].x, x1 = av[p].y, x2 = av[p].z, x3 = av[p].w;
        const unsigned short h0 = f2bf(x0), h1 = f2bf(x1), h2 = f2bf(x2), h3 = f2bf(x3);
        *(ushort4*)&Ah[r][c * 4] = make_ushort4(h0, h1, h2, h3);
        *(ushort4*)&Al[r][c * 4] = make_ushort4(f2bf(x0 - bf2f(h0)), f2bf(x1 - bf2f(h1)),
                                                f2bf(x2 - bf2f(h2)), f2bf(x3 - bf2f(h3)));
      }
      {
        const float x0 = bv[p].x, x1 = bv[p].y, x2 = bv[p].z, x3 = bv[p].w;
        const unsigned short h0 = f2bf(x0), h1 = f2bf(x1), h2 = f2bf(x2), h3 = f2bf(x3);
        *(ushort4*)&Bh[r][c * 4] = make_ushort4(h0, h1, h2, h3);
        *(ushort4*)&Bl[r][c * 4] = make_ushort4(f2bf(x0 - bf2f(h0)), f2bf(x1 - bf2f(h1)),
                                                f2bf(x2 - bf2f(h2)), f2bf(x3 - bf2f(h3)));
      }
    }
    __syncthreads();
    if (it + 1 < D_ / 32) {
      const int kk = (it + 1) * 32;
#pragma unroll
      for (int p = 0; p < 4; ++p) {
        const int f = tid + p * 256, r = f >> 3, c = f & 7;
        av[p] = *(const float4*)(X + (size_t)(m0 + r) * D_ + kk + c * 4);
        bv[p] = *(const float4*)(W + (size_t)(n0 + r) * D_ + kk + c * 4);
      }
    }
    bf16x8 fah[4], fal[4], fbh[4], fbl[4];
#pragma unroll
    for (int i = 0; i < 4; ++i) {
      fah[i] = *(const bf16x8*)&Ah[wr * 64 + i * 16 + fr][kg * 8];
      fal[i] = *(const bf16x8*)&Al[wr * 64 + i * 16 + fr][kg * 8];
      fbh[i] = *(const bf16x8*)&Bh[wc * 64 + i * 16 + fr][kg * 8];
      fbl[i] = *(const bf16x8*)&Bl[wc * 64 + i * 16 + fr][kg * 8];
    }
#pragma unroll
    for (int i = 0; i < 4; ++i)
#pragma unroll
      for (int j = 0; j < 4; ++j) {
        acc[i][j] = __builtin_amdgcn_mfma_f32_16x16x32_bf16(fah[i], fbh[j], acc[i][j], 0, 0, 0);
        acc[i][j] = __builtin_amdgcn_mfma_f32_16x16x32_bf16(fah[i], fbl[j], acc[i][j], 0, 0, 0);
        acc[i][j] = __builtin_amdgcn_mfma_f32_16x16x32_bf16(fal[i], fbh[j], acc[i][j], 0, 0, 0);
      }
  }

  unsigned short* scr = smem + wave * 2304;
  const int row = lane >> 2, seg = lane & 3;
  float bj[4];
#pragma unroll
  for (int j = 0; j < 4; ++j) bj[j] = bias[n0 + wc * 64 + j * 16 + fr];
  for (int i = 0; i < 4; ++i) {
    __syncthreads();
#pragma unroll
    for (int j = 0; j < 4; ++j)
#pragma unroll
      for (int r = 0; r < 4; ++r) {
        float v = fmaxf(acc[i][j][r] + bj[j], 0.f);
        const unsigned short h = f2bf(v);
        scr[(kg * 4 + r) * 72 + j * 16 + fr] = h;
        scr[1152 + (kg * 4 + r) * 72 + j * 16 + fr] = f2bf(v - bf2f(h));
      }
    __syncthreads();
    const size_t gr = (size_t)(m0 + wr * 64 + i * 16 + row);
    const int gc0 = n0 + wc * 64 + seg * 16;
    const uint4 h0 = *(const uint4*)&scr[row * 72 + seg * 16];
    const uint4 h1 = *(const uint4*)&scr[row * 72 + seg * 16 + 8];
    const uint4 q0 = *(const uint4*)&scr[1152 + row * 72 + seg * 16];
    const uint4 q1 = *(const uint4*)&scr[1152 + row * 72 + seg * 16 + 8];
    *(uint4*)(Ph + gr * D_ + gc0)     = h0;
    *(uint4*)(Ph + gr * D_ + gc0 + 8) = h1;
    *(uint4*)(Pl + gr * D_ + gc0)     = q0;
    *(uint4*)(Pl + gr * D_ + gc0 + 8) = q1;
  }
}

// ---------------------------------------------------------------------------
// K2 v2 (MFMA): S = Pf·Pf^T, single fp16 pass, symmetric pairs, K-tile 64.
// 64KB LDS (mirror epilogue needs the full 128x512B staging area).
// ---------------------------------------------------------------------------
__global__ __launch_bounds__(256) void k_scores(const unsigned short* __restrict__ Pf,
                                                const int* __restrict__ mask,
                                                float* __restrict__ S) {
  __shared__ __align__(16) char smem[65536];

  const int tid = threadIdx.x;
  const int swz = ((int)blockIdx.x % 8) * 72 + (int)blockIdx.x / 8;
  const int bb = swz / 36;
  const int pr = swz % 36;
  int ti = 0;
  while ((ti + 1) * (ti + 2) / 2 <= pr) ++ti;
  const int tj = pr - ti * (ti + 1) / 2;
  const int l0 = ti * 128, m0 = tj * 128;
  const int lane = tid & 63, wave = tid >> 6;
  const int wr = wave >> 1, wc = wave & 1;
  const int fr = lane & 15, kg = lane >> 4;
  f32x4 acc[4][4];
#pragma unroll
  for (int i = 0; i < 4; ++i)
#pragma unroll
    for (int j = 0; j < 4; ++j) acc[i][j] = 0;

  const unsigned short* a0 = Pf + ((size_t)bb * L_ + l0) * D_;
  const unsigned short* b0 = Pf + ((size_t)bb * L_ + m0) * D_;

  stage_panel1(a0, D_, smem, wave, lane);
  stage_panel1(b0, D_, smem + 16384, wave, lane);
  __syncthreads();

  int cur = 0;
  for (int it = 0; it < D_ / 64; ++it) {
    char* cb = smem + cur * 32768;
    if (it + 1 < D_ / 64) {
      char* nb = smem + (cur ^ 1) * 32768;
      stage_panel1(a0 + (it + 1) * 64, D_, nb, wave, lane);
      stage_panel1(b0 + (it + 1) * 64, D_, nb + 16384, wave, lane);
    }
    half8 fa[2][4], fb[2][4];
#pragma unroll
    for (int i = 0; i < 4; ++i) {
      const int ra = wr * 64 + i * 16 + fr;
      const int rb = wc * 64 + i * 16 + fr;
#pragma unroll
      for (int ks = 0; ks < 2; ++ks) {
        fa[ks][i] = ldsfrag_h(cb, ra, ks * 4 + kg);
        fb[ks][i] = ldsfrag_h(cb + 16384, rb, ks * 4 + kg);
      }
    }
#pragma unroll
    for (int ks = 0; ks < 2; ++ks)
#pragma unroll
      for (int i = 0; i < 4; ++i)
#pragma unroll
        for (int j = 0; j < 4; ++j)
          acc[i][j] = __builtin_amdgcn_mfma_f32_16x16x32_f16(fa[ks][i], fb[ks][j],
                                                             acc[i][j], 0, 0, 0);
    __syncthreads();
    cur ^= 1;
  }

  float* scr = (float*)smem + wave * 1280;
  const int row = lane >> 2, seg = lane & 3;
  for (int i = 0; i < 4; ++i) {
    __syncthreads();
#pragma unroll
    for (int j = 0; j < 4; ++j)
#pragma unroll
      for (int r = 0; r < 4; ++r)
        scr[(kg * 4 + r) * 68 + j * 16 + fr] = acc[i][j][r];
    __syncthreads();
    const int gl = l0 + wr * 64 + i * 16 + row;
    const int gm0 = m0 + wc * 64 + seg * 16;
    const size_t sbase = ((size_t)bb * L_ + gl) * L_ + gm0;
#pragma unroll
    for (int t = 0; t < 4; ++t) {
      float4 o = *(const float4*)&scr[row * 68 + seg * 16 + t * 4];
      const int4 mk = *(const int4*)(mask + bb * L_ + gm0 + t * 4);
      float* op = (float*)&o;
      const int* mp = (const int*)&mk;
#pragma unroll
      for (int e = 0; e < 4; ++e) {
        const int gm = gm0 + t * 4 + e;
        if (gm == gl) op[e] = 0.f;
        if (mp[e]) op[e] = -INFINITY;
      }
      *(float4*)(S + sbase + t * 4) = o;
    }
  }

  if (ti != tj) {
    __syncthreads();
#pragma unroll
    for (int j = 0; j < 4; ++j) {
      const int mloc = wc * 64 + j * 16 + fr;
#pragma unroll
      for (int i = 0; i < 4; ++i) {
        const int slot = wr * 16 + i * 4 + kg;
        const int xs = slot ^ (mloc & 7);
        *(f32x4*)(smem + mloc * 512 + xs * 16) = acc[i][j];
      }
    }
    __syncthreads();
    const int mrow = tid >> 1, half = tid & 1;
    const size_t sbase = ((size_t)bb * L_ + m0 + mrow) * L_ + l0;
#pragma unroll
    for (int q = 0; q < 16; ++q) {
      const int slot = half * 16 + q;
      const int xs = slot ^ (mrow & 7);
      float4 o = *(const float4*)(smem + mrow * 512 + xs * 16);
      const int4 mk = *(const int4*)(mask + bb * L_ + l0 + slot * 4);
      if (mk.x) o.x = -INFINITY;
      if (mk.y) o.y = -INFINITY;
      if (mk.z) o.z = -INFINITY;
      if (mk.w) o.w = -INFINITY;
      *(float4*)(S + sbase + slot * 4) = o;
    }
  }
}

// ---------------------------------------------------------------------------
// K2 fallback (r5): S = P·P^T from bf16 hi/lo Ph/Pl, 3-pass.
// ---------------------------------------------------------------------------
__global__ __launch_bounds__(256) void k_scores_bf(const unsigned short* __restrict__ Ph,
                                                   const unsigned short* __restrict__ Pl,
                                                   const int* __restrict__ mask,
                                                   float* __restrict__ S) {
  __shared__ __align__(16) char smem[65536];

  const int tid = threadIdx.x;
  const int swz = ((int)blockIdx.x % 8) * 72 + (int)blockIdx.x / 8;
  const int bb = swz / 36;
  const int pr = swz % 36;
  int ti = 0;
  while ((ti + 1) * (ti + 2) / 2 <= pr) ++ti;
  const int tj = pr - ti * (ti + 1) / 2;
  const int l0 = ti * 128, m0 = tj * 128;
  const int lane = tid & 63, wave = tid >> 6;
  const int wr = wave >> 1, wc = wave & 1;
  const int fr = lane & 15, kg = lane >> 4;
  f32x4 acc[4][4];
#pragma unroll
  for (int i = 0; i < 4; ++i)
#pragma unroll
    for (int j = 0; j < 4; ++j) acc[i][j] = 0;

  const size_t arow0 = (size_t)bb * L_ + l0;
  const size_t brow0 = (size_t)bb * L_ + m0;

  stage_panel(Ph, Pl, arow0, 0, smem, wave, lane);
  stage_panel(Ph, Pl, brow0, 0, smem + 16384, wave, lane);
  __syncthreads();

  int cur = 0;
  for (int it = 0; it < D_ / 32; ++it) {
    char* cb = smem + cur * 32768;
    if (it + 1 < D_ / 32) {
      char* nb = smem + (cur ^ 1) * 32768;
      stage_panel(Ph, Pl, arow0, (it + 1) * 32, nb, wave, lane);
      stage_panel(Ph, Pl, brow0, (it + 1) * 32, nb + 16384, wave, lane);
    }
    bf16x8 fah[4], fal[4], fbh[4], fbl[4];
#pragma unroll
    for (int i = 0; i < 4; ++i) {
      const int ra = wr * 64 + i * 16 + fr;
      const int rb = wc * 64 + i * 16 + fr;
      fah[i] = ldsfrag(cb, ra, kg);
      fal[i] = ldsfrag(cb, ra, kg + 4);
      fbh[i] = ldsfrag(cb + 16384, rb, kg);
      fbl[i] = ldsfrag(cb + 16384, rb, kg + 4);
    }
#pragma unroll
    for (int i = 0; i < 4; ++i)
#pragma unroll
      for (int j = 0; j < 4; ++j) {
        acc[i][j] = __builtin_amdgcn_mfma_f32_16x16x32_bf16(fah[i], fbh[j], acc[i][j], 0, 0, 0);
        acc[i][j] = __builtin_amdgcn_mfma_f32_16x16x32_bf16(fah[i], fbl[j], acc[i][j], 0, 0, 0);
        acc[i][j] = __builtin_amdgcn_mfma_f32_16x16x32_bf16(fal[i], fbh[j], acc[i][j], 0, 0, 0);
      }
    __syncthreads();
    cur ^= 1;
  }

  float* scr = (float*)smem + wave * 1280;
  const int row = lane >> 2, seg = lane & 3;
  for (int i = 0; i < 4; ++i) {
    __syncthreads();
#pragma unroll
    for (int j = 0; j < 4; ++j)
#pragma unroll
      for (int r = 0; r < 4; ++r)
        scr[(kg * 4 + r) * 68 + j * 16 + fr] = acc[i][j][r];
    __syncthreads();
    const int gl = l0 + wr * 64 + i * 16 + row;
    const int gm0 = m0 + wc * 64 + seg * 16;
    const size_t sbase = ((size_t)bb * L_ + gl) * L_ + gm0;
#pragma unroll
    for (int t = 0; t < 4; ++t) {
      float4 o = *(const float4*)&scr[row * 68 + seg * 16 + t * 4];
      const int4 mk = *(const int4*)(mask + bb * L_ + gm0 + t * 4);
      float* op = (float*)&o;
      const int* mp = (const int*)&mk;
#pragma unroll
      for (int e = 0; e < 4; ++e) {
        const int gm = gm0 + t * 4 + e;
        if (gm == gl) op[e] = 0.f;
        if (mp[e]) op[e] = -INFINITY;
      }
      *(float4*)(S + sbase + t * 4) = o;
    }
  }

  if (ti != tj) {
    __syncthreads();
#pragma unroll
    for (int j = 0; j < 4; ++j) {
      const int mloc = wc * 64 + j * 16 + fr;
#pragma unroll
      for (int i = 0; i < 4; ++i) {
        const int slot = wr * 16 + i * 4 + kg;
        const int xs = slot ^ (mloc & 7);
        *(f32x4*)(smem + mloc * 512 + xs * 16) = acc[i][j];
      }
    }
    __syncthreads();
    const int mrow = tid >> 1, half = tid & 1;
    const size_t sbase = ((size_t)bb * L_ + m0 + mrow) * L_ + l0;
#pragma unroll
    for (int q = 0; q < 16; ++q) {
      const int slot = half * 16 + q;
      const int xs = slot ^ (mrow & 7);
      float4 o = *(const float4*)(smem + mrow * 512 + xs * 16);
      const int4 mk = *(const int4*)(mask + bb * L_ + l0 + slot * 4);
      if (mk.x) o.x = -INFINITY;
      if (mk.y) o.y = -INFINITY;
      if (mk.z) o.z = -INFINITY;
      if (mk.w) o.w = -INFINITY;
      *(float4*)(S + sbase + slot * 4) = o;
    }
  }
}

// ---------------------------------------------------------------------------
// K3: in-place row softmax; when a16 != null, scatter-writes the COMPACTED
// fp16 alpha (valid columns at psum positions) and zeroes the row's
// [kv, nt*64) tail (replaces k_pad's a16c half).
// ---------------------------------------------------------------------------
__global__ __launch_bounds__(256) void k_softmax(float* __restrict__ S,
                                                 unsigned short* __restrict__ a16,
                                                 const int* __restrict__ psum,
                                                 const int* __restrict__ canon,
                                                 const int* __restrict__ kinfo) {
  const size_t row = blockIdx.x;
  float4* rp = (float4*)(S + row * L_);
  float4 v = rp[threadIdx.x];
  float mx = fmaxf(fmaxf(v.x, v.y), fmaxf(v.z, v.w));
#pragma unroll
  for (int o = 32; o > 0; o >>= 1) mx = fmaxf(mx, __shfl_xor(mx, o));
  __shared__ float rmax[4], rsum[4];
  const int wv = threadIdx.x >> 6, ln = threadIdx.x & 63;
  if (ln == 0) rmax[wv] = mx;
  __syncthreads();
  mx = fmaxf(fmaxf(rmax[0], rmax[1]), fmaxf(rmax[2], rmax[3]));
  float4 e;
  e.x = __expf(v.x - mx); e.y = __expf(v.y - mx);
  e.z = __expf(v.z - mx); e.w = __expf(v.w - mx);
  float s = (e.x + e.y) + (e.z + e.w);
#pragma unroll
  for (int o = 32; o > 0; o >>= 1) s += __shfl_xor(s, o);
  if (ln == 0) rsum[wv] = s;
  __syncthreads();
  s = (rsum[0] + rsum[1]) + (rsum[2] + rsum[3]);
  const float inv = 1.0f / s;
  e.x *= inv; e.y *= inv; e.z *= inv; e.w *= inv;
  rp[threadIdx.x] = e;
  if (a16) {
    const int bbat = (int)(row >> 10);
    const int m0 = threadIdx.x * 4;
    const int4 mk = *(const int4*)(canon + bbat * L_ + m0);
    const int4 ps = *(const int4*)(psum + bbat * L_ + m0);
    unsigned short* arow = a16 + row * L_;
    if (!mk.x) arow[ps.x] = f2h(e.x);
    if (!mk.y) arow[ps.y] = f2h(e.y);
    if (!mk.z) arow[ps.z] = f2h(e.z);
    if (!mk.w) arow[ps.w] = f2h(e.w);
    // tail zero [kv, nt*64): <= 63 elems, covered by 256 threads
    const int nt64 = kinfo[bbat] * 64;
    const int kv = kinfo[16 + bbat];
    const int c = kv + (int)threadIdx.x;
    if (c < nt64) arow[c] = 0;
  }
}

// ---------------------------------------------------------------------------
// K5 v5 (MFMA): align = a16c·Xtc^T per batch, COMPACTED K, dynamic K-loop.
// 48KB LDS (A dbuf + B single, proj3 pattern) -> 3 blocks/CU.
// ---------------------------------------------------------------------------
__global__ __launch_bounds__(256) void k_align2(const unsigned short* __restrict__ A16,
                                                const unsigned short* __restrict__ Xt,
                                                const int* __restrict__ kinfo,
                                                float* __restrict__ O) {
  __shared__ __align__(16) char smem[49152];  // A: 2x16KB @0, B: 16KB @32KB
  const int tid = threadIdx.x;
  const int swz = ((int)blockIdx.x % 8) * 96 + (int)blockIdx.x / 8;
  const int bb = swz / 48;
  const int l0 = ((swz / 6) % 8) * 128;
  const int n0 = (swz % 6) * 128;
  const int nt = kinfo[bb];
  const int lane = tid & 63, wave = tid >> 6;
  const int wr = wave >> 1, wc = wave & 1;
  const int fr = lane & 15, kg = lane >> 4;
  f32x4 acc[4][4];
#pragma unroll
  for (int i = 0; i < 4; ++i)
#pragma unroll
    for (int j = 0; j < 4; ++j) acc[i][j] = 0;

  const unsigned short* a0 = A16 + ((size_t)bb * L_ + l0) * L_;
  const unsigned short* b0 = Xt + ((size_t)bb * D_ + n0) * L_;

  if (nt > 0) {
    stage_panel1(a0, L_, smem, wave, lane);
    stage_panel1(b0, L_, smem + 32768, wave, lane);
  }
  __syncthreads();

  int cur = 0;
  for (int it = 0; it < nt; ++it) {
    const char* ab = smem + cur * 16384;
    const char* bb2 = smem + 32768;
    half8 fa[2][4], fb[2][4];
#pragma unroll
    for (int i = 0; i < 4; ++i) {
      const int ra = wr * 64 + i * 16 + fr;
      const int rb = wc * 64 + i * 16 + fr;
#pragma unroll
      for (int ks = 0; ks < 2; ++ks) {
        fa[ks][i] = ldsfrag_h(ab, ra, ks * 4 + kg);
        fb[ks][i] = ldsfrag_h(bb2, rb, ks * 4 + kg);
      }
    }
    __syncthreads();  // all reads done -> safe to overwrite B / stage next A
    if (it + 1 < nt) {
      stage_panel1(a0 + (it + 1) * 64, L_, smem + (cur ^ 1) * 16384, wave, lane);
      stage_panel1(b0 + (it + 1) * 64, L_, smem + 32768, wave, lane);
    }
#pragma unroll
    for (int ks = 0; ks < 2; ++ks)
#pragma unroll
      for (int i = 0; i < 4; ++i)
#pragma unroll
        for (int j = 0; j < 4; ++j)
          acc[i][j] = __builtin_amdgcn_mfma_f32_16x16x32_f16(fa[ks][i], fb[ks][j],
                                                             acc[i][j], 0, 0, 0);
    __syncthreads();  // drains vmcnt -> next buffers ready
    cur ^= 1;
  }

  float* scr = (float*)smem + wave * 1280;
  const int row = lane >> 2, seg = lane & 3;
  for (int i = 0; i < 4; ++i) {
    __syncthreads();
#pragma unroll
    for (int j = 0; j < 4; ++j)
#pragma unroll
      for (int r = 0; r < 4; ++r)
        scr[(kg * 4 + r) * 68 + j * 16 + fr] = acc[i][j][r];
    __syncthreads();
    const int gl = l0 + wr * 64 + i * 16 + row;
    const int gc0 = n0 + wc * 64 + seg * 16;
    const size_t obase = ((size_t)bb * L_ + gl) * D_ + gc0;
#pragma unroll
    for (int t = 0; t < 4; ++t) {
      const float4 o = *(const float4*)&scr[row * 68 + seg * 16 + t * 4];
      *(float4*)(O + obase + t * 4) = o;
    }
  }
}

// ---------------------------------------------------------------------------
// K5 fallback (r6): align = alpha(f32)·Xt^T (bf16 Xt), staging conversion.
// ---------------------------------------------------------------------------
__global__ __launch_bounds__(256) void k_align(const float* __restrict__ A,
                                               const unsigned short* __restrict__ Xt,
                                               float* __restrict__ O) {
  __shared__ __align__(16) unsigned short smem[2 * 128 * 32];
  __shared__ __align__(16) float scr_s[4 * 1104];
  unsigned short (*Ab)[32] = (unsigned short(*)[32])smem;
  unsigned short (*Bb)[32] = (unsigned short(*)[32])(smem + 128 * 32);

  const int tid = threadIdx.x;
  const int swz = ((int)blockIdx.x % 8) * 96 + (int)blockIdx.x / 8;
  const int bb = swz / 48;
  const int l0 = ((swz / 6) % 8) * 128;
  const int n0 = (swz % 6) * 128;
  const int lane = tid & 63, wave = tid >> 6;
  const int wr = wave >> 1, wc = wave & 1;
  const int fr = lane & 15, kg = lane >> 4;
  f32x4 acc[4][4];
#pragma unroll
  for (int i = 0; i < 4; ++i)
#pragma unroll
    for (int j = 0; j < 4; ++j) acc[i][j] = 0;

  float4 av[4];
  uint4 bv[2];
#pragma unroll
  for (int p = 0; p < 4; ++p) {
    const int f = tid + p * 256, r = f >> 3, c = f & 7;
    av[p] = *(const float4*)(A + ((size_t)bb * L_ + l0 + r) * L_ + c * 4);
  }
#pragma unroll
  for (int p = 0; p < 2; ++p) {
    const int f = tid + p * 256, r = f >> 2, sl = f & 3;
    bv[p] = *(const uint4*)(Xt + ((size_t)bb * D_ + n0 + r) * L_ + sl * 8);
  }

  for (int it = 0; it < L_ / 32; ++it) {
    __syncthreads();
#pragma unroll
    for (int p = 0; p < 4; ++p) {
      const int f = tid + p * 256, r = f >> 3, c = f & 7;
      *(ushort4*)&Ab[r][c * 4] = make_ushort4(f2bf(av[p].x), f2bf(av[p].y),
                                              f2bf(av[p].z), f2bf(av[p].w));
    }
#pragma unroll
    for (int p = 0; p < 2; ++p) {
      const int f = tid + p * 256, r = f >> 2, sl = f & 3;
      *(uint4*)&Bb[r][sl * 8] = bv[p];
    }
    __syncthreads();
    if (it + 1 < L_ / 32) {
      const int kk = (it + 1) * 32;
#pragma unroll
      for (int p = 0; p < 4; ++p) {
        const int f = tid + p * 256, r = f >> 3, c = f & 7;
        av[p] = *(const float4*)(A + ((size_t)bb * L_ + l0 + r) * L_ + kk + c * 4);
      }
#pragma unroll
      for (int p = 0; p < 2; ++p) {
        const int f = tid + p * 256, r = f >> 2, sl = f & 3;
        bv[p] = *(const uint4*)(Xt + ((size_t)bb * D_ + n0 + r) * L_ + kk + sl * 8);
      }
    }
    bf16x8 fa[4], fb[4];
#pragma unroll
    for (int i = 0; i < 4; ++i) {
      fa[i] = *(const bf16x8*)&Ab[wr * 64 + i * 16 + fr][kg * 8];
      fb[i] = *(const bf16x8*)&Bb[wc * 64 + i * 16 + fr][kg * 8];
    }
#pragma unroll
    for (int i = 0; i < 4; ++i)
#pragma unroll
      for (int j = 0; j < 4; ++j)
        acc[i][j] = __builtin_amdgcn_mfma_f32_16x16x32_bf16(fa[i], fb[j], acc[i][j], 0, 0, 0);
  }

  float* scr = scr_s + wave * 1104;
  const int row = lane >> 2, seg = lane & 3;
  for (int i = 0; i < 4; ++i) {
    __syncthreads();
#pragma unroll
    for (int j = 0; j < 4; ++j)
#pragma unroll
      for (int r = 0; r < 4; ++r)
        scr[(kg * 4 + r) * 68 + j * 16 + fr] = acc[i][j][r];
    __syncthreads();
    const int gl = l0 + wr * 64 + i * 16 + row;
    const int gc0 = n0 + wc * 64 + seg * 16;
    const size_t obase = ((size_t)bb * L_ + gl) * D_ + gc0;
#pragma unroll
    for (int t = 0; t < 4; ++t) {
      const float4 o = *(const float4*)&scr[row * 68 + seg * 16 + t * 4];
      *(float4*)(O + obase + t * 4) = o;
    }
  }
}

// ---------------------------------------------------------------------------
extern "C" void kernel_launch(void* const* d_in, const int* in_sizes, int n_in,
                              void* d_out, int out_size, void* d_ws, size_t ws_size,
                              hipStream_t stream) {
  const float* X    = (const float*)d_in[0];  // [B,L,D]
  const void*  mraw = d_in[1];                // [B,L] bool/int
  const float* W    = (const float*)d_in[2];  // [D,D]
  const float* bias = (const float*)d_in[3];  // [D]

  float* out   = (float*)d_out;
  float* align = out;                          // B*L*D fp32 (48MB)
  float* alpha = out + (size_t)B_ * L_ * D_;   // B*L*L fp32 (64MB)

  const size_t NX = (size_t)B_ * L_ * D_;   // 12,582,912
  const size_t NW = (size_t)D_ * D_;        // 589,824
  const size_t NA = (size_t)B_ * L_ * L_;   // 16,777,216

  // ws layout: maskC(64K) | psum(64K) | kinfo(4K) | Xtc | Wf/a16c overlay
  int* maskC = (int*)d_ws;
  int* psum  = (int*)((char*)d_ws + 65536);
  int* kinfo = (int*)((char*)d_ws + 131072);
  const size_t offXt = 135168;
  unsigned short* Xt = (unsigned short*)((char*)d_ws + offXt);
  const size_t offWf = offXt + NX * 2;
  const size_t offA16 = offWf;              // a16c overlays Wf (dead after proj3)
  const size_t need = offA16 + NA * 2;      // ~58.9 MB (proven OK since r7)

  hipLaunchKernelGGL(k_mask2, dim3(16), dim3(256), 0, stream, mraw, maskC, psum, kinfo);

  if (ws_size >= need) {
    // Xf (fp16, 25MB) in the (dead-until-scores) alpha region; Pf in align
    // region (dead until k_align2 writes it).
    unsigned short* Xf = (unsigned short*)alpha;
    unsigned short* Wf = (unsigned short*)((char*)d_ws + offWf);
    unsigned short* Pf = (unsigned short*)align;
    unsigned short* A16 = (unsigned short*)((char*)d_ws + offA16);
    hipLaunchKernelGGL(k_prep16, dim3(D_ / 64, L_ / 64, B_), dim3(256), 0, stream,
                       X, Xf, Xt, psum, maskC, kinfo);
    hipLaunchKernelGGL(k_castW, dim3((int)(NW / 8 / 256)), dim3(256), 0, stream,
                       W, Wf, (int)(NW / 8));
    hipLaunchKernelGGL(k_proj3, dim3(768), dim3(256), 0, stream, Xf, Wf, bias, Pf);
    hipLaunchKernelGGL(k_scores, dim3(576), dim3(256), 0, stream, Pf, maskC, alpha);
    hipLaunchKernelGGL(k_softmax, dim3(B_ * L_), dim3(256), 0, stream,
                       alpha, A16, psum, maskC, kinfo);
    hipLaunchKernelGGL(k_align2, dim3(768), dim3(256), 0, stream, A16, Xt, kinfo, align);
  } else {
    // fallback: full bf16 path, non-compacted Xt.
    unsigned short* Ph = (unsigned short*)align;
    unsigned short* Pl = Ph + NX;
    hipLaunchKernelGGL(k_prep, dim3(D_ / 64, L_ / 64, B_), dim3(256), 0, stream,
                       X, (unsigned short*)alpha, (unsigned short*)alpha + NX, Xt);
    hipLaunchKernelGGL(k_proj, dim3(768), dim3(256), 0, stream, X, W, bias, Ph, Pl);
    hipLaunchKernelGGL(k_scores_bf, dim3(576), dim3(256), 0, stream, Ph, Pl, maskC, alpha);
    hipLaunchKernelGGL(k_softmax, dim3(B_ * L_), dim3(256), 0, stream,
                       alpha, (unsigned short*)nullptr, psum, maskC, kinfo);
    hipLaunchKernelGGL(k_align, dim3(768), dim3(256), 0, stream, alpha, Xt, align);
  }
}

// Round 13
// 159.868 us; speedup vs baseline: 1.9603x; 1.0159x over previous
//
#include <hip/hip_runtime.h>
#include <math.h>

// Problem constants
#define B_ 16
#define L_ 1024
#define D_ 768

typedef short bf16x8 __attribute__((ext_vector_type(8)));
typedef _Float16 half8 __attribute__((ext_vector_type(8)));
typedef float f32x4 __attribute__((ext_vector_type(4)));

__device__ __forceinline__ unsigned short f2bf(float x) {
  unsigned u = __float_as_uint(x);
  u = (u + 0x7FFFu + ((u >> 16) & 1u)) >> 16;
  return (unsigned short)u;
}
__device__ __forceinline__ float bf2f(unsigned short h) {
  return __uint_as_float(((unsigned)h) << 16);
}
__device__ __forceinline__ unsigned short f2h(float x) {
  union { _Float16 h; unsigned short u; } v;
  v.h = (_Float16)x;
  return v.u;
}

// ---------------------------------------------------------------------------
// K0 v3: mask canon (dtype auto-detect) + per-batch validity prefix-sum
// (psum), kinfo[b]=nt(64-tiles)/kinfo[16+b]=valid count, and ctok[b][j] =
// token index of compacted column j (0-filled for j >= kv).
// ---------------------------------------------------------------------------
__global__ __launch_bounds__(256) void k_mask2(const void* __restrict__ mraw,
                                               int* __restrict__ canon,
                                               int* __restrict__ psum,
                                               int* __restrict__ kinfo,
                                               int* __restrict__ ctok) {
  __shared__ int flags[2];
  __shared__ int tsum[256];
  const int b = blockIdx.x;
  const int tid = threadIdx.x;
  if (tid < 2) flags[tid] = 0;
  __syncthreads();
  const unsigned* m32 = (const unsigned*)mraw;
  int gt = 0, oddnz = 0;
  for (int i = tid; i < 4096; i += 256) {
    unsigned v = m32[i];
    if (v > 1u) gt = 1;
    if ((i & 1) && v != 0u) oddnz = 1;
  }
  if (gt) atomicOr(&flags[0], 1);
  if (oddnz) atomicOr(&flags[1], 1);
  __syncthreads();
  const int mode = flags[0] ? 0 : (flags[1] ? 1 : 2);  // 0=u8, 1=i32, 2=i64
  int v[4];
#pragma unroll
  for (int e = 0; e < 4; ++e) {
    const int i = b * L_ + tid * 4 + e;
    int mv;
    if (mode == 0)      mv = ((const unsigned char*)mraw)[i];
    else if (mode == 1) mv = ((const int*)mraw)[i];
    else                mv = (int)(((const long long*)mraw)[i] != 0);
    v[e] = (mv != 0);          // 1 = padding
    canon[i] = v[e];
    ctok[i] = 0;               // init (garbage-region cols read row 0, safe)
  }
  const int vc = (1 - v[0]) + (1 - v[1]) + (1 - v[2]) + (1 - v[3]);
  tsum[tid] = vc;
  __syncthreads();
  for (int off = 1; off < 256; off <<= 1) {
    const int t = (tid >= off) ? tsum[tid - off] : 0;
    __syncthreads();
    tsum[tid] += t;
    __syncthreads();
  }
  int run = tsum[tid] - vc;  // exclusive prefix
#pragma unroll
  for (int e = 0; e < 4; ++e) {
    psum[b * L_ + tid * 4 + e] = run;
    if (!v[e]) ctok[b * L_ + run] = tid * 4 + e;
    run += 1 - v[e];
  }
  if (tid == 255) {
    const int tot = tsum[255];
    kinfo[b] = (tot + 63) >> 6;
    kinfo[16 + b] = tot;
  }
}

// ---------------------------------------------------------------------------
// K-prep16: X -> Xf (fp16) + Xtc (fp16 transposed, compacted cols, tails 0).
// ---------------------------------------------------------------------------
__global__ __launch_bounds__(256) void k_prep16(const float* __restrict__ X,
                                                unsigned short* __restrict__ Xf,
                                                unsigned short* __restrict__ Xt,
                                                const int* __restrict__ psum,
                                                const int* __restrict__ canon,
                                                const int* __restrict__ kinfo) {
  __shared__ unsigned short t16[64][66];
  const int b = blockIdx.z;
  const int d0 = blockIdx.x * 64, m0 = blockIdx.y * 64;
  const int dd = threadIdx.x & 63, mq = threadIdx.x >> 6;
#pragma unroll
  for (int i = 0; i < 16; ++i) {
    const int m = mq * 16 + i;
    const size_t gidx = ((size_t)b * L_ + m0 + m) * D_ + d0 + dd;
    const unsigned short h = f2h(X[gidx]);
    Xf[gidx] = h;
    t16[dd][m] = h;
  }
  __syncthreads();
  const int mm = threadIdx.x & 63, dq = threadIdx.x >> 6;
  const int gm = m0 + mm;
  if (!canon[b * L_ + gm]) {
    const int j = psum[b * L_ + gm];
#pragma unroll
    for (int i = 0; i < 16; ++i) {
      const int d = dq * 16 + i;
      Xt[((size_t)b * D_ + d0 + d) * L_ + j] = t16[d][mm];
    }
  }
  if (blockIdx.y == 15) {
    const int nt64 = kinfo[b] * 64;
    const int kv = kinfo[16 + b];
    if (kv < nt64) {
      const int rr = threadIdx.x >> 2, cg = threadIdx.x & 3;
      unsigned short* base = Xt + ((size_t)b * D_ + d0 + rr) * L_;
#pragma unroll
      for (int q = 0; q < 16; ++q) {
        const int c = kv + cg * 16 + q;
        if (c < nt64) base[c] = 0;
      }
    }
  }
}

// ---------------------------------------------------------------------------
// K-prep (fallback): X -> Xh/Xl bf16 hi/lo + full bf16 Xt.
// ---------------------------------------------------------------------------
__global__ __launch_bounds__(256) void k_prep(const float* __restrict__ X,
                                              unsigned short* __restrict__ Xh,
                                              unsigned short* __restrict__ Xl,
                                              unsigned short* __restrict__ Xt) {
  __shared__ unsigned short t16[64][66];
  const int b = blockIdx.z;
  const int d0 = blockIdx.x * 64, m0 = blockIdx.y * 64;
  const int dd = threadIdx.x & 63, mq = threadIdx.x >> 6;
#pragma unroll
  for (int i = 0; i < 16; ++i) {
    const int m = mq * 16 + i;
    const size_t gidx = ((size_t)b * L_ + m0 + m) * D_ + d0 + dd;
    const float x = X[gidx];
    const unsigned short h = f2bf(x);
    Xh[gidx] = h;
    Xl[gidx] = f2bf(x - bf2f(h));
    t16[dd][m] = h;
  }
  __syncthreads();
  const int mm = threadIdx.x & 63, dq = threadIdx.x >> 6;
#pragma unroll
  for (int i = 0; i < 16; ++i) {
    const int d = dq * 16 + i;
    Xt[((size_t)b * D_ + d0 + d) * L_ + m0 + mm] = t16[d][mm];
  }
}

// ---------------------------------------------------------------------------
// K-castW: W f32 -> fp16.
// ---------------------------------------------------------------------------
__global__ __launch_bounds__(256) void k_castW(const float* __restrict__ W,
                                               unsigned short* __restrict__ Wf,
                                               int n8) {
  const int i = blockIdx.x * 256 + threadIdx.x;
  if (i >= n8) return;
  const float4 a = *(const float4*)(W + (size_t)i * 8);
  const float4 b = *(const float4*)(W + (size_t)i * 8 + 4);
  *(ushort4*)(Wf + (size_t)i * 8)     = make_ushort4(f2h(a.x), f2h(a.y), f2h(a.z), f2h(a.w));
  *(ushort4*)(Wf + (size_t)i * 8 + 4) = make_ushort4(f2h(b.x), f2h(b.y), f2h(b.z), f2h(b.w));
}

// ---------------------------------------------------------------------------
// Staging helpers: 128-row x 128B LDS panels, XOR-swizzled pre-swizzled src.
// ---------------------------------------------------------------------------
__device__ __forceinline__ void stage_panel(const unsigned short* __restrict__ ph,
                                            const unsigned short* __restrict__ pl,
                                            size_t grow0, int kk,
                                            char* ldsbase, int wave, int lane) {
#pragma unroll
  for (int q = 0; q < 4; ++q) {
    const int s = wave * 4 + q;
    const int row = s * 8 + (lane >> 3);
    const int xs = (lane & 7) ^ (row & 7);
    const unsigned short* src = (xs & 4) ? pl : ph;
    const unsigned short* g = src + (grow0 + row) * D_ + kk + (xs & 3) * 8;
    __builtin_amdgcn_global_load_lds(
        (const __attribute__((address_space(1))) void*)g,
        (__attribute__((address_space(3))) void*)(ldsbase + s * 1024),
        16, 0, 0);
  }
}

__device__ __forceinline__ void stage_panel1(const unsigned short* __restrict__ g0,
                                             size_t rstride,
                                             char* ldsbase, int wave, int lane) {
#pragma unroll
  for (int q = 0; q < 4; ++q) {
    const int s = wave * 4 + q;
    const int row = s * 8 + (lane >> 3);
    const int xs = (lane & 7) ^ (row & 7);
    const unsigned short* g = g0 + (size_t)row * rstride + xs * 8;
    __builtin_amdgcn_global_load_lds(
        (const __attribute__((address_space(1))) void*)g,
        (__attribute__((address_space(3))) void*)(ldsbase + s * 1024),
        16, 0, 0);
  }
}

// indirect-row variant: row -> tokB[q] (hoisted), for compacted B panels
__device__ __forceinline__ void stage_panelI(const unsigned short* __restrict__ base,
                                             const int* __restrict__ tokB,
                                             int kk, char* ldsbase, int wave, int lane) {
#pragma unroll
  for (int q = 0; q < 4; ++q) {
    const int s = wave * 4 + q;
    const int row = s * 8 + (lane >> 3);
    const int xs = (lane & 7) ^ (row & 7);
    const unsigned short* g = base + (size_t)tokB[q] * D_ + kk + xs * 8;
    __builtin_amdgcn_global_load_lds(
        (const __attribute__((address_space(1))) void*)g,
        (__attribute__((address_space(3))) void*)(ldsbase + s * 1024),
        16, 0, 0);
  }
}

__device__ __forceinline__ bf16x8 ldsfrag(const char* base, int row, int g) {
  return *(const bf16x8*)(base + row * 128 + ((g ^ (row & 7)) * 16));
}
__device__ __forceinline__ half8 ldsfrag_h(const char* base, int row, int g) {
  return *(const half8*)(base + row * 128 + ((g ^ (row & 7)) * 16));
}

// ---------------------------------------------------------------------------
// K1 v4 (MFMA): P = relu(Xf·Wf^T + b), single fp16 pass. (unchanged r12)
// ---------------------------------------------------------------------------
__global__ __launch_bounds__(256) void k_proj3(const unsigned short* __restrict__ Xf,
                                               const unsigned short* __restrict__ Wf,
                                               const float* __restrict__ bias,
                                               unsigned short* __restrict__ Pf) {
  __shared__ __align__(16) char smem[49152];
  const int tid = threadIdx.x;
  const int xcd = (int)blockIdx.x & 7;
  const int li  = (int)blockIdx.x >> 3;
  const int m0 = (xcd * 16 + li / 6) * 128;
  const int n0 = (li % 6) * 128;
  const int lane = tid & 63, wave = tid >> 6;
  const int wr = wave >> 1, wc = wave & 1;
  const int fr = lane & 15, kg = lane >> 4;
  f32x4 acc[4][4];
#pragma unroll
  for (int i = 0; i < 4; ++i)
#pragma unroll
    for (int j = 0; j < 4; ++j) acc[i][j] = 0;

  const unsigned short* a0 = Xf + (size_t)m0 * D_;
  const unsigned short* b0 = Wf + (size_t)n0 * D_;

  stage_panel1(a0, D_, smem, wave, lane);
  stage_panel1(b0, D_, smem + 32768, wave, lane);
  __syncthreads();

  int cur = 0;
  for (int it = 0; it < D_ / 64; ++it) {
    const char* ab = smem + cur * 16384;
    const char* bb = smem + 32768;
    half8 fa[2][4], fb[2][4];
#pragma unroll
    for (int i = 0; i < 4; ++i) {
      const int ra = wr * 64 + i * 16 + fr;
      const int rb = wc * 64 + i * 16 + fr;
#pragma unroll
      for (int ks = 0; ks < 2; ++ks) {
        fa[ks][i] = ldsfrag_h(ab, ra, ks * 4 + kg);
        fb[ks][i] = ldsfrag_h(bb, rb, ks * 4 + kg);
      }
    }
    __syncthreads();
    if (it + 1 < D_ / 64) {
      stage_panel1(a0 + (it + 1) * 64, D_, smem + (cur ^ 1) * 16384, wave, lane);
      stage_panel1(b0 + (it + 1) * 64, D_, smem + 32768, wave, lane);
    }
#pragma unroll
    for (int ks = 0; ks < 2; ++ks)
#pragma unroll
      for (int i = 0; i < 4; ++i)
#pragma unroll
        for (int j = 0; j < 4; ++j)
          acc[i][j] = __builtin_amdgcn_mfma_f32_16x16x32_f16(fa[ks][i], fb[ks][j],
                                                             acc[i][j], 0, 0, 0);
    __syncthreads();
    cur ^= 1;
  }

  unsigned short* scr = (unsigned short*)smem + wave * 1152;
  const int row = lane >> 2, seg = lane & 3;
  float bj[4];
#pragma unroll
  for (int j = 0; j < 4; ++j) bj[j] = bias[n0 + wc * 64 + j * 16 + fr];
  for (int i = 0; i < 4; ++i) {
    __syncthreads();
#pragma unroll
    for (int j = 0; j < 4; ++j)
#pragma unroll
      for (int r = 0; r < 4; ++r)
        scr[(kg * 4 + r) * 72 + j * 16 + fr] = f2h(fmaxf(acc[i][j][r] + bj[j], 0.f));
    __syncthreads();
    const size_t gr = (size_t)(m0 + wr * 64 + i * 16 + row);
    const int gc0 = n0 + wc * 64 + seg * 16;
    const uint4 h0 = *(const uint4*)&scr[row * 72 + seg * 16];
    const uint4 h1 = *(const uint4*)&scr[row * 72 + seg * 16 + 8];
    *(uint4*)(Pf + gr * D_ + gc0)     = h0;
    *(uint4*)(Pf + gr * D_ + gc0 + 8) = h1;
  }
}

// ---------------------------------------------------------------------------
// K1 fallback (r5): on-the-fly split proj -> bf16 Ph/Pl.
// ---------------------------------------------------------------------------
__global__ __launch_bounds__(256) void k_proj(const float* __restrict__ X,
                                              const float* __restrict__ W,
                                              const float* __restrict__ bias,
                                              unsigned short* __restrict__ Ph,
                                              unsigned short* __restrict__ Pl) {
  __shared__ __align__(16) unsigned short smem[4 * 128 * 32];
  unsigned short (*Ah)[32] = (unsigned short(*)[32])smem;
  unsigned short (*Al)[32] = (unsigned short(*)[32])(smem + 1 * 128 * 32);
  unsigned short (*Bh)[32] = (unsigned short(*)[32])(smem + 2 * 128 * 32);
  unsigned short (*Bl)[32] = (unsigned short(*)[32])(smem + 3 * 128 * 32);

  const int tid = threadIdx.x;
  const int swz = ((int)blockIdx.x % 8) * 96 + (int)blockIdx.x / 8;
  const int m0 = (swz / 6) * 128, n0 = (swz % 6) * 128;
  const int lane = tid & 63, wave = tid >> 6;
  const int wr = wave >> 1, wc = wave & 1;
  const int fr = lane & 15, kg = lane >> 4;
  f32x4 acc[4][4];
#pragma unroll
  for (int i = 0; i < 4; ++i)
#pragma unroll
    for (int j = 0; j < 4; ++j) acc[i][j] = 0;

  float4 av[4], bv[4];
#pragma unroll
  for (int p = 0; p < 4; ++p) {
    const int f = tid + p * 256, r = f >> 3, c = f & 7;
    av[p] = *(const float4*)(X + (size_t)(m0 + r) * D_ + c * 4);
    bv[p] = *(const float4*)(W + (size_t)(n0 + r) * D_ + c * 4);
  }

  for (int it = 0; it < D_ / 32; ++it) {
    __syncthreads();
#pragma unroll
    for (int p = 0; p < 4; ++p) {
      const int f = tid + p * 256, r = f >> 3, c = f & 7;
      {
        const float x0 = av[p].x, x1 = av[p].y, x2 = av[p].z, x3 = av[p].w;
        const unsigned short h0 = f2bf(x0), h1 = f2bf(x1), h2 = f2bf(x2), h3 = f2bf(x3);
        *(ushort4*)&Ah[r][c * 4] = make_ushort4(h0, h1, h2, h3);
        *(ushort4*)&Al[r][c * 4] = make_ushort4(f2bf(x0 - bf2f(h0)), f2bf(x1 - bf2f(h1)),
                                                f2bf(x2 - bf2f(h2)), f2bf(x3 - bf2f(h3)));
      }
      {
        const float x0 = bv[p].x, x1 = bv[p].y, x2 = bv[p].z, x3 = bv[p].w;
        const unsigned short h0 = f2bf(x0), h1 = f2bf(x1), h2 = f2bf(x2), h3 = f2bf(x3);
        *(ushort4*)&Bh[r][c * 4] = make_ushort4(h0, h1, h2, h3);
        *(ushort4*)&Bl[r][c * 4] = make_ushort4(f2bf(x0 - bf2f(h0)), f2bf(x1 - bf2f(h1)),
                                                f2bf(x2 - bf2f(h2)), f2bf(x3 - bf2f(h3)));
      }
    }
    __syncthreads();
    if (it + 1 < D_ / 32) {
      const int kk = (it + 1) * 32;
#pragma unroll
      for (int p = 0; p < 4; ++p) {
        const int f = tid + p * 256, r = f >> 3, c = f & 7;
        av[p] = *(const float4*)(X + (size_t)(m0 + r) * D_ + kk + c * 4);
        bv[p] = *(const float4*)(W + (size_t)(n0 + r) * D_ + kk + c * 4);
      }
    }
    bf16x8 fah[4], fal[4], fbh[4], fbl[4];
#pragma unroll
    for (int i = 0; i < 4; ++i) {
      fah[i] = *(const bf16x8*)&Ah[wr * 64 + i * 16 + fr][kg * 8];
      fal[i] = *(const bf16x8*)&Al[wr * 64 + i * 16 + fr][kg * 8];
      fbh[i] = *(const bf16x8*)&Bh[wc * 64 + i * 16 + fr][kg * 8];
      fbl[i] = *(const bf16x8*)&Bl[wc * 64 + i * 16 + fr][kg * 8];
    }
#pragma unroll
    for (int i = 0; i < 4; ++i)
#pragma unroll
      for (int j = 0; j < 4; ++j) {
        acc[i][j] = __builtin_amdgcn_mfma_f32_16x16x32_bf16(fah[i], fbh[j], acc[i][j], 0, 0, 0);
        acc[i][j] = __builtin_amdgcn_mfma_f32_16x16x32_bf16(fah[i], fbl[j], acc[i][j], 0, 0, 0);
        acc[i][j] = __builtin_amdgcn_mfma_f32_16x16x32_bf16(fal[i], fbh[j], acc[i][j], 0, 0, 0);
      }
  }

  unsigned short* scr = smem + wave * 2304;
  const int row = lane >> 2, seg = lane & 3;
  float bj[4];
#pragma unroll
  for (int j = 0; j < 4; ++j) bj[j] = bias[n0 + wc * 64 + j * 16 + fr];
  for (int i = 0; i < 4; ++i) {
    __syncthreads();
#pragma unroll
    for (int j = 0; j < 4; ++j)
#pragma unroll
      for (int r = 0; r < 4; ++r) {
        float v = fmaxf(acc[i][j][r] + bj[j], 0.f);
        const unsigned short h = f2bf(v);
        scr[(kg * 4 + r) * 72 + j * 16 + fr] = h;
        scr[1152 + (kg * 4 + r) * 72 + j * 16 + fr] = f2bf(v - bf2f(h));
      }
    __syncthreads();
    const size_t gr = (size_t)(m0 + wr * 64 + i * 16 + row);
    const int gc0 = n0 + wc * 64 + seg * 16;
    const uint4 h0 = *(const uint4*)&scr[row * 72 + seg * 16];
    const uint4 h1 = *(const uint4*)&scr[row * 72 + seg * 16 + 8];
    const uint4 q0 = *(const uint4*)&scr[1152 + row * 72 + seg * 16];
    const uint4 q1 = *(const uint4*)&scr[1152 + row * 72 + seg * 16 + 8];
    *(uint4*)(Ph + gr * D_ + gc0)     = h0;
    *(uint4*)(Ph + gr * D_ + gc0 + 8) = h1;
    *(uint4*)(Pl + gr * D_ + gc0)     = q0;
    *(uint4*)(Pl + gr * D_ + gc0 + 8) = q1;
  }
}

// ---------------------------------------------------------------------------
// K2 v3 (MFMA): COMPACT-COLUMN scores. S_c[l][j] = Pf[l]·Pf[tok(j)] for
// j < kv only (B staged via ctok indirection). Diag: tok(j)==l -> 0.
// No mask (-inf) needed: all compacted cols are valid keys. No mirror.
// Grid 1024 (XCD-swizzled, 2 batches/XCD); blocks with c0 >= kv exit.
// ---------------------------------------------------------------------------
__global__ __launch_bounds__(256) void k_scores_c(const unsigned short* __restrict__ Pf,
                                                  const int* __restrict__ ctok,
                                                  const int* __restrict__ kinfo,
                                                  float* __restrict__ S) {
  __shared__ __align__(16) char smem[49152];  // A: 2x16KB @0, B: 16KB @32KB
  const int tid = threadIdx.x;
  const int swz = ((int)blockIdx.x & 7) * 128 + ((int)blockIdx.x >> 3);
  const int bb = swz >> 6;
  const int l0 = ((swz >> 3) & 7) * 128;
  const int c0 = (swz & 7) * 128;
  const int kv = kinfo[16 + bb];
  if (c0 >= kv) return;  // uniform early exit (whole block)

  const int lane = tid & 63, wave = tid >> 6;
  const int wr = wave >> 1, wc = wave & 1;
  const int fr = lane & 15, kg = lane >> 4;
  f32x4 acc[4][4];
#pragma unroll
  for (int i = 0; i < 4; ++i)
#pragma unroll
    for (int j = 0; j < 4; ++j) acc[i][j] = 0;

  const unsigned short* Pfb = Pf + (size_t)bb * L_ * D_;
  const int* ctokb = ctok + bb * L_;
  const unsigned short* a0 = Pfb + (size_t)l0 * D_;

  // hoist B-panel row tokens (4 per thread)
  int tokB[4];
#pragma unroll
  for (int q = 0; q < 4; ++q)
    tokB[q] = ctokb[c0 + (wave * 4 + q) * 8 + (lane >> 3)];

  stage_panel1(a0, D_, smem, wave, lane);
  stage_panelI(Pfb, tokB, 0, smem + 32768, wave, lane);
  __syncthreads();

  int cur = 0;
  for (int it = 0; it < D_ / 64; ++it) {
    const char* ab = smem + cur * 16384;
    const char* bpan = smem + 32768;
    half8 fa[2][4], fb[2][4];
#pragma unroll
    for (int i = 0; i < 4; ++i) {
      const int ra = wr * 64 + i * 16 + fr;
      const int rb = wc * 64 + i * 16 + fr;
#pragma unroll
      for (int ks = 0; ks < 2; ++ks) {
        fa[ks][i] = ldsfrag_h(ab, ra, ks * 4 + kg);
        fb[ks][i] = ldsfrag_h(bpan, rb, ks * 4 + kg);
      }
    }
    __syncthreads();  // all reads done -> safe to overwrite B / stage next A
    if (it + 1 < D_ / 64) {
      stage_panel1(a0 + (it + 1) * 64, D_, smem + (cur ^ 1) * 16384, wave, lane);
      stage_panelI(Pfb, tokB, (it + 1) * 64, smem + 32768, wave, lane);
    }
#pragma unroll
    for (int ks = 0; ks < 2; ++ks)
#pragma unroll
      for (int i = 0; i < 4; ++i)
#pragma unroll
        for (int j = 0; j < 4; ++j)
          acc[i][j] = __builtin_amdgcn_mfma_f32_16x16x32_f16(fa[ks][i], fb[ks][j],
                                                             acc[i][j], 0, 0, 0);
    __syncthreads();
    cur ^= 1;
  }

  // Epilogue: LDS transpose -> coalesced 64B/lane rows; diag via ctok.
  float* scr = (float*)smem + wave * 1280;
  const int row = lane >> 2, seg = lane & 3;
  for (int i = 0; i < 4; ++i) {
    __syncthreads();
#pragma unroll
    for (int j = 0; j < 4; ++j)
#pragma unroll
      for (int r = 0; r < 4; ++r)
        scr[(kg * 4 + r) * 68 + j * 16 + fr] = acc[i][j][r];
    __syncthreads();
    const int gl = l0 + wr * 64 + i * 16 + row;
    const int gcb = c0 + wc * 64 + seg * 16;
    const size_t sbase = ((size_t)bb * L_ + gl) * L_ + gcb;
#pragma unroll
    for (int t = 0; t < 4; ++t) {
      float4 o = *(const float4*)&scr[row * 68 + seg * 16 + t * 4];
      const int4 tk = *(const int4*)(ctokb + gcb + t * 4);
      if (tk.x == gl) o.x = 0.f;
      if (tk.y == gl) o.y = 0.f;
      if (tk.z == gl) o.z = 0.f;
      if (tk.w == gl) o.w = 0.f;
      *(float4*)(S + sbase + t * 4) = o;
    }
  }
}

// ---------------------------------------------------------------------------
// K2 fallback (r5): S = P·P^T from bf16 hi/lo Ph/Pl, 3-pass, symmetric.
// ---------------------------------------------------------------------------
__global__ __launch_bounds__(256) void k_scores_bf(const unsigned short* __restrict__ Ph,
                                                   const unsigned short* __restrict__ Pl,
                                                   const int* __restrict__ mask,
                                                   float* __restrict__ S) {
  __shared__ __align__(16) char smem[65536];

  const int tid = threadIdx.x;
  const int swz = ((int)blockIdx.x % 8) * 72 + (int)blockIdx.x / 8;
  const int bb = swz / 36;
  const int pr = swz % 36;
  int ti = 0;
  while ((ti + 1) * (ti + 2) / 2 <= pr) ++ti;
  const int tj = pr - ti * (ti + 1) / 2;
  const int l0 = ti * 128, m0 = tj * 128;
  const int lane = tid & 63, wave = tid >> 6;
  const int wr = wave >> 1, wc = wave & 1;
  const int fr = lane & 15, kg = lane >> 4;
  f32x4 acc[4][4];
#pragma unroll
  for (int i = 0; i < 4; ++i)
#pragma unroll
    for (int j = 0; j < 4; ++j) acc[i][j] = 0;

  const size_t arow0 = (size_t)bb * L_ + l0;
  const size_t brow0 = (size_t)bb * L_ + m0;

  stage_panel(Ph, Pl, arow0, 0, smem, wave, lane);
  stage_panel(Ph, Pl, brow0, 0, smem + 16384, wave, lane);
  __syncthreads();

  int cur = 0;
  for (int it = 0; it < D_ / 32; ++it) {
    char* cb = smem + cur * 32768;
    if (it + 1 < D_ / 32) {
      char* nb = smem + (cur ^ 1) * 32768;
      stage_panel(Ph, Pl, arow0, (it + 1) * 32, nb, wave, lane);
      stage_panel(Ph, Pl, brow0, (it + 1) * 32, nb + 16384, wave, lane);
    }
    bf16x8 fah[4], fal[4], fbh[4], fbl[4];
#pragma unroll
    for (int i = 0; i < 4; ++i) {
      const int ra = wr * 64 + i * 16 + fr;
      const int rb = wc * 64 + i * 16 + fr;
      fah[i] = ldsfrag(cb, ra, kg);
      fal[i] = ldsfrag(cb, ra, kg + 4);
      fbh[i] = ldsfrag(cb + 16384, rb, kg);
      fbl[i] = ldsfrag(cb + 16384, rb, kg + 4);
    }
#pragma unroll
    for (int i = 0; i < 4; ++i)
#pragma unroll
      for (int j = 0; j < 4; ++j) {
        acc[i][j] = __builtin_amdgcn_mfma_f32_16x16x32_bf16(fah[i], fbh[j], acc[i][j], 0, 0, 0);
        acc[i][j] = __builtin_amdgcn_mfma_f32_16x16x32_bf16(fah[i], fbl[j], acc[i][j], 0, 0, 0);
        acc[i][j] = __builtin_amdgcn_mfma_f32_16x16x32_bf16(fal[i], fbh[j], acc[i][j], 0, 0, 0);
      }
    __syncthreads();
    cur ^= 1;
  }

  float* scr = (float*)smem + wave * 1280;
  const int row = lane >> 2, seg = lane & 3;
  for (int i = 0; i < 4; ++i) {
    __syncthreads();
#pragma unroll
    for (int j = 0; j < 4; ++j)
#pragma unroll
      for (int r = 0; r < 4; ++r)
        scr[(kg * 4 + r) * 68 + j * 16 + fr] = acc[i][j][r];
    __syncthreads();
    const int gl = l0 + wr * 64 + i * 16 + row;
    const int gm0 = m0 + wc * 64 + seg * 16;
    const size_t sbase = ((size_t)bb * L_ + gl) * L_ + gm0;
#pragma unroll
    for (int t = 0; t < 4; ++t) {
      float4 o = *(const float4*)&scr[row * 68 + seg * 16 + t * 4];
      const int4 mk = *(const int4*)(mask + bb * L_ + gm0 + t * 4);
      float* op = (float*)&o;
      const int* mp = (const int*)&mk;
#pragma unroll
      for (int e = 0; e < 4; ++e) {
        const int gm = gm0 + t * 4 + e;
        if (gm == gl) op[e] = 0.f;
        if (mp[e]) op[e] = -INFINITY;
      }
      *(float4*)(S + sbase + t * 4) = o;
    }
  }

  if (ti != tj) {
    __syncthreads();
#pragma unroll
    for (int j = 0; j < 4; ++j) {
      const int mloc = wc * 64 + j * 16 + fr;
#pragma unroll
      for (int i = 0; i < 4; ++i) {
        const int slot = wr * 16 + i * 4 + kg;
        const int xs = slot ^ (mloc & 7);
        *(f32x4*)(smem + mloc * 512 + xs * 16) = acc[i][j];
      }
    }
    __syncthreads();
    const int mrow = tid >> 1, half = tid & 1;
    const size_t sbase = ((size_t)bb * L_ + m0 + mrow) * L_ + l0;
#pragma unroll
    for (int q = 0; q < 16; ++q) {
      const int slot = half * 16 + q;
      const int xs = slot ^ (mrow & 7);
      float4 o = *(const float4*)(smem + mrow * 512 + xs * 16);
      const int4 mk = *(const int4*)(mask + bb * L_ + l0 + slot * 4);
      if (mk.x) o.x = -INFINITY;
      if (mk.y) o.y = -INFINITY;
      if (mk.z) o.z = -INFINITY;
      if (mk.w) o.w = -INFINITY;
      *(float4*)(S + sbase + slot * 4) = o;
    }
  }
}

// ---------------------------------------------------------------------------
// K3 v2 (fast path): softmax over COMPACTED row [0,kv); writes a16c
// coalesced (+tail zeros to nt*64) and scatters the full alpha row via LDS
// (masked cols exactly 0).
// ---------------------------------------------------------------------------
__global__ __launch_bounds__(256) void k_softmax_c(float* __restrict__ S,
                                                   unsigned short* __restrict__ a16,
                                                   const int* __restrict__ ctok,
                                                   const int* __restrict__ kinfo) {
  __shared__ float ar[1024];
  __shared__ float rmax[4], rsum[4];
  const size_t row = blockIdx.x;
  const int bb = (int)(row >> 10);
  const int kv = kinfo[16 + bb];
  const int nt64 = kinfo[bb] * 64;
  const int tid = threadIdx.x;
  const int p0 = tid * 4;

  const float4 v = *(const float4*)(S + row * L_ + p0);
  float vv[4];
#pragma unroll
  for (int e = 0; e < 4; ++e) vv[e] = (p0 + e < kv) ? ((const float*)&v)[e] : -INFINITY;

  float mx = fmaxf(fmaxf(vv[0], vv[1]), fmaxf(vv[2], vv[3]));
#pragma unroll
  for (int o = 32; o > 0; o >>= 1) mx = fmaxf(mx, __shfl_xor(mx, o));
  const int wv = tid >> 6, ln = tid & 63;
  if (ln == 0) rmax[wv] = mx;
  __syncthreads();
  mx = fmaxf(fmaxf(rmax[0], rmax[1]), fmaxf(rmax[2], rmax[3]));

  float ee[4];
  float s = 0.f;
#pragma unroll
  for (int e = 0; e < 4; ++e) {
    ee[e] = (p0 + e < kv) ? __expf(vv[e] - mx) : 0.f;
    s += ee[e];
  }
#pragma unroll
  for (int o = 32; o > 0; o >>= 1) s += __shfl_xor(s, o);
  if (ln == 0) rsum[wv] = s;
  __syncthreads();
  s = (rsum[0] + rsum[1]) + (rsum[2] + rsum[3]);
  const float inv = 1.0f / s;
#pragma unroll
  for (int e = 0; e < 4; ++e) ee[e] *= inv;

  // a16c: coalesced compacted write, zeros over [kv, nt64)
  if (p0 < nt64) {
    ushort4 h;
    h.x = (p0 + 0 < kv) ? f2h(ee[0]) : 0;
    h.y = (p0 + 1 < kv) ? f2h(ee[1]) : 0;
    h.z = (p0 + 2 < kv) ? f2h(ee[2]) : 0;
    h.w = (p0 + 3 < kv) ? f2h(ee[3]) : 0;
    *(ushort4*)(a16 + row * L_ + p0) = h;
  }

  // full alpha row via LDS scatter (masked cols stay 0)
  *(float4*)&ar[p0] = make_float4(0.f, 0.f, 0.f, 0.f);
  __syncthreads();
  const int* ctokb = ctok + bb * L_;
#pragma unroll
  for (int e = 0; e < 4; ++e)
    if (p0 + e < kv) ar[ctokb[p0 + e]] = ee[e];
  __syncthreads();
  *(float4*)(S + row * L_ + p0) = *(const float4*)&ar[p0];
}

// ---------------------------------------------------------------------------
// K3 fallback: full-row softmax (in-place), no a16.
// ---------------------------------------------------------------------------
__global__ __launch_bounds__(256) void k_softmax(float* __restrict__ S) {
  const size_t row = blockIdx.x;
  float4* rp = (float4*)(S + row * L_);
  float4 v = rp[threadIdx.x];
  float mx = fmaxf(fmaxf(v.x, v.y), fmaxf(v.z, v.w));
#pragma unroll
  for (int o = 32; o > 0; o >>= 1) mx = fmaxf(mx, __shfl_xor(mx, o));
  __shared__ float rmax[4], rsum[4];
  const int wv = threadIdx.x >> 6, ln = threadIdx.x & 63;
  if (ln == 0) rmax[wv] = mx;
  __syncthreads();
  mx = fmaxf(fmaxf(rmax[0], rmax[1]), fmaxf(rmax[2], rmax[3]));
  float4 e;
  e.x = __expf(v.x - mx); e.y = __expf(v.y - mx);
  e.z = __expf(v.z - mx); e.w = __expf(v.w - mx);
  float s = (e.x + e.y) + (e.z + e.w);
#pragma unroll
  for (int o = 32; o > 0; o >>= 1) s += __shfl_xor(s, o);
  if (ln == 0) rsum[wv] = s;
  __syncthreads();
  s = (rsum[0] + rsum[1]) + (rsum[2] + rsum[3]);
  const float inv = 1.0f / s;
  e.x *= inv; e.y *= inv; e.z *= inv; e.w *= inv;
  rp[threadIdx.x] = e;
}

// ---------------------------------------------------------------------------
// K5 v5 (MFMA): align = a16c·Xtc^T, compacted K, dynamic loop. (unchanged r12)
// ---------------------------------------------------------------------------
__global__ __launch_bounds__(256) void k_align2(const unsigned short* __restrict__ A16,
                                                const unsigned short* __restrict__ Xt,
                                                const int* __restrict__ kinfo,
                                                float* __restrict__ O) {
  __shared__ __align__(16) char smem[49152];
  const int tid = threadIdx.x;
  const int swz = ((int)blockIdx.x % 8) * 96 + (int)blockIdx.x / 8;
  const int bb = swz / 48;
  const int l0 = ((swz / 6) % 8) * 128;
  const int n0 = (swz % 6) * 128;
  const int nt = kinfo[bb];
  const int lane = tid & 63, wave = tid >> 6;
  const int wr = wave >> 1, wc = wave & 1;
  const int fr = lane & 15, kg = lane >> 4;
  f32x4 acc[4][4];
#pragma unroll
  for (int i = 0; i < 4; ++i)
#pragma unroll
    for (int j = 0; j < 4; ++j) acc[i][j] = 0;

  const unsigned short* a0 = A16 + ((size_t)bb * L_ + l0) * L_;
  const unsigned short* b0 = Xt + ((size_t)bb * D_ + n0) * L_;

  if (nt > 0) {
    stage_panel1(a0, L_, smem, wave, lane);
    stage_panel1(b0, L_, smem + 32768, wave, lane);
  }
  __syncthreads();

  int cur = 0;
  for (int it = 0; it < nt; ++it) {
    const char* ab = smem + cur * 16384;
    const char* bb2 = smem + 32768;
    half8 fa[2][4], fb[2][4];
#pragma unroll
    for (int i = 0; i < 4; ++i) {
      const int ra = wr * 64 + i * 16 + fr;
      const int rb = wc * 64 + i * 16 + fr;
#pragma unroll
      for (int ks = 0; ks < 2; ++ks) {
        fa[ks][i] = ldsfrag_h(ab, ra, ks * 4 + kg);
        fb[ks][i] = ldsfrag_h(bb2, rb, ks * 4 + kg);
      }
    }
    __syncthreads();
    if (it + 1 < nt) {
      stage_panel1(a0 + (it + 1) * 64, L_, smem + (cur ^ 1) * 16384, wave, lane);
      stage_panel1(b0 + (it + 1) * 64, L_, smem + 32768, wave, lane);
    }
#pragma unroll
    for (int ks = 0; ks < 2; ++ks)
#pragma unroll
      for (int i = 0; i < 4; ++i)
#pragma unroll
        for (int j = 0; j < 4; ++j)
          acc[i][j] = __builtin_amdgcn_mfma_f32_16x16x32_f16(fa[ks][i], fb[ks][j],
                                                             acc[i][j], 0, 0, 0);
    __syncthreads();
    cur ^= 1;
  }

  float* scr = (float*)smem + wave * 1280;
  const int row = lane >> 2, seg = lane & 3;
  for (int i = 0; i < 4; ++i) {
    __syncthreads();
#pragma unroll
    for (int j = 0; j < 4; ++j)
#pragma unroll
      for (int r = 0; r < 4; ++r)
        scr[(kg * 4 + r) * 68 + j * 16 + fr] = acc[i][j][r];
    __syncthreads();
    const int gl = l0 + wr * 64 + i * 16 + row;
    const int gc0 = n0 + wc * 64 + seg * 16;
    const size_t obase = ((size_t)bb * L_ + gl) * D_ + gc0;
#pragma unroll
    for (int t = 0; t < 4; ++t) {
      const float4 o = *(const float4*)&scr[row * 68 + seg * 16 + t * 4];
      *(float4*)(O + obase + t * 4) = o;
    }
  }
}

// ---------------------------------------------------------------------------
// K5 fallback (r6): align = alpha(f32)·Xt^T (bf16 Xt), staging conversion.
// ---------------------------------------------------------------------------
__global__ __launch_bounds__(256) void k_align(const float* __restrict__ A,
                                               const unsigned short* __restrict__ Xt,
                                               float* __restrict__ O) {
  __shared__ __align__(16) unsigned short smem[2 * 128 * 32];
  __shared__ __align__(16) float scr_s[4 * 1104];
  unsigned short (*Ab)[32] = (unsigned short(*)[32])smem;
  unsigned short (*Bb)[32] = (unsigned short(*)[32])(smem + 128 * 32);

  const int tid = threadIdx.x;
  const int swz = ((int)blockIdx.x % 8) * 96 + (int)blockIdx.x / 8;
  const int bb = swz / 48;
  const int l0 = ((swz / 6) % 8) * 128;
  const int n0 = (swz % 6) * 128;
  const int lane = tid & 63, wave = tid >> 6;
  const int wr = wave >> 1, wc = wave & 1;
  const int fr = lane & 15, kg = lane >> 4;
  f32x4 acc[4][4];
#pragma unroll
  for (int i = 0; i < 4; ++i)
#pragma unroll
    for (int j = 0; j < 4; ++j) acc[i][j] = 0;

  float4 av[4];
  uint4 bv[2];
#pragma unroll
  for (int p = 0; p < 4; ++p) {
    const int f = tid + p * 256, r = f >> 3, c = f & 7;
    av[p] = *(const float4*)(A + ((size_t)bb * L_ + l0 + r) * L_ + c * 4);
  }
#pragma unroll
  for (int p = 0; p < 2; ++p) {
    const int f = tid + p * 256, r = f >> 2, sl = f & 3;
    bv[p] = *(const uint4*)(Xt + ((size_t)bb * D_ + n0 + r) * L_ + sl * 8);
  }

  for (int it = 0; it < L_ / 32; ++it) {
    __syncthreads();
#pragma unroll
    for (int p = 0; p < 4; ++p) {
      const int f = tid + p * 256, r = f >> 3, c = f & 7;
      *(ushort4*)&Ab[r][c * 4] = make_ushort4(f2bf(av[p].x), f2bf(av[p].y),
                                              f2bf(av[p].z), f2bf(av[p].w));
    }
#pragma unroll
    for (int p = 0; p < 2; ++p) {
      const int f = tid + p * 256, r = f >> 2, sl = f & 3;
      *(uint4*)&Bb[r][sl * 8] = bv[p];
    }
    __syncthreads();
    if (it + 1 < L_ / 32) {
      const int kk = (it + 1) * 32;
#pragma unroll
      for (int p = 0; p < 4; ++p) {
        const int f = tid + p * 256, r = f >> 3, c = f & 7;
        av[p] = *(const float4*)(A + ((size_t)bb * L_ + l0 + r) * L_ + kk + c * 4);
      }
#pragma unroll
      for (int p = 0; p < 2; ++p) {
        const int f = tid + p * 256, r = f >> 2, sl = f & 3;
        bv[p] = *(const uint4*)(Xt + ((size_t)bb * D_ + n0 + r) * L_ + kk + sl * 8);
      }
    }
    bf16x8 fa[4], fb[4];
#pragma unroll
    for (int i = 0; i < 4; ++i) {
      fa[i] = *(const bf16x8*)&Ab[wr * 64 + i * 16 + fr][kg * 8];
      fb[i] = *(const bf16x8*)&Bb[wc * 64 + i * 16 + fr][kg * 8];
    }
#pragma unroll
    for (int i = 0; i < 4; ++i)
#pragma unroll
      for (int j = 0; j < 4; ++j)
        acc[i][j] = __builtin_amdgcn_mfma_f32_16x16x32_bf16(fa[i], fb[j], acc[i][j], 0, 0, 0);
  }

  float* scr = scr_s + wave * 1104;
  const int row = lane >> 2, seg = lane & 3;
  for (int i = 0; i < 4; ++i) {
    __syncthreads();
#pragma unroll
    for (int j = 0; j < 4; ++j)
#pragma unroll
      for (int r = 0; r < 4; ++r)
        scr[(kg * 4 + r) * 68 + j * 16 + fr] = acc[i][j][r];
    __syncthreads();
    const int gl = l0 + wr * 64 + i * 16 + row;
    const int gc0 = n0 + wc * 64 + seg * 16;
    const size_t obase = ((size_t)bb * L_ + gl) * D_ + gc0;
#pragma unroll
    for (int t = 0; t < 4; ++t) {
      const float4 o = *(const float4*)&scr[row * 68 + seg * 16 + t * 4];
      *(float4*)(O + obase + t * 4) = o;
    }
  }
}

// ---------------------------------------------------------------------------
extern "C" void kernel_launch(void* const* d_in, const int* in_sizes, int n_in,
                              void* d_out, int out_size, void* d_ws, size_t ws_size,
                              hipStream_t stream) {
  const float* X    = (const float*)d_in[0];  // [B,L,D]
  const void*  mraw = d_in[1];                // [B,L] bool/int
  const float* W    = (const float*)d_in[2];  // [D,D]
  const float* bias = (const float*)d_in[3];  // [D]

  float* out   = (float*)d_out;
  float* align = out;                          // B*L*D fp32 (48MB)
  float* alpha = out + (size_t)B_ * L_ * D_;   // B*L*L fp32 (64MB)

  const size_t NX = (size_t)B_ * L_ * D_;   // 12,582,912
  const size_t NW = (size_t)D_ * D_;        // 589,824
  const size_t NA = (size_t)B_ * L_ * L_;   // 16,777,216

  // ws layout: maskC(64K) | psum(64K) | kinfo(4K) | ctok(64K) | Xtc | Wf/a16c
  int* maskC = (int*)d_ws;
  int* psum  = (int*)((char*)d_ws + 65536);
  int* kinfo = (int*)((char*)d_ws + 131072);
  int* ctok  = (int*)((char*)d_ws + 135168);
  const size_t offXt = 135168 + 65536;
  unsigned short* Xt = (unsigned short*)((char*)d_ws + offXt);
  const size_t offWf = offXt + NX * 2;
  const size_t offA16 = offWf;              // a16c overlays Wf (dead after proj3)
  const size_t need = offA16 + NA * 2;      // ~59.0 MB

  hipLaunchKernelGGL(k_mask2, dim3(16), dim3(256), 0, stream, mraw, maskC, psum, kinfo, ctok);

  if (ws_size >= need) {
    unsigned short* Xf = (unsigned short*)alpha;   // dead until scores_c writes S_c
    unsigned short* Wf = (unsigned short*)((char*)d_ws + offWf);
    unsigned short* Pf = (unsigned short*)align;   // dead until k_align2 writes
    unsigned short* A16 = (unsigned short*)((char*)d_ws + offA16);
    hipLaunchKernelGGL(k_prep16, dim3(D_ / 64, L_ / 64, B_), dim3(256), 0, stream,
                       X, Xf, Xt, psum, maskC, kinfo);
    hipLaunchKernelGGL(k_castW, dim3((int)(NW / 8 / 256)), dim3(256), 0, stream,
                       W, Wf, (int)(NW / 8));
    hipLaunchKernelGGL(k_proj3, dim3(768), dim3(256), 0, stream, Xf, Wf, bias, Pf);
    hipLaunchKernelGGL(k_scores_c, dim3(1024), dim3(256), 0, stream, Pf, ctok, kinfo, alpha);
    hipLaunchKernelGGL(k_softmax_c, dim3(B_ * L_), dim3(256), 0, stream,
                       alpha, A16, ctok, kinfo);
    hipLaunchKernelGGL(k_align2, dim3(768), dim3(256), 0, stream, A16, Xt, kinfo, align);
  } else {
    // fallback: full bf16 path, non-compacted Xt, symmetric scores.
    unsigned short* Ph = (unsigned short*)align;
    unsigned short* Pl = Ph + NX;
    hipLaunchKernelGGL(k_prep, dim3(D_ / 64, L_ / 64, B_), dim3(256), 0, stream,
                       X, (unsigned short*)alpha, (unsigned short*)alpha + NX, Xt);
    hipLaunchKernelGGL(k_proj, dim3(768), dim3(256), 0, stream, X, W, bias, Ph, Pl);
    hipLaunchKernelGGL(k_scores_bf, dim3(576), dim3(256), 0, stream, Ph, Pl, maskC, alpha);
    hipLaunchKernelGGL(k_softmax, dim3(B_ * L_), dim3(256), 0, stream, alpha);
    hipLaunchKernelGGL(k_align, dim3(768), dim3(256), 0, stream, alpha, Xt, align);
  }
}